// Round 6
// baseline (448.426 us; speedup 1.0000x reference)
//
#include <hip/hip_runtime.h>
#include <cstddef>
#include <cstdint>

#define N_SH 1195
#define N_SS 390
#define N_HH 805
#define DIM  64
#define RPB  14        // rows per histogram bucket

typedef __bf16 bf16_t;
typedef bf16_t bf16x4v __attribute__((ext_vector_type(4)));
typedef bf16_t bf16x8v __attribute__((ext_vector_type(8)));
typedef float f32x4 __attribute__((ext_vector_type(4)));

__device__ inline ushort f2bf(float f) {
    union { float f; uint32_t u; } c; c.f = f;
    uint32_t u = c.u;
    u += 0x7FFFu + ((u >> 16) & 1u);
    return (ushort)(u >> 16);
}

// bijective XCD swizzle (m204)
__device__ inline void xcd_swizzle(int gx, int gy, int& bx, int& by) {
    int nwg = gx * gy;
    int lin = by * gx + bx;
    int q = nwg >> 3, r = nwg & 7;
    int xcd = lin & 7, idx = lin >> 3;
    int nt = (xcd < r ? xcd * (q + 1) : r * (q + 1) + (xcd - r) * q) + idx;
    by = nt / gx; bx = nt % gx;
}

// ================= binned adjacency build =================================
// Phase A: bucket counts (bucket = dst / RPB)
__global__ void bucket_count_kernel(const int* __restrict__ ei, int E, int NB,
                                    uint32_t* __restrict__ cnt) {
    __shared__ uint32_t lc[96];
    int tid = threadIdx.x;
    if (tid < 96) lc[tid] = 0;
    __syncthreads();
    for (int i = blockIdx.x * blockDim.x + tid; i < E; i += gridDim.x * blockDim.x) {
        int dst = ei[E + i];
        atomicAdd(&lc[dst / RPB], 1u);
    }
    __syncthreads();
    if (tid < NB && lc[tid]) atomicAdd(&cnt[tid], lc[tid]);
}

// Phase B: per-graph exclusive scan; bases at +256, cursors at +512
__global__ void bucket_scan_kernel(uint32_t* __restrict__ ctr) {
    if (threadIdx.x != 0 || blockIdx.x != 0) return;
    const int segs[4] = {0, 86, 114, 172};
    for (int s = 0; s < 3; ++s) {
        uint32_t run = 0;
        for (int b = segs[s]; b < segs[s + 1]; ++b) {
            ctr[256 + b] = run;
            ctr[512 + b] = run;
            run += ctr[b];
        }
    }
}

// Phase C: scatter packed cells into bucket segments
__global__ __launch_bounds__(256) void bucket_scatter_kernel(
    const int* __restrict__ ei, int E, int N,
    uint32_t* __restrict__ cursor, uint32_t* __restrict__ binned) {
    __shared__ uint32_t lcnt[96];
    __shared__ uint32_t lbase[96];
    const int tid = threadIdx.x;
    const int start = blockIdx.x * 4096;
    const int end = (start + 4096 < E) ? start + 4096 : E;
    if (tid < 96) lcnt[tid] = 0;
    __syncthreads();
    for (int i = start + tid; i < end; i += 256)
        atomicAdd(&lcnt[ei[E + i] / RPB], 1u);
    __syncthreads();
    if (tid < 96) {
        lbase[tid] = lcnt[tid] ? atomicAdd(&cursor[tid], lcnt[tid]) : 0u;
    }
    __syncthreads();
    if (tid < 96) lcnt[tid] = 0;
    __syncthreads();
    for (int i = start + tid; i < end; i += 256) {
        int dst = ei[E + i], src = ei[i];
        int b = dst / RPB;
        uint32_t off = atomicAdd(&lcnt[b], 1u);
        binned[lbase[b] + off] = (uint32_t)dst * (uint32_t)N + (uint32_t)src;
    }
}

// Phase D: per-bucket exact histogram -> bf16 padded adjacency (+ row sums)
__global__ __launch_bounds__(256) void hist_write_kernel(
    const uint32_t* __restrict__ binned,
    const uint32_t* __restrict__ bCnt, const uint32_t* __restrict__ bBase,
    int N, int Kp, ushort* __restrict__ adj, float* __restrict__ cntInv) {
    extern __shared__ uint32_t h[];   // RPB * N counters
    const int tid = threadIdx.x;
    const int b = blockIdx.x;
    const int row0 = b * RPB;
    const int tot = RPB * N;
    for (int i = tid; i < tot; i += 256) h[i] = 0;
    __syncthreads();
    const uint32_t cnt = bCnt[b], base = bBase[b];
    const uint32_t cell0 = (uint32_t)row0 * (uint32_t)N;
    for (uint32_t i = tid; i < cnt; i += 256)
        atomicAdd(&h[binned[base + i] - cell0], 1u);
    __syncthreads();
    #pragma unroll 1
    for (int rr = 0; rr < RPB; ++rr) {
        int row = row0 + rr;
        for (int col = tid; col < Kp; col += 256) {
            float v = (col < N) ? (float)h[rr * N + col] : 0.f;
            adj[(size_t)row * Kp + col] = f2bf(v);
        }
    }
    if (cntInv) {
        __shared__ float red[4];
        for (int rr = 0; rr < RPB; ++rr) {
            int row = row0 + rr;
            if (row >= N) break;
            float s = 0.f;
            for (int c = tid; c < N; c += 256) s += (float)h[rr * N + c];
            for (int off2 = 32; off2 > 0; off2 >>= 1) s += __shfl_down(s, off2);
            if ((tid & 63) == 0) red[tid >> 6] = s;
            __syncthreads();
            if (tid == 0) {
                float t = red[0] + red[1] + red[2] + red[3];
                cntInv[row] = 1.0f / fmaxf(t, 1.0f);
            }
            __syncthreads();
        }
    }
}

// P[r][0:390] f32 -> P_b[r][0:416] bf16 (zero-pad) + presInv[r] = 1/rowsum
__global__ __launch_bounds__(128) void cvt_rowsum_p_kernel(
    const float* __restrict__ P, ushort* __restrict__ Pb,
    float* __restrict__ presInv)
{
    __shared__ float red[2];
    const int r = blockIdx.x;
    const int tid = threadIdx.x;
    float s = 0.f;
    #pragma unroll
    for (int it = 0; it < 4; ++it) {
        int c = tid + it * 128;
        float v = 0.f;
        if (c < N_SS) { v = P[(size_t)r * N_SS + c]; s += v; }
        if (c < 416) Pb[(size_t)r * 416 + c] = f2bf(v);
    }
    for (int off = 32; off > 0; off >>= 1) s += __shfl_down(s, off);
    if ((tid & 63) == 0) red[tid >> 6] = s;
    __syncthreads();
    if (tid == 0) {
        float t = red[0] + red[1];
        presInv[r] = (t != 0.f) ? 1.0f / t : 0.f;
    }
}

// ---------------- fp32 GEMM (small dense layers) ----------------------------
#define BM 64
#define BN 64
#define BK 16

__global__ __launch_bounds__(256) void gemm_kernel(
    const float* __restrict__ A, const float* __restrict__ B,
    const float* __restrict__ bias, const float* __restrict__ rowScale,
    float* __restrict__ C, int M, int N, int K, int act)
{
    __shared__ float As[BK][BM + 4];
    __shared__ float Bs[BK][BN];
    const int tid  = threadIdx.x;
    const int row0 = blockIdx.y * BM;
    const int col0 = blockIdx.x * BN;
    const int tr  = (tid >> 4) << 2;
    const int tc  = (tid & 15) << 2;
    const int lar = tid >> 2;
    const int lac = (tid & 3) << 2;
    const int lbr = tid >> 4;
    const int lbc = (tid & 15) << 2;

    float acc[4][4] = {{0.f}};

    for (int k0 = 0; k0 < K; k0 += BK) {
        const int gr = row0 + lar;
        const float* Ap = A + (size_t)gr * K + k0 + lac;
        #pragma unroll
        for (int i = 0; i < 4; ++i) {
            int gk = k0 + lac + i;
            As[lac + i][lar] = (gr < M && gk < K) ? Ap[i] : 0.f;
        }
        const int gk = k0 + lbr;
        const float* Bp = B + (size_t)gk * N + col0 + lbc;
        #pragma unroll
        for (int i = 0; i < 4; ++i) {
            int gc = col0 + lbc + i;
            Bs[lbr][lbc + i] = (gk < K && gc < N) ? Bp[i] : 0.f;
        }
        __syncthreads();
        #pragma unroll
        for (int kk = 0; kk < BK; ++kk) {
            float4 a = *reinterpret_cast<const float4*>(&As[kk][tr]);
            float4 b = *reinterpret_cast<const float4*>(&Bs[kk][tc]);
            acc[0][0] += a.x * b.x; acc[0][1] += a.x * b.y; acc[0][2] += a.x * b.z; acc[0][3] += a.x * b.w;
            acc[1][0] += a.y * b.x; acc[1][1] += a.y * b.y; acc[1][2] += a.y * b.z; acc[1][3] += a.y * b.w;
            acc[2][0] += a.z * b.x; acc[2][1] += a.z * b.y; acc[2][2] += a.z * b.z; acc[2][3] += a.z * b.w;
            acc[3][0] += a.w * b.x; acc[3][1] += a.w * b.y; acc[3][2] += a.w * b.z; acc[3][3] += a.w * b.w;
        }
        __syncthreads();
    }

    #pragma unroll
    for (int i = 0; i < 4; ++i) {
        int gr = row0 + tr + i;
        if (gr >= M) continue;
        float rs = rowScale ? rowScale[gr] : 1.0f;
        #pragma unroll
        for (int j = 0; j < 4; ++j) {
            int gc = col0 + tc + j;
            if (gc >= N) continue;
            float v = acc[i][j];
            if (bias) v += bias[gc];
            v *= rs;
            if (act == 1) v = tanhf(v);
            C[(size_t)gr * N + gc] = v;
        }
    }
}

// ---------------- bf16 MFMA GEMM: 128x128 tile, BK=32, 4 waves --------------
#define LDT 40

__global__ __launch_bounds__(256) void mfma_gemm_kernel(
    const ushort* __restrict__ A, const ushort* __restrict__ Bt,
    int M, int Nw, int K, int lda,
    const float* __restrict__ bias, const float* __restrict__ rowScale,
    float* __restrict__ outF, ushort* __restrict__ outB, ushort* __restrict__ outLo,
    int ldo)
{
    __shared__ __align__(16) ushort As[128 * LDT];
    __shared__ __align__(16) ushort Bs[128 * LDT];
    const int tid  = threadIdx.x;
    int bx = blockIdx.x, by = blockIdx.y;
    xcd_swizzle(gridDim.x, gridDim.y, bx, by);
    const int row0 = by * 128;
    const int col0 = bx * 128;
    const int wid  = tid >> 6, lane = tid & 63;
    const int wr = wid >> 1, wc = wid & 1;
    const int l15 = lane & 15, lg = lane >> 4;
    const int kg = lg * 4;
    const int sr = tid >> 2;
    const int sc = (tid & 3) * 8;

    f32x4 acc[4][4];
    #pragma unroll
    for (int m = 0; m < 4; ++m)
        #pragma unroll
        for (int n = 0; n < 4; ++n) acc[m][n] = (f32x4)0.f;

    for (int k0 = 0; k0 < K; k0 += 32) {
        const ushort* ga0 = A  + (size_t)(row0 + sr)      * lda + k0 + sc;
        const ushort* ga1 = A  + (size_t)(row0 + sr + 64) * lda + k0 + sc;
        const ushort* gb0 = Bt + (size_t)(col0 + sr)      * lda + k0 + sc;
        const ushort* gb1 = Bt + (size_t)(col0 + sr + 64) * lda + k0 + sc;
        *reinterpret_cast<uint4*>(&As[sr * LDT + sc])        = *reinterpret_cast<const uint4*>(ga0);
        *reinterpret_cast<uint4*>(&As[(sr + 64) * LDT + sc]) = *reinterpret_cast<const uint4*>(ga1);
        *reinterpret_cast<uint4*>(&Bs[sr * LDT + sc])        = *reinterpret_cast<const uint4*>(gb0);
        *reinterpret_cast<uint4*>(&Bs[(sr + 64) * LDT + sc]) = *reinterpret_cast<const uint4*>(gb1);
        __syncthreads();

        bf16x8v af[4], bfr[4];
        #pragma unroll
        for (int m = 0; m < 4; ++m) {
            int ar = wr * 64 + m * 16 + l15;
            bf16x4v lo = *reinterpret_cast<const bf16x4v*>(&As[ar * LDT + kg]);
            bf16x4v hi = *reinterpret_cast<const bf16x4v*>(&As[ar * LDT + kg + 16]);
            af[m] = __builtin_shufflevector(lo, hi, 0, 1, 2, 3, 4, 5, 6, 7);
        }
        #pragma unroll
        for (int n = 0; n < 4; ++n) {
            int br = wc * 64 + n * 16 + l15;
            bf16x4v lo = *reinterpret_cast<const bf16x4v*>(&Bs[br * LDT + kg]);
            bf16x4v hi = *reinterpret_cast<const bf16x4v*>(&Bs[br * LDT + kg + 16]);
            bfr[n] = __builtin_shufflevector(lo, hi, 0, 1, 2, 3, 4, 5, 6, 7);
        }
        #pragma unroll
        for (int m = 0; m < 4; ++m)
            #pragma unroll
            for (int n = 0; n < 4; ++n)
                acc[m][n] = __builtin_amdgcn_mfma_f32_16x16x32_bf16(af[m], bfr[n], acc[m][n], 0, 0, 0);
        __syncthreads();
    }

    #pragma unroll
    for (int m = 0; m < 4; ++m) {
        int grow_base = row0 + wr * 64 + m * 16 + kg;
        #pragma unroll
        for (int j = 0; j < 4; ++j) {
            int grow = grow_base + j;
            if (grow >= M) continue;
            float rs = rowScale ? rowScale[grow] : 1.0f;
            #pragma unroll
            for (int n = 0; n < 4; ++n) {
                int gcol = col0 + wc * 64 + n * 16 + l15;
                if (gcol >= Nw) continue;
                float v = acc[m][n][j];
                if (bias) v += bias[gcol];
                v *= rs;
                if (outB) {
                    ushort h = f2bf(v);
                    outB[(size_t)grow * ldo + gcol] = h;
                    if (outLo) {
                        float hv = __uint_as_float(((uint32_t)h) << 16);
                        outLo[(size_t)grow * ldo + gcol] = f2bf(v - hv);
                    }
                } else {
                    outF[(size_t)grow * ldo + gcol] = v;
                }
            }
        }
    }
}

// ---------------- C3: A = relu(bufM*scale+shift) staged f32->bf16, K=256 ----
__global__ __launch_bounds__(256) void mfma_c3_kernel(
    const float* __restrict__ Abuf, const ushort* __restrict__ Bt,
    int M, int Nw,
    const float* __restrict__ scale, const float* __restrict__ shift,
    float* __restrict__ outF, int ldo)
{
    __shared__ __align__(16) ushort As[128 * LDT];
    __shared__ __align__(16) ushort Bs[128 * LDT];
    const int tid  = threadIdx.x;
    int bx = blockIdx.x, by = blockIdx.y;
    xcd_swizzle(gridDim.x, gridDim.y, bx, by);
    const int row0 = by * 128;
    const int col0 = bx * 128;
    const int wid  = tid >> 6, lane = tid & 63;
    const int wr = wid >> 1, wc = wid & 1;
    const int l15 = lane & 15, lg = lane >> 4;
    const int kg = lg * 4;
    const int sr = tid >> 2;
    const int sc = (tid & 3) * 8;

    f32x4 acc[4][4];
    #pragma unroll
    for (int m = 0; m < 4; ++m)
        #pragma unroll
        for (int n = 0; n < 4; ++n) acc[m][n] = (f32x4)0.f;

    for (int k0 = 0; k0 < 256; k0 += 32) {
        float sc8[8], sh8[8];
        #pragma unroll
        for (int i = 0; i < 8; ++i) { sc8[i] = scale[k0 + sc + i]; sh8[i] = shift[k0 + sc + i]; }
        #pragma unroll
        for (int half = 0; half < 2; ++half) {
            const float* ga = Abuf + (size_t)(row0 + sr + half * 64) * 256 + k0 + sc;
            float4 v0 = *reinterpret_cast<const float4*>(ga);
            float4 v1 = *reinterpret_cast<const float4*>(ga + 4);
            ushort h[8];
            h[0] = f2bf(fmaxf(v0.x * sc8[0] + sh8[0], 0.f));
            h[1] = f2bf(fmaxf(v0.y * sc8[1] + sh8[1], 0.f));
            h[2] = f2bf(fmaxf(v0.z * sc8[2] + sh8[2], 0.f));
            h[3] = f2bf(fmaxf(v0.w * sc8[3] + sh8[3], 0.f));
            h[4] = f2bf(fmaxf(v1.x * sc8[4] + sh8[4], 0.f));
            h[5] = f2bf(fmaxf(v1.y * sc8[5] + sh8[5], 0.f));
            h[6] = f2bf(fmaxf(v1.z * sc8[6] + sh8[6], 0.f));
            h[7] = f2bf(fmaxf(v1.w * sc8[7] + sh8[7], 0.f));
            *reinterpret_cast<uint4*>(&As[(sr + half * 64) * LDT + sc]) =
                *reinterpret_cast<const uint4*>(h);
        }
        const ushort* gb0 = Bt + (size_t)(col0 + sr)      * 256 + k0 + sc;
        const ushort* gb1 = Bt + (size_t)(col0 + sr + 64) * 256 + k0 + sc;
        *reinterpret_cast<uint4*>(&Bs[sr * LDT + sc])        = *reinterpret_cast<const uint4*>(gb0);
        *reinterpret_cast<uint4*>(&Bs[(sr + 64) * LDT + sc]) = *reinterpret_cast<const uint4*>(gb1);
        __syncthreads();

        bf16x8v af[4], bfr[4];
        #pragma unroll
        for (int m = 0; m < 4; ++m) {
            int ar = wr * 64 + m * 16 + l15;
            bf16x4v lo = *reinterpret_cast<const bf16x4v*>(&As[ar * LDT + kg]);
            bf16x4v hi = *reinterpret_cast<const bf16x4v*>(&As[ar * LDT + kg + 16]);
            af[m] = __builtin_shufflevector(lo, hi, 0, 1, 2, 3, 4, 5, 6, 7);
        }
        #pragma unroll
        for (int n = 0; n < 4; ++n) {
            int br = wc * 64 + n * 16 + l15;
            bf16x4v lo = *reinterpret_cast<const bf16x4v*>(&Bs[br * LDT + kg]);
            bf16x4v hi = *reinterpret_cast<const bf16x4v*>(&Bs[br * LDT + kg + 16]);
            bfr[n] = __builtin_shufflevector(lo, hi, 0, 1, 2, 3, 4, 5, 6, 7);
        }
        #pragma unroll
        for (int m = 0; m < 4; ++m)
            #pragma unroll
            for (int n = 0; n < 4; ++n)
                acc[m][n] = __builtin_amdgcn_mfma_f32_16x16x32_bf16(af[m], bfr[n], acc[m][n], 0, 0, 0);
        __syncthreads();
    }

    #pragma unroll
    for (int m = 0; m < 4; ++m) {
        int grow_base = row0 + wr * 64 + m * 16 + kg;
        #pragma unroll
        for (int j = 0; j < 4; ++j) {
            int grow = grow_base + j;
            if (grow >= M) continue;
            #pragma unroll
            for (int n = 0; n < 4; ++n) {
                int gcol = col0 + wc * 64 + n * 16 + l15;
                if (gcol >= Nw) continue;
                outF[(size_t)grow * ldo + gcol] = acc[m][n][j];
            }
        }
    }
}

// ---------------- split-K MFMA: partials (f32), grid.z = K-chunk ------------
__global__ __launch_bounds__(256) void mfma_splitk_kernel(
    const ushort* __restrict__ A, const ushort* __restrict__ Bt,
    int M, int K, int lda, int kChunk, int Ntot,
    float* __restrict__ part)
{
    __shared__ __align__(16) ushort As[128 * LDT];
    __shared__ __align__(16) ushort Bs[128 * LDT];
    const int tid  = threadIdx.x;
    const int row0 = blockIdx.y * 128;
    const int col0 = blockIdx.x * 128;
    const int wid  = tid >> 6, lane = tid & 63;
    const int wr = wid >> 1, wc = wid & 1;
    const int l15 = lane & 15, lg = lane >> 4;
    const int kg = lg * 4;
    const int sr = tid >> 2;
    const int sc = (tid & 3) * 8;

    const int k0s = blockIdx.z * kChunk;
    const int k0e = (k0s + kChunk < K) ? k0s + kChunk : K;

    f32x4 acc[4][4];
    #pragma unroll
    for (int m = 0; m < 4; ++m)
        #pragma unroll
        for (int n = 0; n < 4; ++n) acc[m][n] = (f32x4)0.f;

    for (int k0 = k0s; k0 < k0e; k0 += 32) {
        const ushort* ga0 = A  + (size_t)(row0 + sr)      * lda + k0 + sc;
        const ushort* ga1 = A  + (size_t)(row0 + sr + 64) * lda + k0 + sc;
        const ushort* gb0 = Bt + (size_t)(col0 + sr)      * lda + k0 + sc;
        const ushort* gb1 = Bt + (size_t)(col0 + sr + 64) * lda + k0 + sc;
        *reinterpret_cast<uint4*>(&As[sr * LDT + sc])        = *reinterpret_cast<const uint4*>(ga0);
        *reinterpret_cast<uint4*>(&As[(sr + 64) * LDT + sc]) = *reinterpret_cast<const uint4*>(ga1);
        *reinterpret_cast<uint4*>(&Bs[sr * LDT + sc])        = *reinterpret_cast<const uint4*>(gb0);
        *reinterpret_cast<uint4*>(&Bs[(sr + 64) * LDT + sc]) = *reinterpret_cast<const uint4*>(gb1);
        __syncthreads();

        bf16x8v af[4], bfr[4];
        #pragma unroll
        for (int m = 0; m < 4; ++m) {
            int ar = wr * 64 + m * 16 + l15;
            bf16x4v lo = *reinterpret_cast<const bf16x4v*>(&As[ar * LDT + kg]);
            bf16x4v hi = *reinterpret_cast<const bf16x4v*>(&As[ar * LDT + kg + 16]);
            af[m] = __builtin_shufflevector(lo, hi, 0, 1, 2, 3, 4, 5, 6, 7);
        }
        #pragma unroll
        for (int n = 0; n < 4; ++n) {
            int br = wc * 64 + n * 16 + l15;
            bf16x4v lo = *reinterpret_cast<const bf16x4v*>(&Bs[br * LDT + kg]);
            bf16x4v hi = *reinterpret_cast<const bf16x4v*>(&Bs[br * LDT + kg + 16]);
            bfr[n] = __builtin_shufflevector(lo, hi, 0, 1, 2, 3, 4, 5, 6, 7);
        }
        #pragma unroll
        for (int m = 0; m < 4; ++m)
            #pragma unroll
            for (int n = 0; n < 4; ++n)
                acc[m][n] = __builtin_amdgcn_mfma_f32_16x16x32_bf16(af[m], bfr[n], acc[m][n], 0, 0, 0);
        __syncthreads();
    }

    float* pslab = part + (size_t)blockIdx.z * M * Ntot;
    #pragma unroll
    for (int m = 0; m < 4; ++m) {
        int grow_base = row0 + wr * 64 + m * 16 + kg;
        #pragma unroll
        for (int j = 0; j < 4; ++j) {
            int grow = grow_base + j;
            if (grow >= M) continue;
            #pragma unroll
            for (int n = 0; n < 4; ++n) {
                int gcol = col0 + wc * 64 + n * 16 + l15;
                pslab[(size_t)grow * Ntot + gcol] = acc[m][n][j];
            }
        }
    }
}

__global__ void reduce_tanh_kernel(const float* __restrict__ part, int S, int M, int N,
                                   const float* __restrict__ rs, float* __restrict__ out) {
    int i = blockIdx.x * blockDim.x + threadIdx.x;
    if (i >= M * N) return;
    int r = i / N;
    float s = 0.f;
    for (int z = 0; z < S; ++z) s += part[(size_t)z * M * N + i];
    if (rs) s *= rs[r];
    out[i] = tanhf(s);
}

// ---------------- conversion / fusion helpers -------------------------------
__global__ void transpose_cvt_kernel(const float* __restrict__ in, int K, int N, int ldin,
                                     ushort* __restrict__ out, int Kp) {
    int i = blockIdx.x * blockDim.x + threadIdx.x;
    if (i >= N * Kp) return;
    int n = i / Kp, k = i % Kp;
    float v = (k < K) ? in[(size_t)k * ldin + n] : 0.f;
    out[i] = f2bf(v);
}

__global__ void make_cat_weights_kernel(
    const float* __restrict__ w_sh1, const float* __restrict__ w_sh1h,
    const float* __restrict__ b_sh1, const float* __restrict__ b_sh1h,
    const float* __restrict__ w_sh2, const float* __restrict__ w_sh2h,
    const float* __restrict__ b_sh2, const float* __restrict__ b_sh2h,
    const float* __restrict__ w_mlp1, const float* __restrict__ w_mlp1h,
    const float* __restrict__ b_mlp1, const float* __restrict__ b_mlp1h,
    float* __restrict__ W1cat, float* __restrict__ b1cat,
    float* __restrict__ W2bd,  float* __restrict__ b2cat,
    float* __restrict__ WMbd,  float* __restrict__ bMcat)
{
    int i = blockIdx.x * blockDim.x + threadIdx.x;
    if (i < 64 * 128) {
        int k = i >> 7, j = i & 127;
        W1cat[i] = (j < 64) ? w_sh1[k * 64 + j] : w_sh1h[k * 64 + (j - 64)];
        return;
    }
    i -= 64 * 128;
    if (i < 128) { b1cat[i] = (i < 64) ? b_sh1[i] : b_sh1h[i - 64]; return; }
    i -= 128;
    if (i < 128 * 128) {
        int k = i >> 7, j = i & 127;
        float v = 0.f;
        if (k < 64 && j < 64) v = w_sh2[k * 64 + j];
        else if (k >= 64 && j >= 64) v = w_sh2h[(k - 64) * 64 + (j - 64)];
        W2bd[i] = v;
        return;
    }
    i -= 128 * 128;
    if (i < 128) { b2cat[i] = (i < 64) ? b_sh2[i] : b_sh2h[i - 64]; return; }
    i -= 128;
    if (i < 128 * 512) {
        int k = i >> 9, j = i & 511;
        float v = 0.f;
        if (j < 256) { if (k < 64) v = w_mlp1[k * 256 + j]; }
        else         { if (k >= 64) v = w_mlp1h[(k - 64) * 256 + (j - 256)]; }
        WMbd[i] = v;
        return;
    }
    i -= 128 * 512;
    if (i < 512) { bMcat[i] = (i < 256) ? b_mlp1[i] : b_mlp1h[i - 256]; }
}

__global__ void avg3cat_kernel(const float* __restrict__ emb, const float* __restrict__ x2cat,
                               const float* __restrict__ x6cat, float* __restrict__ o) {
    int i = blockIdx.x * blockDim.x + threadIdx.x;
    if (i >= N_SH * 128) return;
    int r = i >> 7, j = i & 127;
    o[i] = (emb[r * 64 + (j & 63)] + x2cat[i] + x6cat[i]) * (1.0f / 3.0f);
}

__global__ void concat_hh_kernel(const float* __restrict__ emb, const float* __restrict__ kg,
                                 float* __restrict__ out) {
    int i = blockIdx.x * blockDim.x + threadIdx.x;
    const int n = N_HH * 91;
    if (i >= n) return;
    int r = i / 91, c = i % 91;
    out[i] = (c < DIM) ? emb[r * DIM + c] : kg[r * 27 + (c - DIM)];
}

__global__ void make_esbt_kernel(const float* __restrict__ x9cat, const float* __restrict__ ss1,
                                 ushort* __restrict__ out, int Kp) {
    int i = blockIdx.x * blockDim.x + threadIdx.x;
    if (i >= 256 * Kp) return;
    int n = i / Kp, k = i % Kp;
    float v = (k < N_SS) ? (x9cat[(size_t)k * 512 + n] + ss1[(size_t)k * 256 + n]) : 0.f;
    out[i] = f2bf(v);
}

__global__ void make_wmlp2_kernel(const float* __restrict__ wm, ushort* __restrict__ out) {
    int i = blockIdx.x * blockDim.x + threadIdx.x;
    if (i >= 256 * 512) return;
    int n = i >> 9, k = i & 511;
    out[i] = f2bf(wm[(size_t)(k & 255) * 256 + n]);
}

__global__ void make_ehb_kernel(const float* __restrict__ x9cat, const float* __restrict__ hh1,
                                ushort* __restrict__ out, int Rp) {
    int i = blockIdx.x * blockDim.x + threadIdx.x;
    if (i >= Rp * 256) return;
    int r = i >> 8, c = i & 255;
    float v = (r < N_HH) ? (x9cat[(size_t)(N_SS + r) * 512 + 256 + c] + hh1[(size_t)r * 256 + c]) : 0.f;
    out[i] = f2bf(v);
}

// ---------------- BatchNorm -------------------------------------------------
__global__ void bn_stats_cat_kernel(const float* __restrict__ X, int M,
                                    float* __restrict__ stats) {
    int j = threadIdx.x;  // 512
    float s = 0.f, ss = 0.f;
    for (int r = blockIdx.x; r < M; r += gridDim.x) {
        float v = X[(size_t)r * 512 + j];
        s += v; ss += v * v;
    }
    atomicAdd(&stats[j], s);
    atomicAdd(&stats[512 + j], ss);
}

__global__ void bn_apply_cat_kernel(const float* __restrict__ X, const float* __restrict__ stats,
                                    const float* __restrict__ g1, const float* __restrict__ be1,
                                    const float* __restrict__ g2, const float* __restrict__ be2,
                                    int M, float* __restrict__ out) {
    int i = blockIdx.x * blockDim.x + threadIdx.x;
    if (i >= M * 512) return;
    int j = i & 511;
    float invM = 1.0f / (float)M;
    float mean = stats[j] * invM;
    float var  = fmaxf(stats[512 + j] * invM - mean * mean, 0.f);
    float ga = (j < 256) ? g1[j]  : g2[j - 256];
    float bb = (j < 256) ? be1[j] : be2[j - 256];
    float y = (X[i] - mean) * rsqrtf(var + 1e-5f) * ga + bb;
    out[i] = tanhf(y);
}

__global__ void bn_stats_kernel(const float* __restrict__ X, int M,
                                float* __restrict__ stats) {
    int j = threadIdx.x;
    float s = 0.f, ss = 0.f;
    for (int r = blockIdx.x; r < M; r += gridDim.x) {
        float v = X[(size_t)r * 256 + j];
        s += v; ss += v * v;
    }
    atomicAdd(&stats[j], s);
    atomicAdd(&stats[256 + j], ss);
}

__global__ void bn_finalize_kernel(const float* __restrict__ stats,
                                   const float* __restrict__ g, const float* __restrict__ be,
                                   int M, float* __restrict__ scale, float* __restrict__ shift) {
    int j = threadIdx.x;  // 256
    float invM = 1.0f / (float)M;
    float mean = stats[j] * invM;
    float var  = fmaxf(stats[256 + j] * invM - mean * mean, 0.f);
    float sc = g[j] * rsqrtf(var + 1e-5f);
    scale[j] = sc;
    shift[j] = be[j] - mean * sc;
}

// ---------------- driver -----------------------------------------------------
extern "C" void kernel_launch(void* const* d_in, const int* in_sizes, int n_in,
                              void* d_out, int out_size, void* d_ws, size_t ws_size,
                              hipStream_t stream) {
    const int*   eiSH = (const int*)d_in[1];
    const int*   eiSS = (const int*)d_in[3];
    const int*   eiHH = (const int*)d_in[5];
    const float* P    = (const float*)d_in[6];
    const float* kg   = (const float*)d_in[7];
    const float* emb  = (const float*)d_in[8];
    const float* w_sh1  = (const float*)d_in[9];   const float* b_sh1  = (const float*)d_in[10];
    const float* w_sh2  = (const float*)d_in[11];  const float* b_sh2  = (const float*)d_in[12];
    const float* w_mlp1 = (const float*)d_in[13];  const float* b_mlp1 = (const float*)d_in[14];
    const float* g_bn1  = (const float*)d_in[15];  const float* be_bn1 = (const float*)d_in[16];
    const float* w_sh1h = (const float*)d_in[17];  const float* b_sh1h = (const float*)d_in[18];
    const float* w_sh2h = (const float*)d_in[19];  const float* b_sh2h = (const float*)d_in[20];
    const float* w_mlp1h= (const float*)d_in[21];  const float* b_mlp1h= (const float*)d_in[22];
    const float* g_bn1h = (const float*)d_in[23];  const float* be_bn1h= (const float*)d_in[24];
    const float* w_ss   = (const float*)d_in[25];  const float* b_ss   = (const float*)d_in[26];
    const float* w_hh   = (const float*)d_in[27];  const float* b_hh   = (const float*)d_in[28];
    const float* w_mlp  = (const float*)d_in[29];  const float* b_mlp  = (const float*)d_in[30];
    const float* g_si   = (const float*)d_in[31];  const float* be_si  = (const float*)d_in[32];
    float* out = (float*)d_out;

    const int E_SH = in_sizes[1] / 2;
    const int E_SS = in_sizes[3] / 2;
    const int E_HH = in_sizes[5] / 2;
    const int B    = in_sizes[6] / N_SS;      // 20000
    const int Mp   = ((B + 127) / 128) * 128; // 20096
    const int KP1  = 416;
    const int NP3  = 896;
    const int KSH  = 1216;
    const int KHH  = 832;
    const int NB_SH = (N_SH + RPB - 1) / RPB;   // 86
    const int NB_SS = (N_SS + RPB - 1) / RPB;   // 28
    const int NB_HH = (N_HH + RPB - 1) / RPB;   // 58

    float* w = (float*)d_ws;
    size_t off = 0;
    auto alloc = [&](size_t n) { float* p = w + off; off += (n + 3) & ~(size_t)3; return p; };

    float* cntInv  = alloc(N_SH);
    float* presInv = alloc(B);
    float* stats   = alloc(1024);
    float* bnScale = alloc(256);
    float* bnShift = alloc(256);
    float* W1cat   = alloc(64 * 128);
    float* b1cat   = alloc(128);
    float* W2bd    = alloc(128 * 128);
    float* b2cat   = alloc(128);
    float* WMbd    = alloc(128 * 512);
    float* bMcat   = alloc(512);
    // bf16 adjacencies + bucket counters: contiguous -> single memset
    ushort* adjb   = (ushort*)alloc((size_t)1280 * KSH / 2);
    ushort* adjSSb = (ushort*)alloc((size_t)512 * KP1 / 2);
    ushort* adjHHb = (ushort*)alloc((size_t)896 * KHH / 2);
    uint32_t* bctr = (uint32_t*)alloc(1024);      // [0,172) cnt | +256 base | +512 cursor
    size_t memset_bytes = ((size_t)1280 * KSH + (size_t)512 * KP1 + (size_t)896 * KHH) * 2
                          + 1024 * sizeof(float);
    float* tmpL    = alloc((size_t)N_SH * 128);
    ushort* HT     = (ushort*)alloc((size_t)128 * KSH / 2);
    float* x2cat   = alloc((size_t)N_SH * 128);
    float* x6cat   = alloc((size_t)N_SH * 128);
    float* x9a2    = alloc((size_t)N_SH * 128);
    float* tmpBN   = alloc((size_t)N_SH * 512);
    float* x9cat   = alloc((size_t)N_SH * 512);
    float* ss1     = alloc((size_t)N_SS * 256);
    float* hh1     = alloc((size_t)N_HH * 256);
    float* xhh0    = alloc((size_t)N_HH * 91);
    ushort* HSST   = (ushort*)alloc((size_t)256 * KP1 / 2);
    ushort* HHHT   = (ushort*)alloc((size_t)256 * KHH / 2);
    ushort* es_bT  = (ushort*)alloc((size_t)256 * KP1 / 2);
    ushort* wmlp2  = (ushort*)alloc((size_t)256 * 512 / 2);
    ushort* eh_b   = (ushort*)alloc((size_t)NP3 * 256 / 2);
    // region A: P_b bf16 [Mp][416] -> bufM f32 [Mp][256]
    float* regionA = alloc((size_t)Mp * 256);
    ushort* P_b    = (ushort*)regionA;
    float*  bufM   = regionA;
    // region B: binned cells (build) -> split-K partials -> e_hilo bf16 [Mp][512]
    float* regionB = alloc((size_t)Mp * 256);
    uint32_t* binnedSH = (uint32_t*)regionB;
    uint32_t* binnedSS = binnedSH + E_SH;
    uint32_t* binnedHH = binnedSS + E_SS;
    float*  partials = regionB;
    ushort* e_hilo = (ushort*)regionB;
    (void)ws_size; (void)n_in; (void)out_size;

    auto gemm = [&](const float* Am, const float* Bm, const float* bias, const float* rs,
                    float* C, int M, int N, int K, int act) {
        dim3 g((N + BN - 1) / BN, (M + BM - 1) / BM);
        gemm_kernel<<<g, 256, 0, stream>>>(Am, Bm, bias, rs, C, M, N, K, act);
    };
    auto mgemm = [&](const ushort* Am, const ushort* Bm, int M, int Np, int Nw, int K, int lda,
                     const float* bias, const float* rs,
                     float* oF, ushort* oB, ushort* oLo, int ldo) {
        dim3 g(Np / 128, (M + 127) / 128);
        mfma_gemm_kernel<<<g, 256, 0, stream>>>(Am, Bm, M, Nw, K, lda, bias, rs, oF, oB, oLo, ldo);
    };
    auto splitk = [&](const ushort* Am, const ushort* Bm, int M, int Mtiles, int K, int lda,
                      int Ntot, int S, const float* rs, float* outp) {
        dim3 g(Ntot / 128, Mtiles, S);
        mfma_splitk_kernel<<<g, 256, 0, stream>>>(Am, Bm, M, K, lda, 128, Ntot, partials);
        reduce_tanh_kernel<<<(M * Ntot + 255) / 256, 256, 0, stream>>>(partials, S, M, Ntot, rs, outp);
    };

    // ---- adjacency: binned histogram build (bf16 direct) ----
    hipMemsetAsync(adjb, 0, memset_bytes, stream);
    bucket_count_kernel<<<256, 256, 0, stream>>>(eiSH, E_SH, NB_SH, bctr + 0);
    bucket_count_kernel<<<256, 256, 0, stream>>>(eiSS, E_SS, NB_SS, bctr + 86);
    bucket_count_kernel<<<256, 256, 0, stream>>>(eiHH, E_HH, NB_HH, bctr + 114);
    bucket_scan_kernel<<<1, 64, 0, stream>>>(bctr);
    bucket_scatter_kernel<<<(E_SH + 4095) / 4096, 256, 0, stream>>>(eiSH, E_SH, N_SH, bctr + 512 + 0,   binnedSH);
    bucket_scatter_kernel<<<(E_SS + 4095) / 4096, 256, 0, stream>>>(eiSS, E_SS, N_SS, bctr + 512 + 86,  binnedSS);
    bucket_scatter_kernel<<<(E_HH + 4095) / 4096, 256, 0, stream>>>(eiHH, E_HH, N_HH, bctr + 512 + 114, binnedHH);
    hist_write_kernel<<<NB_SH, 256, RPB * N_SH * 4, stream>>>(binnedSH, bctr + 0,   bctr + 256 + 0,   N_SH, KSH, adjb,   cntInv);
    hist_write_kernel<<<NB_SS, 256, RPB * N_SS * 4, stream>>>(binnedSS, bctr + 86,  bctr + 256 + 86,  N_SS, KP1, adjSSb, nullptr);
    hist_write_kernel<<<NB_HH, 256, RPB * N_HH * 4, stream>>>(binnedHH, bctr + 114, bctr + 256 + 114, N_HH, KHH, adjHHb, nullptr);

    make_cat_weights_kernel<<<(90880 + 255) / 256, 256, 0, stream>>>(
        w_sh1, w_sh1h, b_sh1, b_sh1h, w_sh2, w_sh2h, b_sh2, b_sh2h,
        w_mlp1, w_mlp1h, b_mlp1, b_mlp1h,
        W1cat, b1cat, W2bd, b2cat, WMbd, bMcat);

    // ---- SH layers (fused branches) ----
    gemm(emb, W1cat, b1cat, nullptr, tmpL, N_SH, 128, 64, 0);
    transpose_cvt_kernel<<<(128 * KSH + 255) / 256, 256, 0, stream>>>(tmpL, N_SH, 128, 128, HT, KSH);
    splitk(adjb, HT, N_SH, 10, KSH, KSH, 128, 10, cntInv, x2cat);
    gemm(x2cat, W2bd, b2cat, nullptr, tmpL, N_SH, 128, 128, 0);
    transpose_cvt_kernel<<<(128 * KSH + 255) / 256, 256, 0, stream>>>(tmpL, N_SH, 128, 128, HT, KSH);
    splitk(adjb, HT, N_SH, 10, KSH, KSH, 128, 10, cntInv, x6cat);
    avg3cat_kernel<<<(N_SH * 128 + 255) / 256, 256, 0, stream>>>(emb, x2cat, x6cat, x9a2);
    gemm(x9a2, WMbd, bMcat, nullptr, tmpBN, N_SH, 512, 128, 0);
    hipMemsetAsync(stats, 0, 1024 * sizeof(float), stream);
    bn_stats_cat_kernel<<<64, 512, 0, stream>>>(tmpBN, N_SH, stats);
    bn_apply_cat_kernel<<<(N_SH * 512 + 255) / 256, 256, 0, stream>>>(
        tmpBN, stats, g_bn1, be_bn1, g_bn1h, be_bn1h, N_SH, x9cat);

    // ---- SS graph ----
    gemm(emb, w_ss, b_ss, nullptr, tmpBN, N_SS, 256, 64, 0);
    transpose_cvt_kernel<<<(256 * KP1 + 255) / 256, 256, 0, stream>>>(tmpBN, N_SS, 256, 256, HSST, KP1);
    splitk(adjSSb, HSST, N_SS, 4, KP1, KP1, 256, 4, nullptr, ss1);

    // ---- HH graph ----
    concat_hh_kernel<<<(N_HH * 91 + 255) / 256, 256, 0, stream>>>(emb, kg, xhh0);
    gemm(xhh0, w_hh, b_hh, nullptr, tmpBN, N_HH, 256, 91, 0);
    transpose_cvt_kernel<<<(256 * KHH + 255) / 256, 256, 0, stream>>>(tmpBN, N_HH, 256, 256, HHHT, KHH);
    splitk(adjHHb, HHHT, N_HH, 7, KHH, KHH, 256, 7, nullptr, hh1);

    // ---- prepare bf16 operands for prescription path ----
    make_esbt_kernel<<<(256 * KP1 + 255) / 256, 256, 0, stream>>>(x9cat, ss1, es_bT, KP1);
    make_wmlp2_kernel<<<(256 * 512 + 255) / 256, 256, 0, stream>>>(w_mlp, wmlp2);
    make_ehb_kernel<<<(NP3 * 256 + 255) / 256, 256, 0, stream>>>(x9cat, hh1, eh_b, NP3);
    cvt_rowsum_p_kernel<<<B, 128, 0, stream>>>(P, P_b, presInv);

    // ---- prescription path (bf16 MFMA) ----
    mgemm(P_b, es_bT, B, 256, 256, KP1, KP1, nullptr, presInv,
          nullptr, e_hilo, e_hilo + 256, 512);
    mgemm(e_hilo, wmlp2, B, 256, 256, 512, 512, b_mlp, nullptr,
          bufM, nullptr, nullptr, 256);
    hipMemsetAsync(stats, 0, 512 * sizeof(float), stream);
    bn_stats_kernel<<<256, 256, 0, stream>>>(bufM, B, stats);
    bn_finalize_kernel<<<1, 256, 0, stream>>>(stats, g_si, be_si, B, bnScale, bnShift);
    {
        dim3 g(NP3 / 128, (B + 127) / 128);
        mfma_c3_kernel<<<g, 256, 0, stream>>>(bufM, eh_b, B, N_HH, bnScale, bnShift, out, N_HH);
    }
}

// Round 7
// 377.217 us; speedup vs baseline: 1.1888x; 1.1888x over previous
//
#include <hip/hip_runtime.h>
#include <cstddef>
#include <cstdint>

#define N_SH 1195
#define N_SS 390
#define N_HH 805
#define DIM  64

typedef __bf16 bf16_t;
typedef bf16_t bf16x4v __attribute__((ext_vector_type(4)));
typedef bf16_t bf16x8v __attribute__((ext_vector_type(8)));
typedef float f32x4 __attribute__((ext_vector_type(4)));

__device__ inline ushort f2bf(float f) {
    union { float f; uint32_t u; } c; c.f = f;
    uint32_t u = c.u;
    u += 0x7FFFu + ((u >> 16) & 1u);
    return (ushort)(u >> 16);
}

// bijective XCD swizzle (m204)
__device__ inline void xcd_swizzle(int gx, int gy, int& bx, int& by) {
    int nwg = gx * gy;
    int lin = by * gx + bx;
    int q = nwg >> 3, r = nwg & 7;
    int xcd = lin & 7, idx = lin >> 3;
    int nt = (xcd < r ? xcd * (q + 1) : r * (q + 1) + (xcd - r) * q) + idx;
    by = nt / gx; bx = nt % gx;
}

// ---------------- adjacency build (naive atomic; counts exact) --------------
__global__ void build_adj_kernel(const int* __restrict__ ei, int E,
                                 float* __restrict__ A, int N) {
    int i = blockIdx.x * blockDim.x + threadIdx.x;
    if (i < E) {
        int src = ei[i];
        int dst = ei[E + i];
        atomicAdd(&A[(size_t)dst * N + src], 1.0f);
    }
}

__global__ void rowsum_inv_kernel(const float* __restrict__ X, int M, int K,
                                  float* __restrict__ inv, int use_max1) {
    int row  = blockIdx.x * (blockDim.x / 64) + (threadIdx.x / 64);
    int lane = threadIdx.x & 63;
    if (row >= M) return;
    const float* p = X + (size_t)row * K;
    float s = 0.f;
    for (int c = lane; c < K; c += 64) s += p[c];
    for (int off = 32; off > 0; off >>= 1) s += __shfl_down(s, off);
    if (lane == 0) {
        float d = use_max1 ? fmaxf(s, 1.0f) : s;
        inv[row] = 1.0f / d;
    }
}

// f32 [R][C] -> bf16 [Rp][Cp], zero-padded
__global__ void cvt_pad2_kernel(const float* __restrict__ in, int R, int C,
                                ushort* __restrict__ out, int Rp, int Cp) {
    int i = blockIdx.x * blockDim.x + threadIdx.x;
    if (i >= Rp * Cp) return;
    int r = i / Cp, c = i % Cp;
    float v = (r < R && c < C) ? in[(size_t)r * C + c] : 0.f;
    out[i] = f2bf(v);
}

// P[r][0:390] f32 -> P_b[r][0:416] bf16 (zero-pad) + presInv[r] = 1/rowsum
__global__ __launch_bounds__(128) void cvt_rowsum_p_kernel(
    const float* __restrict__ P, ushort* __restrict__ Pb,
    float* __restrict__ presInv)
{
    __shared__ float red[2];
    const int r = blockIdx.x;
    const int tid = threadIdx.x;
    float s = 0.f;
    #pragma unroll
    for (int it = 0; it < 4; ++it) {
        int c = tid + it * 128;
        float v = 0.f;
        if (c < N_SS) { v = P[(size_t)r * N_SS + c]; s += v; }
        if (c < 416) Pb[(size_t)r * 416 + c] = f2bf(v);
    }
    for (int off = 32; off > 0; off >>= 1) s += __shfl_down(s, off);
    if ((tid & 63) == 0) red[tid >> 6] = s;
    __syncthreads();
    if (tid == 0) {
        float t = red[0] + red[1];
        presInv[r] = (t != 0.f) ? 1.0f / t : 0.f;
    }
}

// ---------------- fp32 GEMM (small dense layers) ----------------------------
#define BM 64
#define BN 64
#define BK 16

__global__ __launch_bounds__(256) void gemm_kernel(
    const float* __restrict__ A, const float* __restrict__ B,
    const float* __restrict__ bias, const float* __restrict__ rowScale,
    float* __restrict__ C, int M, int N, int K, int act)
{
    __shared__ float As[BK][BM + 4];
    __shared__ float Bs[BK][BN];
    const int tid  = threadIdx.x;
    const int row0 = blockIdx.y * BM;
    const int col0 = blockIdx.x * BN;
    const int tr  = (tid >> 4) << 2;
    const int tc  = (tid & 15) << 2;
    const int lar = tid >> 2;
    const int lac = (tid & 3) << 2;
    const int lbr = tid >> 4;
    const int lbc = (tid & 15) << 2;

    float acc[4][4] = {{0.f}};

    for (int k0 = 0; k0 < K; k0 += BK) {
        const int gr = row0 + lar;
        const float* Ap = A + (size_t)gr * K + k0 + lac;
        #pragma unroll
        for (int i = 0; i < 4; ++i) {
            int gk = k0 + lac + i;
            As[lac + i][lar] = (gr < M && gk < K) ? Ap[i] : 0.f;
        }
        const int gk = k0 + lbr;
        const float* Bp = B + (size_t)gk * N + col0 + lbc;
        #pragma unroll
        for (int i = 0; i < 4; ++i) {
            int gc = col0 + lbc + i;
            Bs[lbr][lbc + i] = (gk < K && gc < N) ? Bp[i] : 0.f;
        }
        __syncthreads();
        #pragma unroll
        for (int kk = 0; kk < BK; ++kk) {
            float4 a = *reinterpret_cast<const float4*>(&As[kk][tr]);
            float4 b = *reinterpret_cast<const float4*>(&Bs[kk][tc]);
            acc[0][0] += a.x * b.x; acc[0][1] += a.x * b.y; acc[0][2] += a.x * b.z; acc[0][3] += a.x * b.w;
            acc[1][0] += a.y * b.x; acc[1][1] += a.y * b.y; acc[1][2] += a.y * b.z; acc[1][3] += a.y * b.w;
            acc[2][0] += a.z * b.x; acc[2][1] += a.z * b.y; acc[2][2] += a.z * b.z; acc[2][3] += a.z * b.w;
            acc[3][0] += a.w * b.x; acc[3][1] += a.w * b.y; acc[3][2] += a.w * b.z; acc[3][3] += a.w * b.w;
        }
        __syncthreads();
    }

    #pragma unroll
    for (int i = 0; i < 4; ++i) {
        int gr = row0 + tr + i;
        if (gr >= M) continue;
        float rs = rowScale ? rowScale[gr] : 1.0f;
        #pragma unroll
        for (int j = 0; j < 4; ++j) {
            int gc = col0 + tc + j;
            if (gc >= N) continue;
            float v = acc[i][j];
            if (bias) v += bias[gc];
            v *= rs;
            if (act == 1) v = tanhf(v);
            C[(size_t)gr * N + gc] = v;
        }
    }
}

// ---------------- bf16 MFMA GEMM, 2-phase prefetch --------------------------
#define LDT 40

__global__ __launch_bounds__(256) void mfma_gemm_kernel(
    const ushort* __restrict__ A, const ushort* __restrict__ Bt,
    int M, int Nw, int K, int lda,
    const float* __restrict__ bias, const float* __restrict__ rowScale,
    float* __restrict__ outF, ushort* __restrict__ outB, ushort* __restrict__ outLo,
    int ldo, float* __restrict__ statsOut)
{
    __shared__ __align__(16) ushort As[128 * LDT];
    __shared__ __align__(16) ushort Bs[128 * LDT];
    __shared__ float cs[256];
    const int tid  = threadIdx.x;
    int bx = blockIdx.x, by = blockIdx.y;
    xcd_swizzle(gridDim.x, gridDim.y, bx, by);
    const int row0 = by * 128;
    const int col0 = bx * 128;
    const int wid  = tid >> 6, lane = tid & 63;
    const int wr = wid >> 1, wc = wid & 1;
    const int l15 = lane & 15, lg = lane >> 4;
    const int kg = lg * 4;
    const int sr = tid >> 2;
    const int sc = (tid & 3) * 8;

    const ushort* pA0 = A  + (size_t)(row0 + sr)      * lda + sc;
    const ushort* pA1 = A  + (size_t)(row0 + sr + 64) * lda + sc;
    const ushort* pB0 = Bt + (size_t)(col0 + sr)      * lda + sc;
    const ushort* pB1 = Bt + (size_t)(col0 + sr + 64) * lda + sc;

    uint4 ra0 = *reinterpret_cast<const uint4*>(pA0);
    uint4 ra1 = *reinterpret_cast<const uint4*>(pA1);
    uint4 rb0 = *reinterpret_cast<const uint4*>(pB0);
    uint4 rb1 = *reinterpret_cast<const uint4*>(pB1);

    f32x4 acc[4][4];
    #pragma unroll
    for (int m = 0; m < 4; ++m)
        #pragma unroll
        for (int n = 0; n < 4; ++n) acc[m][n] = (f32x4)0.f;

    for (int k0 = 0; k0 < K; k0 += 32) {
        *reinterpret_cast<uint4*>(&As[sr * LDT + sc])        = ra0;
        *reinterpret_cast<uint4*>(&As[(sr + 64) * LDT + sc]) = ra1;
        *reinterpret_cast<uint4*>(&Bs[sr * LDT + sc])        = rb0;
        *reinterpret_cast<uint4*>(&Bs[(sr + 64) * LDT + sc]) = rb1;
        __syncthreads();
        if (k0 + 32 < K) {   // prefetch next K-tile; latency hides under MFMA
            ra0 = *reinterpret_cast<const uint4*>(pA0 + k0 + 32);
            ra1 = *reinterpret_cast<const uint4*>(pA1 + k0 + 32);
            rb0 = *reinterpret_cast<const uint4*>(pB0 + k0 + 32);
            rb1 = *reinterpret_cast<const uint4*>(pB1 + k0 + 32);
        }

        bf16x8v af[4], bfr[4];
        #pragma unroll
        for (int m = 0; m < 4; ++m) {
            int ar = wr * 64 + m * 16 + l15;
            bf16x4v lo = *reinterpret_cast<const bf16x4v*>(&As[ar * LDT + kg]);
            bf16x4v hi = *reinterpret_cast<const bf16x4v*>(&As[ar * LDT + kg + 16]);
            af[m] = __builtin_shufflevector(lo, hi, 0, 1, 2, 3, 4, 5, 6, 7);
        }
        #pragma unroll
        for (int n = 0; n < 4; ++n) {
            int br = wc * 64 + n * 16 + l15;
            bf16x4v lo = *reinterpret_cast<const bf16x4v*>(&Bs[br * LDT + kg]);
            bf16x4v hi = *reinterpret_cast<const bf16x4v*>(&Bs[br * LDT + kg + 16]);
            bfr[n] = __builtin_shufflevector(lo, hi, 0, 1, 2, 3, 4, 5, 6, 7);
        }
        #pragma unroll
        for (int m = 0; m < 4; ++m)
            #pragma unroll
            for (int n = 0; n < 4; ++n)
                acc[m][n] = __builtin_amdgcn_mfma_f32_16x16x32_bf16(af[m], bfr[n], acc[m][n], 0, 0, 0);
        __syncthreads();
    }

    float ls[4] = {0.f, 0.f, 0.f, 0.f}, lq[4] = {0.f, 0.f, 0.f, 0.f};
    #pragma unroll
    for (int m = 0; m < 4; ++m) {
        int grow_base = row0 + wr * 64 + m * 16 + kg;
        #pragma unroll
        for (int j = 0; j < 4; ++j) {
            int grow = grow_base + j;
            if (grow >= M) continue;
            float rs = rowScale ? rowScale[grow] : 1.0f;
            #pragma unroll
            for (int n = 0; n < 4; ++n) {
                int gcol = col0 + wc * 64 + n * 16 + l15;
                if (gcol >= Nw) continue;
                float v = acc[m][n][j];
                if (bias) v += bias[gcol];
                v *= rs;
                if (outB) {
                    ushort h = f2bf(v);
                    outB[(size_t)grow * ldo + gcol] = h;
                    if (outLo) {
                        float hv = __uint_as_float(((uint32_t)h) << 16);
                        outLo[(size_t)grow * ldo + gcol] = f2bf(v - hv);
                    }
                } else {
                    outF[(size_t)grow * ldo + gcol] = v;
                    ls[n] += v; lq[n] += v * v;
                }
            }
        }
    }

    if (statsOut) {   // fused BN column stats (block reduce -> global atomics)
        if (tid < 256) cs[tid] = 0.f;
        __syncthreads();
        #pragma unroll
        for (int n = 0; n < 4; ++n) {
            int lc = wc * 64 + n * 16 + l15;
            atomicAdd(&cs[lc], ls[n]);
            atomicAdd(&cs[128 + lc], lq[n]);
        }
        __syncthreads();
        if (tid < 128) {
            atomicAdd(&statsOut[col0 + tid], cs[tid]);
            atomicAdd(&statsOut[256 + col0 + tid], cs[128 + tid]);
        }
    }
}

// ---------------- C3: A = relu(bufM*scale+shift) f32->bf16, K=256, prefetch -
__global__ __launch_bounds__(256) void mfma_c3_kernel(
    const float* __restrict__ Abuf, const ushort* __restrict__ Bt,
    int M, int Nw,
    const float* __restrict__ scale, const float* __restrict__ shift,
    float* __restrict__ outF, int ldo)
{
    __shared__ __align__(16) ushort As[128 * LDT];
    __shared__ __align__(16) ushort Bs[128 * LDT];
    const int tid  = threadIdx.x;
    int bx = blockIdx.x, by = blockIdx.y;
    xcd_swizzle(gridDim.x, gridDim.y, bx, by);
    const int row0 = by * 128;
    const int col0 = bx * 128;
    const int wid  = tid >> 6, lane = tid & 63;
    const int wr = wid >> 1, wc = wid & 1;
    const int l15 = lane & 15, lg = lane >> 4;
    const int kg = lg * 4;
    const int sr = tid >> 2;
    const int sc = (tid & 3) * 8;

    const float*  pA0 = Abuf + (size_t)(row0 + sr)      * 256 + sc;
    const float*  pA1 = Abuf + (size_t)(row0 + sr + 64) * 256 + sc;
    const ushort* pB0 = Bt + (size_t)(col0 + sr)        * 256 + sc;
    const ushort* pB1 = Bt + (size_t)(col0 + sr + 64)   * 256 + sc;

    float4 a00 = *reinterpret_cast<const float4*>(pA0);
    float4 a01 = *reinterpret_cast<const float4*>(pA0 + 4);
    float4 a10 = *reinterpret_cast<const float4*>(pA1);
    float4 a11 = *reinterpret_cast<const float4*>(pA1 + 4);
    uint4  b0  = *reinterpret_cast<const uint4*>(pB0);
    uint4  b1  = *reinterpret_cast<const uint4*>(pB1);

    f32x4 acc[4][4];
    #pragma unroll
    for (int m = 0; m < 4; ++m)
        #pragma unroll
        for (int n = 0; n < 4; ++n) acc[m][n] = (f32x4)0.f;

    for (int k0 = 0; k0 < 256; k0 += 32) {
        float s8[8], t8[8];
        #pragma unroll
        for (int i = 0; i < 8; ++i) { s8[i] = scale[k0 + sc + i]; t8[i] = shift[k0 + sc + i]; }
        {
            bf16_t h[8];
            h[0] = (bf16_t)fmaxf(a00.x * s8[0] + t8[0], 0.f);
            h[1] = (bf16_t)fmaxf(a00.y * s8[1] + t8[1], 0.f);
            h[2] = (bf16_t)fmaxf(a00.z * s8[2] + t8[2], 0.f);
            h[3] = (bf16_t)fmaxf(a00.w * s8[3] + t8[3], 0.f);
            h[4] = (bf16_t)fmaxf(a01.x * s8[4] + t8[4], 0.f);
            h[5] = (bf16_t)fmaxf(a01.y * s8[5] + t8[5], 0.f);
            h[6] = (bf16_t)fmaxf(a01.z * s8[6] + t8[6], 0.f);
            h[7] = (bf16_t)fmaxf(a01.w * s8[7] + t8[7], 0.f);
            *reinterpret_cast<uint4*>(&As[sr * LDT + sc]) = *reinterpret_cast<const uint4*>(h);
            h[0] = (bf16_t)fmaxf(a10.x * s8[0] + t8[0], 0.f);
            h[1] = (bf16_t)fmaxf(a10.y * s8[1] + t8[1], 0.f);
            h[2] = (bf16_t)fmaxf(a10.z * s8[2] + t8[2], 0.f);
            h[3] = (bf16_t)fmaxf(a10.w * s8[3] + t8[3], 0.f);
            h[4] = (bf16_t)fmaxf(a11.x * s8[4] + t8[4], 0.f);
            h[5] = (bf16_t)fmaxf(a11.y * s8[5] + t8[5], 0.f);
            h[6] = (bf16_t)fmaxf(a11.z * s8[6] + t8[6], 0.f);
            h[7] = (bf16_t)fmaxf(a11.w * s8[7] + t8[7], 0.f);
            *reinterpret_cast<uint4*>(&As[(sr + 64) * LDT + sc]) = *reinterpret_cast<const uint4*>(h);
        }
        *reinterpret_cast<uint4*>(&Bs[sr * LDT + sc])        = b0;
        *reinterpret_cast<uint4*>(&Bs[(sr + 64) * LDT + sc]) = b1;
        __syncthreads();
        if (k0 + 32 < 256) {
            a00 = *reinterpret_cast<const float4*>(pA0 + k0 + 32);
            a01 = *reinterpret_cast<const float4*>(pA0 + k0 + 36);
            a10 = *reinterpret_cast<const float4*>(pA1 + k0 + 32);
            a11 = *reinterpret_cast<const float4*>(pA1 + k0 + 36);
            b0  = *reinterpret_cast<const uint4*>(pB0 + k0 + 32);
            b1  = *reinterpret_cast<const uint4*>(pB1 + k0 + 32);
        }

        bf16x8v af[4], bfr[4];
        #pragma unroll
        for (int m = 0; m < 4; ++m) {
            int ar = wr * 64 + m * 16 + l15;
            bf16x4v lo = *reinterpret_cast<const bf16x4v*>(&As[ar * LDT + kg]);
            bf16x4v hi = *reinterpret_cast<const bf16x4v*>(&As[ar * LDT + kg + 16]);
            af[m] = __builtin_shufflevector(lo, hi, 0, 1, 2, 3, 4, 5, 6, 7);
        }
        #pragma unroll
        for (int n = 0; n < 4; ++n) {
            int br = wc * 64 + n * 16 + l15;
            bf16x4v lo = *reinterpret_cast<const bf16x4v*>(&Bs[br * LDT + kg]);
            bf16x4v hi = *reinterpret_cast<const bf16x4v*>(&Bs[br * LDT + kg + 16]);
            bfr[n] = __builtin_shufflevector(lo, hi, 0, 1, 2, 3, 4, 5, 6, 7);
        }
        #pragma unroll
        for (int m = 0; m < 4; ++m)
            #pragma unroll
            for (int n = 0; n < 4; ++n)
                acc[m][n] = __builtin_amdgcn_mfma_f32_16x16x32_bf16(af[m], bfr[n], acc[m][n], 0, 0, 0);
        __syncthreads();
    }

    #pragma unroll
    for (int m = 0; m < 4; ++m) {
        int grow_base = row0 + wr * 64 + m * 16 + kg;
        #pragma unroll
        for (int j = 0; j < 4; ++j) {
            int grow = grow_base + j;
            if (grow >= M) continue;
            #pragma unroll
            for (int n = 0; n < 4; ++n) {
                int gcol = col0 + wc * 64 + n * 16 + l15;
                if (gcol >= Nw) continue;
                outF[(size_t)grow * ldo + gcol] = acc[m][n][j];
            }
        }
    }
}

// ---------------- split-K MFMA: partials (f32), grid.z = K-chunk ------------
__global__ __launch_bounds__(256) void mfma_splitk_kernel(
    const ushort* __restrict__ A, const ushort* __restrict__ Bt,
    int M, int K, int lda, int kChunk, int Ntot,
    float* __restrict__ part)
{
    __shared__ __align__(16) ushort As[128 * LDT];
    __shared__ __align__(16) ushort Bs[128 * LDT];
    const int tid  = threadIdx.x;
    const int row0 = blockIdx.y * 128;
    const int col0 = blockIdx.x * 128;
    const int wid  = tid >> 6, lane = tid & 63;
    const int wr = wid >> 1, wc = wid & 1;
    const int l15 = lane & 15, lg = lane >> 4;
    const int kg = lg * 4;
    const int sr = tid >> 2;
    const int sc = (tid & 3) * 8;

    const int k0s = blockIdx.z * kChunk;
    const int k0e = (k0s + kChunk < K) ? k0s + kChunk : K;

    const ushort* pA0 = A  + (size_t)(row0 + sr)      * lda + sc;
    const ushort* pA1 = A  + (size_t)(row0 + sr + 64) * lda + sc;
    const ushort* pB0 = Bt + (size_t)(col0 + sr)      * lda + sc;
    const ushort* pB1 = Bt + (size_t)(col0 + sr + 64) * lda + sc;

    uint4 ra0 = *reinterpret_cast<const uint4*>(pA0 + k0s);
    uint4 ra1 = *reinterpret_cast<const uint4*>(pA1 + k0s);
    uint4 rb0 = *reinterpret_cast<const uint4*>(pB0 + k0s);
    uint4 rb1 = *reinterpret_cast<const uint4*>(pB1 + k0s);

    f32x4 acc[4][4];
    #pragma unroll
    for (int m = 0; m < 4; ++m)
        #pragma unroll
        for (int n = 0; n < 4; ++n) acc[m][n] = (f32x4)0.f;

    for (int k0 = k0s; k0 < k0e; k0 += 32) {
        *reinterpret_cast<uint4*>(&As[sr * LDT + sc])        = ra0;
        *reinterpret_cast<uint4*>(&As[(sr + 64) * LDT + sc]) = ra1;
        *reinterpret_cast<uint4*>(&Bs[sr * LDT + sc])        = rb0;
        *reinterpret_cast<uint4*>(&Bs[(sr + 64) * LDT + sc]) = rb1;
        __syncthreads();
        if (k0 + 32 < k0e) {
            ra0 = *reinterpret_cast<const uint4*>(pA0 + k0 + 32);
            ra1 = *reinterpret_cast<const uint4*>(pA1 + k0 + 32);
            rb0 = *reinterpret_cast<const uint4*>(pB0 + k0 + 32);
            rb1 = *reinterpret_cast<const uint4*>(pB1 + k0 + 32);
        }

        bf16x8v af[4], bfr[4];
        #pragma unroll
        for (int m = 0; m < 4; ++m) {
            int ar = wr * 64 + m * 16 + l15;
            bf16x4v lo = *reinterpret_cast<const bf16x4v*>(&As[ar * LDT + kg]);
            bf16x4v hi = *reinterpret_cast<const bf16x4v*>(&As[ar * LDT + kg + 16]);
            af[m] = __builtin_shufflevector(lo, hi, 0, 1, 2, 3, 4, 5, 6, 7);
        }
        #pragma unroll
        for (int n = 0; n < 4; ++n) {
            int br = wc * 64 + n * 16 + l15;
            bf16x4v lo = *reinterpret_cast<const bf16x4v*>(&Bs[br * LDT + kg]);
            bf16x4v hi = *reinterpret_cast<const bf16x4v*>(&Bs[br * LDT + kg + 16]);
            bfr[n] = __builtin_shufflevector(lo, hi, 0, 1, 2, 3, 4, 5, 6, 7);
        }
        #pragma unroll
        for (int m = 0; m < 4; ++m)
            #pragma unroll
            for (int n = 0; n < 4; ++n)
                acc[m][n] = __builtin_amdgcn_mfma_f32_16x16x32_bf16(af[m], bfr[n], acc[m][n], 0, 0, 0);
        __syncthreads();
    }

    float* pslab = part + (size_t)blockIdx.z * M * Ntot;
    #pragma unroll
    for (int m = 0; m < 4; ++m) {
        int grow_base = row0 + wr * 64 + m * 16 + kg;
        #pragma unroll
        for (int j = 0; j < 4; ++j) {
            int grow = grow_base + j;
            if (grow >= M) continue;
            #pragma unroll
            for (int n = 0; n < 4; ++n) {
                int gcol = col0 + wc * 64 + n * 16 + l15;
                pslab[(size_t)grow * Ntot + gcol] = acc[m][n][j];
            }
        }
    }
}

__global__ void reduce_tanh_kernel(const float* __restrict__ part, int S, int M, int N,
                                   const float* __restrict__ rs, float* __restrict__ out) {
    int i = blockIdx.x * blockDim.x + threadIdx.x;
    if (i >= M * N) return;
    int r = i / N;
    float s = 0.f;
    for (int z = 0; z < S; ++z) s += part[(size_t)z * M * N + i];
    if (rs) s *= rs[r];
    out[i] = tanhf(s);
}

// ---------------- conversion / fusion helpers -------------------------------
__global__ void transpose_cvt_kernel(const float* __restrict__ in, int K, int N, int ldin,
                                     ushort* __restrict__ out, int Kp) {
    int i = blockIdx.x * blockDim.x + threadIdx.x;
    if (i >= N * Kp) return;
    int n = i / Kp, k = i % Kp;
    float v = (k < K) ? in[(size_t)k * ldin + n] : 0.f;
    out[i] = f2bf(v);
}

__global__ void make_cat_weights_kernel(
    const float* __restrict__ w_sh1, const float* __restrict__ w_sh1h,
    const float* __restrict__ b_sh1, const float* __restrict__ b_sh1h,
    const float* __restrict__ w_sh2, const float* __restrict__ w_sh2h,
    const float* __restrict__ b_sh2, const float* __restrict__ b_sh2h,
    const float* __restrict__ w_mlp1, const float* __restrict__ w_mlp1h,
    const float* __restrict__ b_mlp1, const float* __restrict__ b_mlp1h,
    float* __restrict__ W1cat, float* __restrict__ b1cat,
    float* __restrict__ W2bd,  float* __restrict__ b2cat,
    float* __restrict__ WMbd,  float* __restrict__ bMcat)
{
    int i = blockIdx.x * blockDim.x + threadIdx.x;
    if (i < 64 * 128) {
        int k = i >> 7, j = i & 127;
        W1cat[i] = (j < 64) ? w_sh1[k * 64 + j] : w_sh1h[k * 64 + (j - 64)];
        return;
    }
    i -= 64 * 128;
    if (i < 128) { b1cat[i] = (i < 64) ? b_sh1[i] : b_sh1h[i - 64]; return; }
    i -= 128;
    if (i < 128 * 128) {
        int k = i >> 7, j = i & 127;
        float v = 0.f;
        if (k < 64 && j < 64) v = w_sh2[k * 64 + j];
        else if (k >= 64 && j >= 64) v = w_sh2h[(k - 64) * 64 + (j - 64)];
        W2bd[i] = v;
        return;
    }
    i -= 128 * 128;
    if (i < 128) { b2cat[i] = (i < 64) ? b_sh2[i] : b_sh2h[i - 64]; return; }
    i -= 128;
    if (i < 128 * 512) {
        int k = i >> 9, j = i & 511;
        float v = 0.f;
        if (j < 256) { if (k < 64) v = w_mlp1[k * 256 + j]; }
        else         { if (k >= 64) v = w_mlp1h[(k - 64) * 256 + (j - 256)]; }
        WMbd[i] = v;
        return;
    }
    i -= 128 * 512;
    if (i < 512) { bMcat[i] = (i < 256) ? b_mlp1[i] : b_mlp1h[i - 256]; }
}

__global__ void avg3cat_kernel(const float* __restrict__ emb, const float* __restrict__ x2cat,
                               const float* __restrict__ x6cat, float* __restrict__ o) {
    int i = blockIdx.x * blockDim.x + threadIdx.x;
    if (i >= N_SH * 128) return;
    int r = i >> 7, j = i & 127;
    o[i] = (emb[r * 64 + (j & 63)] + x2cat[i] + x6cat[i]) * (1.0f / 3.0f);
}

__global__ void concat_hh_kernel(const float* __restrict__ emb, const float* __restrict__ kg,
                                 float* __restrict__ out) {
    int i = blockIdx.x * blockDim.x + threadIdx.x;
    const int n = N_HH * 91;
    if (i >= n) return;
    int r = i / 91, c = i % 91;
    out[i] = (c < DIM) ? emb[r * DIM + c] : kg[r * 27 + (c - DIM)];
}

__global__ void make_esbt_kernel(const float* __restrict__ x9cat, const float* __restrict__ ss1,
                                 ushort* __restrict__ out, int Kp) {
    int i = blockIdx.x * blockDim.x + threadIdx.x;
    if (i >= 256 * Kp) return;
    int n = i / Kp, k = i % Kp;
    float v = (k < N_SS) ? (x9cat[(size_t)k * 512 + n] + ss1[(size_t)k * 256 + n]) : 0.f;
    out[i] = f2bf(v);
}

__global__ void make_wmlp2_kernel(const float* __restrict__ wm, ushort* __restrict__ out) {
    int i = blockIdx.x * blockDim.x + threadIdx.x;
    if (i >= 256 * 512) return;
    int n = i >> 9, k = i & 511;
    out[i] = f2bf(wm[(size_t)(k & 255) * 256 + n]);
}

__global__ void make_ehb_kernel(const float* __restrict__ x9cat, const float* __restrict__ hh1,
                                ushort* __restrict__ out, int Rp) {
    int i = blockIdx.x * blockDim.x + threadIdx.x;
    if (i >= Rp * 256) return;
    int r = i >> 8, c = i & 255;
    float v = (r < N_HH) ? (x9cat[(size_t)(N_SS + r) * 512 + 256 + c] + hh1[(size_t)r * 256 + c]) : 0.f;
    out[i] = f2bf(v);
}

// ---------------- BatchNorm -------------------------------------------------
__global__ void bn_stats_cat_kernel(const float* __restrict__ X, int M,
                                    float* __restrict__ stats) {
    int j = threadIdx.x;  // 512
    float s = 0.f, ss = 0.f;
    for (int r = blockIdx.x; r < M; r += gridDim.x) {
        float v = X[(size_t)r * 512 + j];
        s += v; ss += v * v;
    }
    atomicAdd(&stats[j], s);
    atomicAdd(&stats[512 + j], ss);
}

__global__ void bn_apply_cat_kernel(const float* __restrict__ X, const float* __restrict__ stats,
                                    const float* __restrict__ g1, const float* __restrict__ be1,
                                    const float* __restrict__ g2, const float* __restrict__ be2,
                                    int M, float* __restrict__ out) {
    int i = blockIdx.x * blockDim.x + threadIdx.x;
    if (i >= M * 512) return;
    int j = i & 511;
    float invM = 1.0f / (float)M;
    float mean = stats[j] * invM;
    float var  = fmaxf(stats[512 + j] * invM - mean * mean, 0.f);
    float ga = (j < 256) ? g1[j]  : g2[j - 256];
    float bb = (j < 256) ? be1[j] : be2[j - 256];
    float y = (X[i] - mean) * rsqrtf(var + 1e-5f) * ga + bb;
    out[i] = tanhf(y);
}

__global__ void bn_finalize_kernel(const float* __restrict__ stats,
                                   const float* __restrict__ g, const float* __restrict__ be,
                                   int M, float* __restrict__ scale, float* __restrict__ shift) {
    int j = threadIdx.x;  // 256
    float invM = 1.0f / (float)M;
    float mean = stats[j] * invM;
    float var  = fmaxf(stats[256 + j] * invM - mean * mean, 0.f);
    float sc = g[j] * rsqrtf(var + 1e-5f);
    scale[j] = sc;
    shift[j] = be[j] - mean * sc;
}

// ---------------- driver -----------------------------------------------------
extern "C" void kernel_launch(void* const* d_in, const int* in_sizes, int n_in,
                              void* d_out, int out_size, void* d_ws, size_t ws_size,
                              hipStream_t stream) {
    const int*   eiSH = (const int*)d_in[1];
    const int*   eiSS = (const int*)d_in[3];
    const int*   eiHH = (const int*)d_in[5];
    const float* P    = (const float*)d_in[6];
    const float* kg   = (const float*)d_in[7];
    const float* emb  = (const float*)d_in[8];
    const float* w_sh1  = (const float*)d_in[9];   const float* b_sh1  = (const float*)d_in[10];
    const float* w_sh2  = (const float*)d_in[11];  const float* b_sh2  = (const float*)d_in[12];
    const float* w_mlp1 = (const float*)d_in[13];  const float* b_mlp1 = (const float*)d_in[14];
    const float* g_bn1  = (const float*)d_in[15];  const float* be_bn1 = (const float*)d_in[16];
    const float* w_sh1h = (const float*)d_in[17];  const float* b_sh1h = (const float*)d_in[18];
    const float* w_sh2h = (const float*)d_in[19];  const float* b_sh2h = (const float*)d_in[20];
    const float* w_mlp1h= (const float*)d_in[21];  const float* b_mlp1h= (const float*)d_in[22];
    const float* g_bn1h = (const float*)d_in[23];  const float* be_bn1h= (const float*)d_in[24];
    const float* w_ss   = (const float*)d_in[25];  const float* b_ss   = (const float*)d_in[26];
    const float* w_hh   = (const float*)d_in[27];  const float* b_hh   = (const float*)d_in[28];
    const float* w_mlp  = (const float*)d_in[29];  const float* b_mlp  = (const float*)d_in[30];
    const float* g_si   = (const float*)d_in[31];  const float* be_si  = (const float*)d_in[32];
    float* out = (float*)d_out;

    const int E_SH = in_sizes[1] / 2;
    const int E_SS = in_sizes[3] / 2;
    const int E_HH = in_sizes[5] / 2;
    const int B    = in_sizes[6] / N_SS;      // 20000
    const int Mp   = ((B + 127) / 128) * 128; // 20096
    const int KP1  = 416;
    const int NP3  = 896;
    const int KSH  = 1216;
    const int KHH  = 832;

    float* w = (float*)d_ws;
    size_t off = 0;
    auto alloc = [&](size_t n) { float* p = w + off; off += (n + 3) & ~(size_t)3; return p; };

    float* cntInv  = alloc(N_SH);
    float* presInv = alloc(B);
    float* stats   = alloc(1024);
    float* bnScale = alloc(256);
    float* bnShift = alloc(256);
    float* W1cat   = alloc(64 * 128);
    float* b1cat   = alloc(128);
    float* W2bd    = alloc(128 * 128);
    float* b2cat   = alloc(128);
    float* WMbd    = alloc(128 * 512);
    float* bMcat   = alloc(512);
    ushort* adjb   = (ushort*)alloc((size_t)1280 * KSH / 2);
    ushort* adjSSb = (ushort*)alloc((size_t)512 * KP1 / 2);
    ushort* adjHHb = (ushort*)alloc((size_t)896 * KHH / 2);
    float* tmpL    = alloc((size_t)N_SH * 128);
    ushort* HT     = (ushort*)alloc((size_t)128 * KSH / 2);
    float* x2cat   = alloc((size_t)N_SH * 128);
    float* x6cat   = alloc((size_t)N_SH * 128);
    float* x9a2    = alloc((size_t)N_SH * 128);
    float* tmpBN   = alloc((size_t)N_SH * 512);
    float* x9cat   = alloc((size_t)N_SH * 512);
    float* ss1     = alloc((size_t)N_SS * 256);
    float* hh1     = alloc((size_t)N_HH * 256);
    float* xhh0    = alloc((size_t)N_HH * 91);
    ushort* HSST   = (ushort*)alloc((size_t)256 * KP1 / 2);
    ushort* HHHT   = (ushort*)alloc((size_t)256 * KHH / 2);
    ushort* es_bT  = (ushort*)alloc((size_t)256 * KP1 / 2);
    ushort* wmlp2  = (ushort*)alloc((size_t)256 * 512 / 2);
    ushort* eh_b   = (ushort*)alloc((size_t)NP3 * 256 / 2);
    // region A: f32 adjacency (early) -> P_b bf16 [Mp][416] -> bufM f32 [Mp][256]
    float* regionA = alloc((size_t)Mp * 256);
    float* adjSH   = regionA;
    float* adjSS   = regionA + (size_t)N_SH * N_SH;
    float* adjHH   = adjSS + (size_t)N_SS * N_SS;
    ushort* P_b    = (ushort*)regionA;
    float*  bufM   = regionA;
    // region B: split-K partials (early) -> e_hilo bf16 [Mp][512]
    float* regionB = alloc((size_t)Mp * 256);
    float*  partials = regionB;
    ushort* e_hilo = (ushort*)regionB;
    (void)ws_size; (void)n_in; (void)out_size;

    auto gemm = [&](const float* Am, const float* Bm, const float* bias, const float* rs,
                    float* C, int M, int N, int K, int act) {
        dim3 g((N + BN - 1) / BN, (M + BM - 1) / BM);
        gemm_kernel<<<g, 256, 0, stream>>>(Am, Bm, bias, rs, C, M, N, K, act);
    };
    auto mgemm = [&](const ushort* Am, const ushort* Bm, int M, int Np, int Nw, int K, int lda,
                     const float* bias, const float* rs,
                     float* oF, ushort* oB, ushort* oLo, int ldo, float* st) {
        dim3 g(Np / 128, (M + 127) / 128);
        mfma_gemm_kernel<<<g, 256, 0, stream>>>(Am, Bm, M, Nw, K, lda, bias, rs, oF, oB, oLo, ldo, st);
    };
    auto splitk = [&](const ushort* Am, const ushort* Bm, int M, int Mtiles, int K, int lda,
                      int Ntot, int S, const float* rs, float* outp) {
        dim3 g(Ntot / 128, Mtiles, S);
        mfma_splitk_kernel<<<g, 256, 0, stream>>>(Am, Bm, M, K, lda, 128, Ntot, partials);
        reduce_tanh_kernel<<<(M * Ntot + 255) / 256, 256, 0, stream>>>(partials, S, M, Ntot, rs, outp);
    };

    // ---- adjacency (naive atomic f32 counts, then bf16 copies) ----
    hipMemsetAsync(regionA, 0,
                   ((size_t)N_SH * N_SH + (size_t)N_SS * N_SS + (size_t)N_HH * N_HH + 16) * sizeof(float),
                   stream);
    build_adj_kernel<<<(E_SH + 255) / 256, 256, 0, stream>>>(eiSH, E_SH, adjSH, N_SH);
    build_adj_kernel<<<(E_SS + 255) / 256, 256, 0, stream>>>(eiSS, E_SS, adjSS, N_SS);
    build_adj_kernel<<<(E_HH + 255) / 256, 256, 0, stream>>>(eiHH, E_HH, adjHH, N_HH);
    rowsum_inv_kernel<<<(N_SH + 3) / 4, 256, 0, stream>>>(adjSH, N_SH, N_SH, cntInv, 1);
    cvt_pad2_kernel<<<(1280 * KSH + 255) / 256, 256, 0, stream>>>(adjSH, N_SH, N_SH, adjb, 1280, KSH);
    cvt_pad2_kernel<<<(512 * KP1 + 255) / 256, 256, 0, stream>>>(adjSS, N_SS, N_SS, adjSSb, 512, KP1);
    cvt_pad2_kernel<<<(896 * KHH + 255) / 256, 256, 0, stream>>>(adjHH, N_HH, N_HH, adjHHb, 896, KHH);

    make_cat_weights_kernel<<<(90880 + 255) / 256, 256, 0, stream>>>(
        w_sh1, w_sh1h, b_sh1, b_sh1h, w_sh2, w_sh2h, b_sh2, b_sh2h,
        w_mlp1, w_mlp1h, b_mlp1, b_mlp1h,
        W1cat, b1cat, W2bd, b2cat, WMbd, bMcat);

    // ---- SH layers (fused branches) ----
    gemm(emb, W1cat, b1cat, nullptr, tmpL, N_SH, 128, 64, 0);
    transpose_cvt_kernel<<<(128 * KSH + 255) / 256, 256, 0, stream>>>(tmpL, N_SH, 128, 128, HT, KSH);
    splitk(adjb, HT, N_SH, 10, KSH, KSH, 128, 10, cntInv, x2cat);
    gemm(x2cat, W2bd, b2cat, nullptr, tmpL, N_SH, 128, 128, 0);
    transpose_cvt_kernel<<<(128 * KSH + 255) / 256, 256, 0, stream>>>(tmpL, N_SH, 128, 128, HT, KSH);
    splitk(adjb, HT, N_SH, 10, KSH, KSH, 128, 10, cntInv, x6cat);
    avg3cat_kernel<<<(N_SH * 128 + 255) / 256, 256, 0, stream>>>(emb, x2cat, x6cat, x9a2);
    gemm(x9a2, WMbd, bMcat, nullptr, tmpBN, N_SH, 512, 128, 0);
    hipMemsetAsync(stats, 0, 1024 * sizeof(float), stream);
    bn_stats_cat_kernel<<<64, 512, 0, stream>>>(tmpBN, N_SH, stats);
    bn_apply_cat_kernel<<<(N_SH * 512 + 255) / 256, 256, 0, stream>>>(
        tmpBN, stats, g_bn1, be_bn1, g_bn1h, be_bn1h, N_SH, x9cat);

    // ---- SS graph ----
    gemm(emb, w_ss, b_ss, nullptr, tmpBN, N_SS, 256, 64, 0);
    transpose_cvt_kernel<<<(256 * KP1 + 255) / 256, 256, 0, stream>>>(tmpBN, N_SS, 256, 256, HSST, KP1);
    splitk(adjSSb, HSST, N_SS, 4, KP1, KP1, 256, 4, nullptr, ss1);

    // ---- HH graph ----
    concat_hh_kernel<<<(N_HH * 91 + 255) / 256, 256, 0, stream>>>(emb, kg, xhh0);
    gemm(xhh0, w_hh, b_hh, nullptr, tmpBN, N_HH, 256, 91, 0);
    transpose_cvt_kernel<<<(256 * KHH + 255) / 256, 256, 0, stream>>>(tmpBN, N_HH, 256, 256, HHHT, KHH);
    splitk(adjHHb, HHHT, N_HH, 7, KHH, KHH, 256, 7, nullptr, hh1);

    // ---- prepare bf16 operands for prescription path ----
    make_esbt_kernel<<<(256 * KP1 + 255) / 256, 256, 0, stream>>>(x9cat, ss1, es_bT, KP1);
    make_wmlp2_kernel<<<(256 * 512 + 255) / 256, 256, 0, stream>>>(w_mlp, wmlp2);
    make_ehb_kernel<<<(NP3 * 256 + 255) / 256, 256, 0, stream>>>(x9cat, hh1, eh_b, NP3);
    cvt_rowsum_p_kernel<<<B, 128, 0, stream>>>(P, P_b, presInv);
    hipMemsetAsync(stats, 0, 512 * sizeof(float), stream);

    // ---- prescription path (bf16 MFMA, prefetched) ----
    // C1: e = (P @ es) * presInv -> hi/lo bf16 pair [Mp][512]
    mgemm(P_b, es_bT, B, 256, 256, KP1, KP1, nullptr, presInv,
          nullptr, e_hilo, e_hilo + 256, 512, nullptr);
    // C2: bufM = (e_hi + e_lo) @ w_mlp + b_mlp; BN col-stats fused in epilogue
    mgemm(e_hilo, wmlp2, B, 256, 256, 512, 512, b_mlp, nullptr,
          bufM, nullptr, nullptr, 256, stats);
    bn_finalize_kernel<<<1, 256, 0, stream>>>(stats, g_si, be_si, B, bnScale, bnShift);
    // C3: out = relu(BN(bufM)) @ eh^T (BN fused into A-staging, prefetched)
    {
        dim3 g(NP3 / 128, (B + 127) / 128);
        mfma_c3_kernel<<<g, 256, 0, stream>>>(bufM, eh_b, B, N_HH, bnScale, bnShift, out, N_HH);
    }
}

// Round 8
// 342.441 us; speedup vs baseline: 1.3095x; 1.1016x over previous
//
#include <hip/hip_runtime.h>
#include <cstddef>
#include <cstdint>

#define N_SH 1195
#define N_SS 390
#define N_HH 805
#define DIM  64

typedef __bf16 bf16_t;
typedef bf16_t bf16x4v __attribute__((ext_vector_type(4)));
typedef bf16_t bf16x8v __attribute__((ext_vector_type(8)));
typedef float f32x4 __attribute__((ext_vector_type(4)));

__device__ inline ushort f2bf(float f) {
    union { float f; uint32_t u; } c; c.f = f;
    uint32_t u = c.u;
    u += 0x7FFFu + ((u >> 16) & 1u);
    return (ushort)(u >> 16);
}

// bijective XCD swizzle (m204)
__device__ inline void xcd_swizzle(int gx, int gy, int& bx, int& by) {
    int nwg = gx * gy;
    int lin = by * gx + bx;
    int q = nwg >> 3, r = nwg & 7;
    int xcd = lin & 7, idx = lin >> 3;
    int nt = (xcd < r ? xcd * (q + 1) : r * (q + 1) + (xcd - r) * q) + idx;
    by = nt / gx; bx = nt % gx;
}

// ---------------- adjacency build: packed 2x16-bit counters per u32 ---------
// counts are small (<=~10) so no carry across the 16-bit halves.
__global__ void build_adj_packed_kernel(const int* __restrict__ ei, int E,
                                        int halfStride, uint32_t* __restrict__ T) {
    int i = blockIdx.x * blockDim.x + threadIdx.x;
    if (i < E) {
        int src = ei[i];
        int dst = ei[E + i];
        atomicAdd(&T[(size_t)dst * halfStride + (src >> 1)], 1u << ((src & 1) * 16));
    }
}

__global__ void rowsum_inv_packed_kernel(const uint32_t* __restrict__ T, int R,
                                         int halfStride, float* __restrict__ inv) {
    int row  = blockIdx.x * (blockDim.x / 64) + (threadIdx.x / 64);
    int lane = threadIdx.x & 63;
    if (row >= R) return;
    const uint32_t* p = T + (size_t)row * halfStride;
    uint32_t s = 0;
    for (int c = lane; c < halfStride; c += 64) {
        uint32_t w = p[c];
        s += (w & 0xFFFFu) + (w >> 16);
    }
    for (int off = 32; off > 0; off >>= 1) s += __shfl_down(s, off);
    if (lane == 0) inv[row] = 1.0f / fmaxf((float)s, 1.0f);
}

// packed u32 table -> bf16 [Rp][Cp], zero-padded
__global__ void cvt_unpack_kernel(const uint32_t* __restrict__ T, int R, int C,
                                  int halfStride, ushort* __restrict__ out,
                                  int Rp, int Cp) {
    int i = blockIdx.x * blockDim.x + threadIdx.x;
    if (i >= Rp * Cp) return;
    int r = i / Cp, c = i % Cp;
    float v = 0.f;
    if (r < R && c < C) {
        uint32_t w = T[(size_t)r * halfStride + (c >> 1)];
        v = (float)((w >> ((c & 1) * 16)) & 0xFFFFu);
    }
    out[i] = f2bf(v);
}

// ---------------- fp32 GEMM (small dense layers) ----------------------------
#define BM 64
#define BN 64
#define BK 16

__global__ __launch_bounds__(256) void gemm_kernel(
    const float* __restrict__ A, const float* __restrict__ B,
    const float* __restrict__ bias, const float* __restrict__ rowScale,
    float* __restrict__ C, int M, int N, int K, int act)
{
    __shared__ float As[BK][BM + 4];
    __shared__ float Bs[BK][BN];
    const int tid  = threadIdx.x;
    const int row0 = blockIdx.y * BM;
    const int col0 = blockIdx.x * BN;
    const int tr  = (tid >> 4) << 2;
    const int tc  = (tid & 15) << 2;
    const int lar = tid >> 2;
    const int lac = (tid & 3) << 2;
    const int lbr = tid >> 4;
    const int lbc = (tid & 15) << 2;

    float acc[4][4] = {{0.f}};

    for (int k0 = 0; k0 < K; k0 += BK) {
        const int gr = row0 + lar;
        const float* Ap = A + (size_t)gr * K + k0 + lac;
        #pragma unroll
        for (int i = 0; i < 4; ++i) {
            int gk = k0 + lac + i;
            As[lac + i][lar] = (gr < M && gk < K) ? Ap[i] : 0.f;
        }
        const int gk = k0 + lbr;
        const float* Bp = B + (size_t)gk * N + col0 + lbc;
        #pragma unroll
        for (int i = 0; i < 4; ++i) {
            int gc = col0 + lbc + i;
            Bs[lbr][lbc + i] = (gk < K && gc < N) ? Bp[i] : 0.f;
        }
        __syncthreads();
        #pragma unroll
        for (int kk = 0; kk < BK; ++kk) {
            float4 a = *reinterpret_cast<const float4*>(&As[kk][tr]);
            float4 b = *reinterpret_cast<const float4*>(&Bs[kk][tc]);
            acc[0][0] += a.x * b.x; acc[0][1] += a.x * b.y; acc[0][2] += a.x * b.z; acc[0][3] += a.x * b.w;
            acc[1][0] += a.y * b.x; acc[1][1] += a.y * b.y; acc[1][2] += a.y * b.z; acc[1][3] += a.y * b.w;
            acc[2][0] += a.z * b.x; acc[2][1] += a.z * b.y; acc[2][2] += a.z * b.z; acc[2][3] += a.z * b.w;
            acc[3][0] += a.w * b.x; acc[3][1] += a.w * b.y; acc[3][2] += a.w * b.z; acc[3][3] += a.w * b.w;
        }
        __syncthreads();
    }

    #pragma unroll
    for (int i = 0; i < 4; ++i) {
        int gr = row0 + tr + i;
        if (gr >= M) continue;
        float rs = rowScale ? rowScale[gr] : 1.0f;
        #pragma unroll
        for (int j = 0; j < 4; ++j) {
            int gc = col0 + tc + j;
            if (gc >= N) continue;
            float v = acc[i][j];
            if (bias) v += bias[gc];
            v *= rs;
            if (act == 1) v = tanhf(v);
            C[(size_t)gr * N + gc] = v;
        }
    }
}

// ---------------- bf16 MFMA GEMM, 2-phase prefetch --------------------------
#define LDT 40

__global__ __launch_bounds__(256) void mfma_gemm_kernel(
    const ushort* __restrict__ A, const ushort* __restrict__ Bt,
    int M, int Nw, int K, int lda,
    const float* __restrict__ bias, const float* __restrict__ rowScale,
    float* __restrict__ outF, ushort* __restrict__ outB, ushort* __restrict__ outLo,
    int ldo, float* __restrict__ statsOut)
{
    __shared__ __align__(16) ushort As[128 * LDT];
    __shared__ __align__(16) ushort Bs[128 * LDT];
    __shared__ float cs[256];
    const int tid  = threadIdx.x;
    int bx = blockIdx.x, by = blockIdx.y;
    xcd_swizzle(gridDim.x, gridDim.y, bx, by);
    const int row0 = by * 128;
    const int col0 = bx * 128;
    const int wid  = tid >> 6, lane = tid & 63;
    const int wr = wid >> 1, wc = wid & 1;
    const int l15 = lane & 15, lg = lane >> 4;
    const int kg = lg * 4;
    const int sr = tid >> 2;
    const int sc = (tid & 3) * 8;

    const ushort* pA0 = A  + (size_t)(row0 + sr)      * lda + sc;
    const ushort* pA1 = A  + (size_t)(row0 + sr + 64) * lda + sc;
    const ushort* pB0 = Bt + (size_t)(col0 + sr)      * lda + sc;
    const ushort* pB1 = Bt + (size_t)(col0 + sr + 64) * lda + sc;

    uint4 ra0 = *reinterpret_cast<const uint4*>(pA0);
    uint4 ra1 = *reinterpret_cast<const uint4*>(pA1);
    uint4 rb0 = *reinterpret_cast<const uint4*>(pB0);
    uint4 rb1 = *reinterpret_cast<const uint4*>(pB1);

    f32x4 acc[4][4];
    #pragma unroll
    for (int m = 0; m < 4; ++m)
        #pragma unroll
        for (int n = 0; n < 4; ++n) acc[m][n] = (f32x4)0.f;

    for (int k0 = 0; k0 < K; k0 += 32) {
        *reinterpret_cast<uint4*>(&As[sr * LDT + sc])        = ra0;
        *reinterpret_cast<uint4*>(&As[(sr + 64) * LDT + sc]) = ra1;
        *reinterpret_cast<uint4*>(&Bs[sr * LDT + sc])        = rb0;
        *reinterpret_cast<uint4*>(&Bs[(sr + 64) * LDT + sc]) = rb1;
        __syncthreads();
        if (k0 + 32 < K) {
            ra0 = *reinterpret_cast<const uint4*>(pA0 + k0 + 32);
            ra1 = *reinterpret_cast<const uint4*>(pA1 + k0 + 32);
            rb0 = *reinterpret_cast<const uint4*>(pB0 + k0 + 32);
            rb1 = *reinterpret_cast<const uint4*>(pB1 + k0 + 32);
        }

        bf16x8v af[4], bfr[4];
        #pragma unroll
        for (int m = 0; m < 4; ++m) {
            int ar = wr * 64 + m * 16 + l15;
            bf16x4v lo = *reinterpret_cast<const bf16x4v*>(&As[ar * LDT + kg]);
            bf16x4v hi = *reinterpret_cast<const bf16x4v*>(&As[ar * LDT + kg + 16]);
            af[m] = __builtin_shufflevector(lo, hi, 0, 1, 2, 3, 4, 5, 6, 7);
        }
        #pragma unroll
        for (int n = 0; n < 4; ++n) {
            int br = wc * 64 + n * 16 + l15;
            bf16x4v lo = *reinterpret_cast<const bf16x4v*>(&Bs[br * LDT + kg]);
            bf16x4v hi = *reinterpret_cast<const bf16x4v*>(&Bs[br * LDT + kg + 16]);
            bfr[n] = __builtin_shufflevector(lo, hi, 0, 1, 2, 3, 4, 5, 6, 7);
        }
        #pragma unroll
        for (int m = 0; m < 4; ++m)
            #pragma unroll
            for (int n = 0; n < 4; ++n)
                acc[m][n] = __builtin_amdgcn_mfma_f32_16x16x32_bf16(af[m], bfr[n], acc[m][n], 0, 0, 0);
        __syncthreads();
    }

    float ls[4] = {0.f, 0.f, 0.f, 0.f}, lq[4] = {0.f, 0.f, 0.f, 0.f};
    #pragma unroll
    for (int m = 0; m < 4; ++m) {
        int grow_base = row0 + wr * 64 + m * 16 + kg;
        #pragma unroll
        for (int j = 0; j < 4; ++j) {
            int grow = grow_base + j;
            if (grow >= M) continue;
            float rs = rowScale ? rowScale[grow] : 1.0f;
            #pragma unroll
            for (int n = 0; n < 4; ++n) {
                int gcol = col0 + wc * 64 + n * 16 + l15;
                if (gcol >= Nw) continue;
                float v = acc[m][n][j];
                if (bias) v += bias[gcol];
                v *= rs;
                if (outB) {
                    ushort h = f2bf(v);
                    outB[(size_t)grow * ldo + gcol] = h;
                    if (outLo) {
                        float hv = __uint_as_float(((uint32_t)h) << 16);
                        outLo[(size_t)grow * ldo + gcol] = f2bf(v - hv);
                    }
                } else {
                    outF[(size_t)grow * ldo + gcol] = v;
                    ls[n] += v; lq[n] += v * v;
                }
            }
        }
    }

    if (statsOut) {
        if (tid < 256) cs[tid] = 0.f;
        __syncthreads();
        #pragma unroll
        for (int n = 0; n < 4; ++n) {
            int lc = wc * 64 + n * 16 + l15;
            atomicAdd(&cs[lc], ls[n]);
            atomicAdd(&cs[128 + lc], lq[n]);
        }
        __syncthreads();
        if (tid < 128) {
            atomicAdd(&statsOut[col0 + tid], cs[tid]);
            atomicAdd(&statsOut[256 + col0 + tid], cs[128 + tid]);
        }
    }
}

// ---------------- C1: A = P (f32, masked), fused row-sum; out hi/lo bf16 ----
// K = 416 (P cols 390 zero-padded), B-operand es^T [256][416] bf16.
__device__ inline void loadP8(const float* __restrict__ rowp, int c0, bool rv,
                              float* a, float& s) {
    if (rv && c0 + 8 <= N_SS) {
        float2 x0 = *reinterpret_cast<const float2*>(rowp + c0);
        float2 x1 = *reinterpret_cast<const float2*>(rowp + c0 + 2);
        float2 x2 = *reinterpret_cast<const float2*>(rowp + c0 + 4);
        float2 x3 = *reinterpret_cast<const float2*>(rowp + c0 + 6);
        a[0] = x0.x; a[1] = x0.y; a[2] = x1.x; a[3] = x1.y;
        a[4] = x2.x; a[5] = x2.y; a[6] = x3.x; a[7] = x3.y;
    } else {
        #pragma unroll
        for (int i = 0; i < 8; ++i) a[i] = (rv && (c0 + i) < N_SS) ? rowp[c0 + i] : 0.f;
    }
    #pragma unroll
    for (int i = 0; i < 8; ++i) s += a[i];
}

__global__ __launch_bounds__(256) void mfma_c1_kernel(
    const float* __restrict__ Pm, const ushort* __restrict__ Bt,
    int M, ushort* __restrict__ outB, ushort* __restrict__ outLo, int ldo)
{
    __shared__ __align__(16) ushort As[128 * LDT];
    __shared__ __align__(16) ushort Bs[128 * LDT];
    __shared__ float sums[128];
    const int tid  = threadIdx.x;
    int bx = blockIdx.x, by = blockIdx.y;
    xcd_swizzle(gridDim.x, gridDim.y, bx, by);
    const int row0 = by * 128;
    const int col0 = bx * 128;
    const int wid  = tid >> 6, lane = tid & 63;
    const int wr = wid >> 1, wc = wid & 1;
    const int l15 = lane & 15, lg = lane >> 4;
    const int kg = lg * 4;
    const int sr = tid >> 2;
    const int sc = (tid & 3) * 8;

    const float* pA0 = Pm + (size_t)(row0 + sr)      * N_SS;
    const float* pA1 = Pm + (size_t)(row0 + sr + 64) * N_SS;
    const bool rv0 = (row0 + sr)      < M;
    const bool rv1 = (row0 + sr + 64) < M;
    const ushort* pB0 = Bt + (size_t)(col0 + sr)      * 416 + sc;
    const ushort* pB1 = Bt + (size_t)(col0 + sr + 64) * 416 + sc;

    float a0[8], a1[8];
    float s0 = 0.f, s1 = 0.f;
    loadP8(pA0, sc, rv0, a0, s0);
    loadP8(pA1, sc, rv1, a1, s1);
    uint4 b0 = *reinterpret_cast<const uint4*>(pB0);
    uint4 b1 = *reinterpret_cast<const uint4*>(pB1);

    f32x4 acc[4][4];
    #pragma unroll
    for (int m = 0; m < 4; ++m)
        #pragma unroll
        for (int n = 0; n < 4; ++n) acc[m][n] = (f32x4)0.f;

    for (int k0 = 0; k0 < 416; k0 += 32) {
        {
            bf16_t h[8];
            #pragma unroll
            for (int i = 0; i < 8; ++i) h[i] = (bf16_t)a0[i];
            *reinterpret_cast<uint4*>(&As[sr * LDT + sc]) = *reinterpret_cast<const uint4*>(h);
            #pragma unroll
            for (int i = 0; i < 8; ++i) h[i] = (bf16_t)a1[i];
            *reinterpret_cast<uint4*>(&As[(sr + 64) * LDT + sc]) = *reinterpret_cast<const uint4*>(h);
        }
        *reinterpret_cast<uint4*>(&Bs[sr * LDT + sc])        = b0;
        *reinterpret_cast<uint4*>(&Bs[(sr + 64) * LDT + sc]) = b1;
        __syncthreads();
        if (k0 + 32 < 416) {
            loadP8(pA0, k0 + 32 + sc, rv0, a0, s0);
            loadP8(pA1, k0 + 32 + sc, rv1, a1, s1);
            b0 = *reinterpret_cast<const uint4*>(pB0 + k0 + 32);
            b1 = *reinterpret_cast<const uint4*>(pB1 + k0 + 32);
        }

        bf16x8v af[4], bfr[4];
        #pragma unroll
        for (int m = 0; m < 4; ++m) {
            int ar = wr * 64 + m * 16 + l15;
            bf16x4v lo = *reinterpret_cast<const bf16x4v*>(&As[ar * LDT + kg]);
            bf16x4v hi = *reinterpret_cast<const bf16x4v*>(&As[ar * LDT + kg + 16]);
            af[m] = __builtin_shufflevector(lo, hi, 0, 1, 2, 3, 4, 5, 6, 7);
        }
        #pragma unroll
        for (int n = 0; n < 4; ++n) {
            int br = wc * 64 + n * 16 + l15;
            bf16x4v lo = *reinterpret_cast<const bf16x4v*>(&Bs[br * LDT + kg]);
            bf16x4v hi = *reinterpret_cast<const bf16x4v*>(&Bs[br * LDT + kg + 16]);
            bfr[n] = __builtin_shufflevector(lo, hi, 0, 1, 2, 3, 4, 5, 6, 7);
        }
        #pragma unroll
        for (int m = 0; m < 4; ++m)
            #pragma unroll
            for (int n = 0; n < 4; ++n)
                acc[m][n] = __builtin_amdgcn_mfma_f32_16x16x32_bf16(af[m], bfr[n], acc[m][n], 0, 0, 0);
        __syncthreads();
    }

    // fused row sums -> presInv (each of 4 threads per row contributes)
    if (tid < 128) sums[tid] = 0.f;
    __syncthreads();
    atomicAdd(&sums[sr], s0);
    atomicAdd(&sums[sr + 64], s1);
    __syncthreads();

    #pragma unroll
    for (int m = 0; m < 4; ++m) {
        int lr_base = wr * 64 + m * 16 + kg;
        #pragma unroll
        for (int j = 0; j < 4; ++j) {
            int lr = lr_base + j;
            int grow = row0 + lr;
            if (grow >= M) continue;
            float t = sums[lr];
            float inv = (t != 0.f) ? 1.0f / t : 0.f;
            #pragma unroll
            for (int n = 0; n < 4; ++n) {
                int gcol = col0 + wc * 64 + n * 16 + l15;
                float v = acc[m][n][j] * inv;
                ushort h = f2bf(v);
                outB[(size_t)grow * ldo + gcol] = h;
                float hv = __uint_as_float(((uint32_t)h) << 16);
                outLo[(size_t)grow * ldo + gcol] = f2bf(v - hv);
            }
        }
    }
}

// ---------------- C3: A = relu(bufM*scale+shift) f32->bf16, K=256, prefetch -
__global__ __launch_bounds__(256) void mfma_c3_kernel(
    const float* __restrict__ Abuf, const ushort* __restrict__ Bt,
    int M, int Nw,
    const float* __restrict__ scale, const float* __restrict__ shift,
    float* __restrict__ outF, int ldo)
{
    __shared__ __align__(16) ushort As[128 * LDT];
    __shared__ __align__(16) ushort Bs[128 * LDT];
    const int tid  = threadIdx.x;
    int bx = blockIdx.x, by = blockIdx.y;
    xcd_swizzle(gridDim.x, gridDim.y, bx, by);
    const int row0 = by * 128;
    const int col0 = bx * 128;
    const int wid  = tid >> 6, lane = tid & 63;
    const int wr = wid >> 1, wc = wid & 1;
    const int l15 = lane & 15, lg = lane >> 4;
    const int kg = lg * 4;
    const int sr = tid >> 2;
    const int sc = (tid & 3) * 8;

    const float*  pA0 = Abuf + (size_t)(row0 + sr)      * 256 + sc;
    const float*  pA1 = Abuf + (size_t)(row0 + sr + 64) * 256 + sc;
    const ushort* pB0 = Bt + (size_t)(col0 + sr)        * 256 + sc;
    const ushort* pB1 = Bt + (size_t)(col0 + sr + 64)   * 256 + sc;

    float4 a00 = *reinterpret_cast<const float4*>(pA0);
    float4 a01 = *reinterpret_cast<const float4*>(pA0 + 4);
    float4 a10 = *reinterpret_cast<const float4*>(pA1);
    float4 a11 = *reinterpret_cast<const float4*>(pA1 + 4);
    uint4  b0  = *reinterpret_cast<const uint4*>(pB0);
    uint4  b1  = *reinterpret_cast<const uint4*>(pB1);

    f32x4 acc[4][4];
    #pragma unroll
    for (int m = 0; m < 4; ++m)
        #pragma unroll
        for (int n = 0; n < 4; ++n) acc[m][n] = (f32x4)0.f;

    for (int k0 = 0; k0 < 256; k0 += 32) {
        float s8[8], t8[8];
        #pragma unroll
        for (int i = 0; i < 8; ++i) { s8[i] = scale[k0 + sc + i]; t8[i] = shift[k0 + sc + i]; }
        {
            bf16_t h[8];
            h[0] = (bf16_t)fmaxf(a00.x * s8[0] + t8[0], 0.f);
            h[1] = (bf16_t)fmaxf(a00.y * s8[1] + t8[1], 0.f);
            h[2] = (bf16_t)fmaxf(a00.z * s8[2] + t8[2], 0.f);
            h[3] = (bf16_t)fmaxf(a00.w * s8[3] + t8[3], 0.f);
            h[4] = (bf16_t)fmaxf(a01.x * s8[4] + t8[4], 0.f);
            h[5] = (bf16_t)fmaxf(a01.y * s8[5] + t8[5], 0.f);
            h[6] = (bf16_t)fmaxf(a01.z * s8[6] + t8[6], 0.f);
            h[7] = (bf16_t)fmaxf(a01.w * s8[7] + t8[7], 0.f);
            *reinterpret_cast<uint4*>(&As[sr * LDT + sc]) = *reinterpret_cast<const uint4*>(h);
            h[0] = (bf16_t)fmaxf(a10.x * s8[0] + t8[0], 0.f);
            h[1] = (bf16_t)fmaxf(a10.y * s8[1] + t8[1], 0.f);
            h[2] = (bf16_t)fmaxf(a10.z * s8[2] + t8[2], 0.f);
            h[3] = (bf16_t)fmaxf(a10.w * s8[3] + t8[3], 0.f);
            h[4] = (bf16_t)fmaxf(a11.x * s8[4] + t8[4], 0.f);
            h[5] = (bf16_t)fmaxf(a11.y * s8[5] + t8[5], 0.f);
            h[6] = (bf16_t)fmaxf(a11.z * s8[6] + t8[6], 0.f);
            h[7] = (bf16_t)fmaxf(a11.w * s8[7] + t8[7], 0.f);
            *reinterpret_cast<uint4*>(&As[(sr + 64) * LDT + sc]) = *reinterpret_cast<const uint4*>(h);
        }
        *reinterpret_cast<uint4*>(&Bs[sr * LDT + sc])        = b0;
        *reinterpret_cast<uint4*>(&Bs[(sr + 64) * LDT + sc]) = b1;
        __syncthreads();
        if (k0 + 32 < 256) {
            a00 = *reinterpret_cast<const float4*>(pA0 + k0 + 32);
            a01 = *reinterpret_cast<const float4*>(pA0 + k0 + 36);
            a10 = *reinterpret_cast<const float4*>(pA1 + k0 + 32);
            a11 = *reinterpret_cast<const float4*>(pA1 + k0 + 36);
            b0  = *reinterpret_cast<const uint4*>(pB0 + k0 + 32);
            b1  = *reinterpret_cast<const uint4*>(pB1 + k0 + 32);
        }

        bf16x8v af[4], bfr[4];
        #pragma unroll
        for (int m = 0; m < 4; ++m) {
            int ar = wr * 64 + m * 16 + l15;
            bf16x4v lo = *reinterpret_cast<const bf16x4v*>(&As[ar * LDT + kg]);
            bf16x4v hi = *reinterpret_cast<const bf16x4v*>(&As[ar * LDT + kg + 16]);
            af[m] = __builtin_shufflevector(lo, hi, 0, 1, 2, 3, 4, 5, 6, 7);
        }
        #pragma unroll
        for (int n = 0; n < 4; ++n) {
            int br = wc * 64 + n * 16 + l15;
            bf16x4v lo = *reinterpret_cast<const bf16x4v*>(&Bs[br * LDT + kg]);
            bf16x4v hi = *reinterpret_cast<const bf16x4v*>(&Bs[br * LDT + kg + 16]);
            bfr[n] = __builtin_shufflevector(lo, hi, 0, 1, 2, 3, 4, 5, 6, 7);
        }
        #pragma unroll
        for (int m = 0; m < 4; ++m)
            #pragma unroll
            for (int n = 0; n < 4; ++n)
                acc[m][n] = __builtin_amdgcn_mfma_f32_16x16x32_bf16(af[m], bfr[n], acc[m][n], 0, 0, 0);
        __syncthreads();
    }

    #pragma unroll
    for (int m = 0; m < 4; ++m) {
        int grow_base = row0 + wr * 64 + m * 16 + kg;
        #pragma unroll
        for (int j = 0; j < 4; ++j) {
            int grow = grow_base + j;
            if (grow >= M) continue;
            #pragma unroll
            for (int n = 0; n < 4; ++n) {
                int gcol = col0 + wc * 64 + n * 16 + l15;
                if (gcol >= Nw) continue;
                outF[(size_t)grow * ldo + gcol] = acc[m][n][j];
            }
        }
    }
}

// ---------------- split-K MFMA: partials (f32), grid.z = K-chunk ------------
__global__ __launch_bounds__(256) void mfma_splitk_kernel(
    const ushort* __restrict__ A, const ushort* __restrict__ Bt,
    int M, int K, int lda, int kChunk, int Ntot,
    float* __restrict__ part)
{
    __shared__ __align__(16) ushort As[128 * LDT];
    __shared__ __align__(16) ushort Bs[128 * LDT];
    const int tid  = threadIdx.x;
    const int row0 = blockIdx.y * 128;
    const int col0 = blockIdx.x * 128;
    const int wid  = tid >> 6, lane = tid & 63;
    const int wr = wid >> 1, wc = wid & 1;
    const int l15 = lane & 15, lg = lane >> 4;
    const int kg = lg * 4;
    const int sr = tid >> 2;
    const int sc = (tid & 3) * 8;

    const int k0s = blockIdx.z * kChunk;
    const int k0e = (k0s + kChunk < K) ? k0s + kChunk : K;

    const ushort* pA0 = A  + (size_t)(row0 + sr)      * lda + sc;
    const ushort* pA1 = A  + (size_t)(row0 + sr + 64) * lda + sc;
    const ushort* pB0 = Bt + (size_t)(col0 + sr)      * lda + sc;
    const ushort* pB1 = Bt + (size_t)(col0 + sr + 64) * lda + sc;

    uint4 ra0 = *reinterpret_cast<const uint4*>(pA0 + k0s);
    uint4 ra1 = *reinterpret_cast<const uint4*>(pA1 + k0s);
    uint4 rb0 = *reinterpret_cast<const uint4*>(pB0 + k0s);
    uint4 rb1 = *reinterpret_cast<const uint4*>(pB1 + k0s);

    f32x4 acc[4][4];
    #pragma unroll
    for (int m = 0; m < 4; ++m)
        #pragma unroll
        for (int n = 0; n < 4; ++n) acc[m][n] = (f32x4)0.f;

    for (int k0 = k0s; k0 < k0e; k0 += 32) {
        *reinterpret_cast<uint4*>(&As[sr * LDT + sc])        = ra0;
        *reinterpret_cast<uint4*>(&As[(sr + 64) * LDT + sc]) = ra1;
        *reinterpret_cast<uint4*>(&Bs[sr * LDT + sc])        = rb0;
        *reinterpret_cast<uint4*>(&Bs[(sr + 64) * LDT + sc]) = rb1;
        __syncthreads();
        if (k0 + 32 < k0e) {
            ra0 = *reinterpret_cast<const uint4*>(pA0 + k0 + 32);
            ra1 = *reinterpret_cast<const uint4*>(pA1 + k0 + 32);
            rb0 = *reinterpret_cast<const uint4*>(pB0 + k0 + 32);
            rb1 = *reinterpret_cast<const uint4*>(pB1 + k0 + 32);
        }

        bf16x8v af[4], bfr[4];
        #pragma unroll
        for (int m = 0; m < 4; ++m) {
            int ar = wr * 64 + m * 16 + l15;
            bf16x4v lo = *reinterpret_cast<const bf16x4v*>(&As[ar * LDT + kg]);
            bf16x4v hi = *reinterpret_cast<const bf16x4v*>(&As[ar * LDT + kg + 16]);
            af[m] = __builtin_shufflevector(lo, hi, 0, 1, 2, 3, 4, 5, 6, 7);
        }
        #pragma unroll
        for (int n = 0; n < 4; ++n) {
            int br = wc * 64 + n * 16 + l15;
            bf16x4v lo = *reinterpret_cast<const bf16x4v*>(&Bs[br * LDT + kg]);
            bf16x4v hi = *reinterpret_cast<const bf16x4v*>(&Bs[br * LDT + kg + 16]);
            bfr[n] = __builtin_shufflevector(lo, hi, 0, 1, 2, 3, 4, 5, 6, 7);
        }
        #pragma unroll
        for (int m = 0; m < 4; ++m)
            #pragma unroll
            for (int n = 0; n < 4; ++n)
                acc[m][n] = __builtin_amdgcn_mfma_f32_16x16x32_bf16(af[m], bfr[n], acc[m][n], 0, 0, 0);
        __syncthreads();
    }

    float* pslab = part + (size_t)blockIdx.z * M * Ntot;
    #pragma unroll
    for (int m = 0; m < 4; ++m) {
        int grow_base = row0 + wr * 64 + m * 16 + kg;
        #pragma unroll
        for (int j = 0; j < 4; ++j) {
            int grow = grow_base + j;
            if (grow >= M) continue;
            #pragma unroll
            for (int n = 0; n < 4; ++n) {
                int gcol = col0 + wc * 64 + n * 16 + l15;
                pslab[(size_t)grow * Ntot + gcol] = acc[m][n][j];
            }
        }
    }
}

__global__ void reduce_tanh_kernel(const float* __restrict__ part, int S, int M, int N,
                                   const float* __restrict__ rs, float* __restrict__ out) {
    int i = blockIdx.x * blockDim.x + threadIdx.x;
    if (i >= M * N) return;
    int r = i / N;
    float s = 0.f;
    for (int z = 0; z < S; ++z) s += part[(size_t)z * M * N + i];
    if (rs) s *= rs[r];
    out[i] = tanhf(s);
}

// ---------------- conversion / fusion helpers -------------------------------
__global__ void transpose_cvt_kernel(const float* __restrict__ in, int K, int N, int ldin,
                                     ushort* __restrict__ out, int Kp) {
    int i = blockIdx.x * blockDim.x + threadIdx.x;
    if (i >= N * Kp) return;
    int n = i / Kp, k = i % Kp;
    float v = (k < K) ? in[(size_t)k * ldin + n] : 0.f;
    out[i] = f2bf(v);
}

__global__ void make_cat_weights_kernel(
    const float* __restrict__ w_sh1, const float* __restrict__ w_sh1h,
    const float* __restrict__ b_sh1, const float* __restrict__ b_sh1h,
    const float* __restrict__ w_sh2, const float* __restrict__ w_sh2h,
    const float* __restrict__ b_sh2, const float* __restrict__ b_sh2h,
    const float* __restrict__ w_mlp1, const float* __restrict__ w_mlp1h,
    const float* __restrict__ b_mlp1, const float* __restrict__ b_mlp1h,
    float* __restrict__ W1cat, float* __restrict__ b1cat,
    float* __restrict__ W2bd,  float* __restrict__ b2cat,
    float* __restrict__ WMbd,  float* __restrict__ bMcat)
{
    int i = blockIdx.x * blockDim.x + threadIdx.x;
    if (i < 64 * 128) {
        int k = i >> 7, j = i & 127;
        W1cat[i] = (j < 64) ? w_sh1[k * 64 + j] : w_sh1h[k * 64 + (j - 64)];
        return;
    }
    i -= 64 * 128;
    if (i < 128) { b1cat[i] = (i < 64) ? b_sh1[i] : b_sh1h[i - 64]; return; }
    i -= 128;
    if (i < 128 * 128) {
        int k = i >> 7, j = i & 127;
        float v = 0.f;
        if (k < 64 && j < 64) v = w_sh2[k * 64 + j];
        else if (k >= 64 && j >= 64) v = w_sh2h[(k - 64) * 64 + (j - 64)];
        W2bd[i] = v;
        return;
    }
    i -= 128 * 128;
    if (i < 128) { b2cat[i] = (i < 64) ? b_sh2[i] : b_sh2h[i - 64]; return; }
    i -= 128;
    if (i < 128 * 512) {
        int k = i >> 9, j = i & 511;
        float v = 0.f;
        if (j < 256) { if (k < 64) v = w_mlp1[k * 256 + j]; }
        else         { if (k >= 64) v = w_mlp1h[(k - 64) * 256 + (j - 256)]; }
        WMbd[i] = v;
        return;
    }
    i -= 128 * 512;
    if (i < 512) { bMcat[i] = (i < 256) ? b_mlp1[i] : b_mlp1h[i - 256]; }
}

__global__ void avg3cat_kernel(const float* __restrict__ emb, const float* __restrict__ x2cat,
                               const float* __restrict__ x6cat, float* __restrict__ o) {
    int i = blockIdx.x * blockDim.x + threadIdx.x;
    if (i >= N_SH * 128) return;
    int r = i >> 7, j = i & 127;
    o[i] = (emb[r * 64 + (j & 63)] + x2cat[i] + x6cat[i]) * (1.0f / 3.0f);
}

__global__ void concat_hh_kernel(const float* __restrict__ emb, const float* __restrict__ kg,
                                 float* __restrict__ out) {
    int i = blockIdx.x * blockDim.x + threadIdx.x;
    const int n = N_HH * 91;
    if (i >= n) return;
    int r = i / 91, c = i % 91;
    out[i] = (c < DIM) ? emb[r * DIM + c] : kg[r * 27 + (c - DIM)];
}

__global__ void make_esbt_kernel(const float* __restrict__ x9cat, const float* __restrict__ ss1,
                                 ushort* __restrict__ out, int Kp) {
    int i = blockIdx.x * blockDim.x + threadIdx.x;
    if (i >= 256 * Kp) return;
    int n = i / Kp, k = i % Kp;
    float v = (k < N_SS) ? (x9cat[(size_t)k * 512 + n] + ss1[(size_t)k * 256 + n]) : 0.f;
    out[i] = f2bf(v);
}

__global__ void make_wmlp2_kernel(const float* __restrict__ wm, ushort* __restrict__ out) {
    int i = blockIdx.x * blockDim.x + threadIdx.x;
    if (i >= 256 * 512) return;
    int n = i >> 9, k = i & 511;
    out[i] = f2bf(wm[(size_t)(k & 255) * 256 + n]);
}

__global__ void make_ehb_kernel(const float* __restrict__ x9cat, const float* __restrict__ hh1,
                                ushort* __restrict__ out, int Rp) {
    int i = blockIdx.x * blockDim.x + threadIdx.x;
    if (i >= Rp * 256) return;
    int r = i >> 8, c = i & 255;
    float v = (r < N_HH) ? (x9cat[(size_t)(N_SS + r) * 512 + 256 + c] + hh1[(size_t)r * 256 + c]) : 0.f;
    out[i] = f2bf(v);
}

// ---------------- BatchNorm -------------------------------------------------
__global__ void bn_stats_cat_kernel(const float* __restrict__ X, int M,
                                    float* __restrict__ stats) {
    int j = threadIdx.x;  // 512
    float s = 0.f, ss = 0.f;
    for (int r = blockIdx.x; r < M; r += gridDim.x) {
        float v = X[(size_t)r * 512 + j];
        s += v; ss += v * v;
    }
    atomicAdd(&stats[j], s);
    atomicAdd(&stats[512 + j], ss);
}

__global__ void bn_apply_cat_kernel(const float* __restrict__ X, const float* __restrict__ stats,
                                    const float* __restrict__ g1, const float* __restrict__ be1,
                                    const float* __restrict__ g2, const float* __restrict__ be2,
                                    int M, float* __restrict__ out) {
    int i = blockIdx.x * blockDim.x + threadIdx.x;
    if (i >= M * 512) return;
    int j = i & 511;
    float invM = 1.0f / (float)M;
    float mean = stats[j] * invM;
    float var  = fmaxf(stats[512 + j] * invM - mean * mean, 0.f);
    float ga = (j < 256) ? g1[j]  : g2[j - 256];
    float bb = (j < 256) ? be1[j] : be2[j - 256];
    float y = (X[i] - mean) * rsqrtf(var + 1e-5f) * ga + bb;
    out[i] = tanhf(y);
}

__global__ void bn_finalize_kernel(const float* __restrict__ stats,
                                   const float* __restrict__ g, const float* __restrict__ be,
                                   int M, float* __restrict__ scale, float* __restrict__ shift) {
    int j = threadIdx.x;  // 256
    float invM = 1.0f / (float)M;
    float mean = stats[j] * invM;
    float var  = fmaxf(stats[256 + j] * invM - mean * mean, 0.f);
    float sc = g[j] * rsqrtf(var + 1e-5f);
    scale[j] = sc;
    shift[j] = be[j] - mean * sc;
}

// ---------------- driver -----------------------------------------------------
extern "C" void kernel_launch(void* const* d_in, const int* in_sizes, int n_in,
                              void* d_out, int out_size, void* d_ws, size_t ws_size,
                              hipStream_t stream) {
    const int*   eiSH = (const int*)d_in[1];
    const int*   eiSS = (const int*)d_in[3];
    const int*   eiHH = (const int*)d_in[5];
    const float* P    = (const float*)d_in[6];
    const float* kg   = (const float*)d_in[7];
    const float* emb  = (const float*)d_in[8];
    const float* w_sh1  = (const float*)d_in[9];   const float* b_sh1  = (const float*)d_in[10];
    const float* w_sh2  = (const float*)d_in[11];  const float* b_sh2  = (const float*)d_in[12];
    const float* w_mlp1 = (const float*)d_in[13];  const float* b_mlp1 = (const float*)d_in[14];
    const float* g_bn1  = (const float*)d_in[15];  const float* be_bn1 = (const float*)d_in[16];
    const float* w_sh1h = (const float*)d_in[17];  const float* b_sh1h = (const float*)d_in[18];
    const float* w_sh2h = (const float*)d_in[19];  const float* b_sh2h = (const float*)d_in[20];
    const float* w_mlp1h= (const float*)d_in[21];  const float* b_mlp1h= (const float*)d_in[22];
    const float* g_bn1h = (const float*)d_in[23];  const float* be_bn1h= (const float*)d_in[24];
    const float* w_ss   = (const float*)d_in[25];  const float* b_ss   = (const float*)d_in[26];
    const float* w_hh   = (const float*)d_in[27];  const float* b_hh   = (const float*)d_in[28];
    const float* w_mlp  = (const float*)d_in[29];  const float* b_mlp  = (const float*)d_in[30];
    const float* g_si   = (const float*)d_in[31];  const float* be_si  = (const float*)d_in[32];
    float* out = (float*)d_out;

    const int E_SH = in_sizes[1] / 2;
    const int E_SS = in_sizes[3] / 2;
    const int E_HH = in_sizes[5] / 2;
    const int B    = in_sizes[6] / N_SS;      // 20000
    const int Mp   = ((B + 127) / 128) * 128; // 20096
    const int KP1  = 416;
    const int NP3  = 896;
    const int KSH  = 1216;
    const int KHH  = 832;
    const int HS_SH = (N_SH + 1) / 2;   // 598
    const int HS_SS = (N_SS + 1) / 2;   // 195
    const int HS_HH = (N_HH + 1) / 2;   // 403

    float* w = (float*)d_ws;
    size_t off = 0;
    auto alloc = [&](size_t n) { float* p = w + off; off += (n + 3) & ~(size_t)3; return p; };

    float* cntInv  = alloc(N_SH);
    float* stats   = alloc(1024);
    float* bnScale = alloc(256);
    float* bnShift = alloc(256);
    float* W1cat   = alloc(64 * 128);
    float* b1cat   = alloc(128);
    float* W2bd    = alloc(128 * 128);
    float* b2cat   = alloc(128);
    float* WMbd    = alloc(128 * 512);
    float* bMcat   = alloc(512);
    ushort* adjb   = (ushort*)alloc((size_t)1280 * KSH / 2);
    ushort* adjSSb = (ushort*)alloc((size_t)512 * KP1 / 2);
    ushort* adjHHb = (ushort*)alloc((size_t)896 * KHH / 2);
    float* tmpL    = alloc((size_t)N_SH * 128);
    ushort* HT     = (ushort*)alloc((size_t)128 * KSH / 2);
    float* x2cat   = alloc((size_t)N_SH * 128);
    float* x6cat   = alloc((size_t)N_SH * 128);
    float* x9a2    = alloc((size_t)N_SH * 128);
    float* tmpBN   = alloc((size_t)N_SH * 512);
    float* x9cat   = alloc((size_t)N_SH * 512);
    float* ss1     = alloc((size_t)N_SS * 256);
    float* hh1     = alloc((size_t)N_HH * 256);
    float* xhh0    = alloc((size_t)N_HH * 91);
    ushort* HSST   = (ushort*)alloc((size_t)256 * KP1 / 2);
    ushort* HHHT   = (ushort*)alloc((size_t)256 * KHH / 2);
    ushort* es_bT  = (ushort*)alloc((size_t)256 * KP1 / 2);
    ushort* wmlp2  = (ushort*)alloc((size_t)256 * 512 / 2);
    ushort* eh_b   = (ushort*)alloc((size_t)NP3 * 256 / 2);
    // region A: packed adjacency tables (early) -> bufM f32 [Mp][256]
    float* regionA = alloc((size_t)Mp * 256);
    uint32_t* uSH  = (uint32_t*)regionA;
    uint32_t* uSS  = uSH + (size_t)N_SH * HS_SH;
    uint32_t* uHH  = uSS + (size_t)N_SS * HS_SS;
    size_t packed_words = (size_t)N_SH * HS_SH + (size_t)N_SS * HS_SS + (size_t)N_HH * HS_HH;
    float*  bufM   = regionA;
    // region B: split-K partials (early) -> e_hilo bf16 [Mp][512]
    float* regionB = alloc((size_t)Mp * 256);
    float*  partials = regionB;
    ushort* e_hilo = (ushort*)regionB;
    (void)ws_size; (void)n_in; (void)out_size;

    auto gemm = [&](const float* Am, const float* Bm, const float* bias, const float* rs,
                    float* C, int M, int N, int K, int act) {
        dim3 g((N + BN - 1) / BN, (M + BM - 1) / BM);
        gemm_kernel<<<g, 256, 0, stream>>>(Am, Bm, bias, rs, C, M, N, K, act);
    };
    auto mgemm = [&](const ushort* Am, const ushort* Bm, int M, int Np, int Nw, int K, int lda,
                     const float* bias, const float* rs,
                     float* oF, ushort* oB, ushort* oLo, int ldo, float* st) {
        dim3 g(Np / 128, (M + 127) / 128);
        mfma_gemm_kernel<<<g, 256, 0, stream>>>(Am, Bm, M, Nw, K, lda, bias, rs, oF, oB, oLo, ldo, st);
    };
    auto splitk = [&](const ushort* Am, const ushort* Bm, int M, int Mtiles, int K, int lda,
                      int Ntot, int S, const float* rs, float* outp) {
        dim3 g(Ntot / 128, Mtiles, S);
        mfma_splitk_kernel<<<g, 256, 0, stream>>>(Am, Bm, M, K, lda, 128, Ntot, partials);
        reduce_tanh_kernel<<<(M * Ntot + 255) / 256, 256, 0, stream>>>(partials, S, M, Ntot, rs, outp);
    };

    // ---- adjacency (packed 16-bit atomic counts -> bf16 unpack) ----
    hipMemsetAsync(uSH, 0, packed_words * sizeof(uint32_t), stream);
    build_adj_packed_kernel<<<(E_SH + 255) / 256, 256, 0, stream>>>(eiSH, E_SH, HS_SH, uSH);
    build_adj_packed_kernel<<<(E_SS + 255) / 256, 256, 0, stream>>>(eiSS, E_SS, HS_SS, uSS);
    build_adj_packed_kernel<<<(E_HH + 255) / 256, 256, 0, stream>>>(eiHH, E_HH, HS_HH, uHH);
    rowsum_inv_packed_kernel<<<(N_SH + 3) / 4, 256, 0, stream>>>(uSH, N_SH, HS_SH, cntInv);
    cvt_unpack_kernel<<<(1280 * KSH + 255) / 256, 256, 0, stream>>>(uSH, N_SH, N_SH, HS_SH, adjb, 1280, KSH);
    cvt_unpack_kernel<<<(512 * KP1 + 255) / 256, 256, 0, stream>>>(uSS, N_SS, N_SS, HS_SS, adjSSb, 512, KP1);
    cvt_unpack_kernel<<<(896 * KHH + 255) / 256, 256, 0, stream>>>(uHH, N_HH, N_HH, HS_HH, adjHHb, 896, KHH);

    make_cat_weights_kernel<<<(90880 + 255) / 256, 256, 0, stream>>>(
        w_sh1, w_sh1h, b_sh1, b_sh1h, w_sh2, w_sh2h, b_sh2, b_sh2h,
        w_mlp1, w_mlp1h, b_mlp1, b_mlp1h,
        W1cat, b1cat, W2bd, b2cat, WMbd, bMcat);

    // ---- SH layers (fused branches) ----
    gemm(emb, W1cat, b1cat, nullptr, tmpL, N_SH, 128, 64, 0);
    transpose_cvt_kernel<<<(128 * KSH + 255) / 256, 256, 0, stream>>>(tmpL, N_SH, 128, 128, HT, KSH);
    splitk(adjb, HT, N_SH, 10, KSH, KSH, 128, 10, cntInv, x2cat);
    gemm(x2cat, W2bd, b2cat, nullptr, tmpL, N_SH, 128, 128, 0);
    transpose_cvt_kernel<<<(128 * KSH + 255) / 256, 256, 0, stream>>>(tmpL, N_SH, 128, 128, HT, KSH);
    splitk(adjb, HT, N_SH, 10, KSH, KSH, 128, 10, cntInv, x6cat);
    avg3cat_kernel<<<(N_SH * 128 + 255) / 256, 256, 0, stream>>>(emb, x2cat, x6cat, x9a2);
    gemm(x9a2, WMbd, bMcat, nullptr, tmpBN, N_SH, 512, 128, 0);
    hipMemsetAsync(stats, 0, 1024 * sizeof(float), stream);
    bn_stats_cat_kernel<<<64, 512, 0, stream>>>(tmpBN, N_SH, stats);
    bn_apply_cat_kernel<<<(N_SH * 512 + 255) / 256, 256, 0, stream>>>(
        tmpBN, stats, g_bn1, be_bn1, g_bn1h, be_bn1h, N_SH, x9cat);

    // ---- SS graph ----
    gemm(emb, w_ss, b_ss, nullptr, tmpBN, N_SS, 256, 64, 0);
    transpose_cvt_kernel<<<(256 * KP1 + 255) / 256, 256, 0, stream>>>(tmpBN, N_SS, 256, 256, HSST, KP1);
    splitk(adjSSb, HSST, N_SS, 4, KP1, KP1, 256, 4, nullptr, ss1);

    // ---- HH graph ----
    concat_hh_kernel<<<(N_HH * 91 + 255) / 256, 256, 0, stream>>>(emb, kg, xhh0);
    gemm(xhh0, w_hh, b_hh, nullptr, tmpBN, N_HH, 256, 91, 0);
    transpose_cvt_kernel<<<(256 * KHH + 255) / 256, 256, 0, stream>>>(tmpBN, N_HH, 256, 256, HHHT, KHH);
    splitk(adjHHb, HHHT, N_HH, 7, KHH, KHH, 256, 7, nullptr, hh1);

    // ---- prepare bf16 operands for prescription path ----
    make_esbt_kernel<<<(256 * KP1 + 255) / 256, 256, 0, stream>>>(x9cat, ss1, es_bT, KP1);
    make_wmlp2_kernel<<<(256 * 512 + 255) / 256, 256, 0, stream>>>(w_mlp, wmlp2);
    make_ehb_kernel<<<(NP3 * 256 + 255) / 256, 256, 0, stream>>>(x9cat, hh1, eh_b, NP3);
    hipMemsetAsync(stats, 0, 512 * sizeof(float), stream);

    // ---- prescription path (bf16 MFMA, prefetched) ----
    // C1: e = (P @ es) / rowsum(P), P read f32 with fused conversion + row-sum
    {
        dim3 g(2, (B + 127) / 128);
        mfma_c1_kernel<<<g, 256, 0, stream>>>(P, es_bT, B, e_hilo, e_hilo + 256, 512);
    }
    // C2: bufM = (e_hi + e_lo) @ w_mlp + b_mlp; BN col-stats fused in epilogue
    mgemm(e_hilo, wmlp2, B, 256, 256, 512, 512, b_mlp, nullptr,
          bufM, nullptr, nullptr, 256, stats);
    bn_finalize_kernel<<<1, 256, 0, stream>>>(stats, g_si, be_si, B, bnScale, bnShift);
    // C3: out = relu(BN(bufM)) @ eh^T (BN fused into A-staging, prefetched)
    {
        dim3 g(NP3 / 128, (B + 127) / 128);
        mfma_c3_kernel<<<g, 256, 0, stream>>>(bufM, eh_b, B, N_HH, bnScale, bnShift, out, N_HH);
    }
}

// Round 9
// 317.963 us; speedup vs baseline: 1.4103x; 1.0770x over previous
//
#include <hip/hip_runtime.h>
#include <cstddef>
#include <cstdint>

#define N_SH 1195
#define N_SS 390
#define N_HH 805
#define DIM  64

typedef __bf16 bf16_t;
typedef bf16_t bf16x4v __attribute__((ext_vector_type(4)));
typedef bf16_t bf16x8v __attribute__((ext_vector_type(8)));
typedef float f32x4 __attribute__((ext_vector_type(4)));

__device__ inline ushort f2bf(float f) {
    union { float f; uint32_t u; } c; c.f = f;
    uint32_t u = c.u;
    u += 0x7FFFu + ((u >> 16) & 1u);
    return (ushort)(u >> 16);
}

// bijective XCD swizzle (m204)
__device__ inline void xcd_swizzle(int gx, int gy, int& bx, int& by) {
    int nwg = gx * gy;
    int lin = by * gx + bx;
    int q = nwg >> 3, r = nwg & 7;
    int xcd = lin & 7, idx = lin >> 3;
    int nt = (xcd < r ? xcd * (q + 1) : r * (q + 1) + (xcd - r) * q) + idx;
    by = nt / gx; bx = nt % gx;
}

// ---------------- adjacency build: packed 2x16-bit counters, all 3 graphs ---
__global__ void build_adj3_kernel(
    const int* __restrict__ e1, int E1, int hs1, uint32_t* __restrict__ T1,
    const int* __restrict__ e2, int E2, int hs2, uint32_t* __restrict__ T2,
    const int* __restrict__ e3, int E3, int hs3, uint32_t* __restrict__ T3)
{
    int i = blockIdx.x * blockDim.x + threadIdx.x;
    if (i < E1) {
        int src = e1[i], dst = e1[E1 + i];
        atomicAdd(&T1[(size_t)dst * hs1 + (src >> 1)], 1u << ((src & 1) * 16));
    } else if (i < E1 + E2) {
        int j = i - E1;
        int src = e2[j], dst = e2[E2 + j];
        atomicAdd(&T2[(size_t)dst * hs2 + (src >> 1)], 1u << ((src & 1) * 16));
    } else if (i < E1 + E2 + E3) {
        int j = i - E1 - E2;
        int src = e3[j], dst = e3[E3 + j];
        atomicAdd(&T3[(size_t)dst * hs3 + (src >> 1)], 1u << ((src & 1) * 16));
    }
}

__global__ void rowsum_inv_packed_kernel(const uint32_t* __restrict__ T, int R,
                                         int halfStride, float* __restrict__ inv) {
    int row  = blockIdx.x * (blockDim.x / 64) + (threadIdx.x / 64);
    int lane = threadIdx.x & 63;
    if (row >= R) return;
    const uint32_t* p = T + (size_t)row * halfStride;
    uint32_t s = 0;
    for (int c = lane; c < halfStride; c += 64) {
        uint32_t w = p[c];
        s += (w & 0xFFFFu) + (w >> 16);
    }
    for (int off = 32; off > 0; off >>= 1) s += __shfl_down(s, off);
    if (lane == 0) inv[row] = 1.0f / fmaxf((float)s, 1.0f);
}

__device__ inline void unpack_one(const uint32_t* __restrict__ T, int R, int C,
                                  int hs, ushort* __restrict__ out, int Cp, int i) {
    int r = i / Cp, c = i % Cp;
    float v = 0.f;
    if (r < R && c < C) {
        uint32_t w = T[(size_t)r * hs + (c >> 1)];
        v = (float)((w >> ((c & 1) * 16)) & 0xFFFFu);
    }
    out[i] = f2bf(v);
}

// all three packed tables -> bf16 padded adjacencies, one grid
__global__ void cvt_unpack3_kernel(
    const uint32_t* __restrict__ T1, int hs1, ushort* __restrict__ o1, int n1, int Cp1,
    const uint32_t* __restrict__ T2, int hs2, ushort* __restrict__ o2, int n2, int Cp2,
    const uint32_t* __restrict__ T3, int hs3, ushort* __restrict__ o3, int n3, int Cp3)
{
    int i = blockIdx.x * blockDim.x + threadIdx.x;
    if (i < n1) { unpack_one(T1, N_SH, N_SH, hs1, o1, Cp1, i); return; }
    i -= n1;
    if (i < n2) { unpack_one(T2, N_SS, N_SS, hs2, o2, Cp2, i); return; }
    i -= n2;
    if (i < n3) { unpack_one(T3, N_HH, N_HH, hs3, o3, Cp3, i); }
}

// ---------------- fp32 GEMM: optional transposed-bf16 out + fused BN stats --
#define BM 64
#define BN 64
#define BK 16

__global__ __launch_bounds__(256) void gemm_kernel(
    const float* __restrict__ A, const float* __restrict__ B,
    const float* __restrict__ bias,
    float* __restrict__ C, ushort* __restrict__ outT, int ldt,
    int M, int N, int K, float* __restrict__ statsOut, int statsStride)
{
    __shared__ float As[BK][BM + 4];
    __shared__ float Bs[BK][BN];
    __shared__ float cs[128];
    const int tid  = threadIdx.x;
    const int row0 = blockIdx.y * BM;
    const int col0 = blockIdx.x * BN;
    const int tr  = (tid >> 4) << 2;
    const int tc  = (tid & 15) << 2;
    const int lar = tid >> 2;
    const int lac = (tid & 3) << 2;
    const int lbr = tid >> 4;
    const int lbc = (tid & 15) << 2;

    float acc[4][4] = {{0.f}};

    for (int k0 = 0; k0 < K; k0 += BK) {
        const int gr = row0 + lar;
        const float* Ap = A + (size_t)gr * K + k0 + lac;
        #pragma unroll
        for (int i = 0; i < 4; ++i) {
            int gk = k0 + lac + i;
            As[lac + i][lar] = (gr < M && gk < K) ? Ap[i] : 0.f;
        }
        const int gk = k0 + lbr;
        const float* Bp = B + (size_t)gk * N + col0 + lbc;
        #pragma unroll
        for (int i = 0; i < 4; ++i) {
            int gc = col0 + lbc + i;
            Bs[lbr][lbc + i] = (gk < K && gc < N) ? Bp[i] : 0.f;
        }
        __syncthreads();
        #pragma unroll
        for (int kk = 0; kk < BK; ++kk) {
            float4 a = *reinterpret_cast<const float4*>(&As[kk][tr]);
            float4 b = *reinterpret_cast<const float4*>(&Bs[kk][tc]);
            acc[0][0] += a.x * b.x; acc[0][1] += a.x * b.y; acc[0][2] += a.x * b.z; acc[0][3] += a.x * b.w;
            acc[1][0] += a.y * b.x; acc[1][1] += a.y * b.y; acc[1][2] += a.y * b.z; acc[1][3] += a.y * b.w;
            acc[2][0] += a.z * b.x; acc[2][1] += a.z * b.y; acc[2][2] += a.z * b.z; acc[2][3] += a.z * b.w;
            acc[3][0] += a.w * b.x; acc[3][1] += a.w * b.y; acc[3][2] += a.w * b.z; acc[3][3] += a.w * b.w;
        }
        __syncthreads();
    }

    float ls[4] = {0.f, 0.f, 0.f, 0.f}, lq[4] = {0.f, 0.f, 0.f, 0.f};
    #pragma unroll
    for (int i = 0; i < 4; ++i) {
        int gr = row0 + tr + i;
        if (gr >= M) continue;
        #pragma unroll
        for (int j = 0; j < 4; ++j) {
            int gc = col0 + tc + j;
            if (gc >= N) continue;
            float v = acc[i][j];
            if (bias) v += bias[gc];
            if (outT) outT[(size_t)gc * ldt + gr] = f2bf(v);
            else      C[(size_t)gr * N + gc] = v;
            ls[j] += v; lq[j] += v * v;
        }
    }

    if (statsOut) {
        if (tid < 128) cs[tid] = 0.f;
        __syncthreads();
        #pragma unroll
        for (int j = 0; j < 4; ++j) {
            atomicAdd(&cs[tc + j], ls[j]);
            atomicAdd(&cs[64 + tc + j], lq[j]);
        }
        __syncthreads();
        if (tid < 64) {
            atomicAdd(&statsOut[col0 + tid], cs[tid]);
            atomicAdd(&statsOut[statsStride + col0 + tid], cs[64 + tid]);
        }
    }
}

// ---------------- bf16 MFMA GEMM, 2-phase prefetch --------------------------
#define LDT 40

__global__ __launch_bounds__(256) void mfma_gemm_kernel(
    const ushort* __restrict__ A, const ushort* __restrict__ Bt,
    int M, int Nw, int K, int lda,
    const float* __restrict__ bias, const float* __restrict__ rowScale,
    float* __restrict__ outF, ushort* __restrict__ outB, ushort* __restrict__ outLo,
    int ldo, float* __restrict__ statsOut)
{
    __shared__ __align__(16) ushort As[128 * LDT];
    __shared__ __align__(16) ushort Bs[128 * LDT];
    __shared__ float cs[256];
    const int tid  = threadIdx.x;
    int bx = blockIdx.x, by = blockIdx.y;
    xcd_swizzle(gridDim.x, gridDim.y, bx, by);
    const int row0 = by * 128;
    const int col0 = bx * 128;
    const int wid  = tid >> 6, lane = tid & 63;
    const int wr = wid >> 1, wc = wid & 1;
    const int l15 = lane & 15, lg = lane >> 4;
    const int kg = lg * 4;
    const int sr = tid >> 2;
    const int sc = (tid & 3) * 8;

    const ushort* pA0 = A  + (size_t)(row0 + sr)      * lda + sc;
    const ushort* pA1 = A  + (size_t)(row0 + sr + 64) * lda + sc;
    const ushort* pB0 = Bt + (size_t)(col0 + sr)      * lda + sc;
    const ushort* pB1 = Bt + (size_t)(col0 + sr + 64) * lda + sc;

    uint4 ra0 = *reinterpret_cast<const uint4*>(pA0);
    uint4 ra1 = *reinterpret_cast<const uint4*>(pA1);
    uint4 rb0 = *reinterpret_cast<const uint4*>(pB0);
    uint4 rb1 = *reinterpret_cast<const uint4*>(pB1);

    f32x4 acc[4][4];
    #pragma unroll
    for (int m = 0; m < 4; ++m)
        #pragma unroll
        for (int n = 0; n < 4; ++n) acc[m][n] = (f32x4)0.f;

    for (int k0 = 0; k0 < K; k0 += 32) {
        *reinterpret_cast<uint4*>(&As[sr * LDT + sc])        = ra0;
        *reinterpret_cast<uint4*>(&As[(sr + 64) * LDT + sc]) = ra1;
        *reinterpret_cast<uint4*>(&Bs[sr * LDT + sc])        = rb0;
        *reinterpret_cast<uint4*>(&Bs[(sr + 64) * LDT + sc]) = rb1;
        __syncthreads();
        if (k0 + 32 < K) {
            ra0 = *reinterpret_cast<const uint4*>(pA0 + k0 + 32);
            ra1 = *reinterpret_cast<const uint4*>(pA1 + k0 + 32);
            rb0 = *reinterpret_cast<const uint4*>(pB0 + k0 + 32);
            rb1 = *reinterpret_cast<const uint4*>(pB1 + k0 + 32);
        }

        bf16x8v af[4], bfr[4];
        #pragma unroll
        for (int m = 0; m < 4; ++m) {
            int ar = wr * 64 + m * 16 + l15;
            bf16x4v lo = *reinterpret_cast<const bf16x4v*>(&As[ar * LDT + kg]);
            bf16x4v hi = *reinterpret_cast<const bf16x4v*>(&As[ar * LDT + kg + 16]);
            af[m] = __builtin_shufflevector(lo, hi, 0, 1, 2, 3, 4, 5, 6, 7);
        }
        #pragma unroll
        for (int n = 0; n < 4; ++n) {
            int br = wc * 64 + n * 16 + l15;
            bf16x4v lo = *reinterpret_cast<const bf16x4v*>(&Bs[br * LDT + kg]);
            bf16x4v hi = *reinterpret_cast<const bf16x4v*>(&Bs[br * LDT + kg + 16]);
            bfr[n] = __builtin_shufflevector(lo, hi, 0, 1, 2, 3, 4, 5, 6, 7);
        }
        #pragma unroll
        for (int m = 0; m < 4; ++m)
            #pragma unroll
            for (int n = 0; n < 4; ++n)
                acc[m][n] = __builtin_amdgcn_mfma_f32_16x16x32_bf16(af[m], bfr[n], acc[m][n], 0, 0, 0);
        __syncthreads();
    }

    float ls[4] = {0.f, 0.f, 0.f, 0.f}, lq[4] = {0.f, 0.f, 0.f, 0.f};
    #pragma unroll
    for (int m = 0; m < 4; ++m) {
        int grow_base = row0 + wr * 64 + m * 16 + kg;
        #pragma unroll
        for (int j = 0; j < 4; ++j) {
            int grow = grow_base + j;
            if (grow >= M) continue;
            float rs = rowScale ? rowScale[grow] : 1.0f;
            #pragma unroll
            for (int n = 0; n < 4; ++n) {
                int gcol = col0 + wc * 64 + n * 16 + l15;
                if (gcol >= Nw) continue;
                float v = acc[m][n][j];
                if (bias) v += bias[gcol];
                v *= rs;
                if (outB) {
                    ushort h = f2bf(v);
                    outB[(size_t)grow * ldo + gcol] = h;
                    if (outLo) {
                        float hv = __uint_as_float(((uint32_t)h) << 16);
                        outLo[(size_t)grow * ldo + gcol] = f2bf(v - hv);
                    }
                } else {
                    outF[(size_t)grow * ldo + gcol] = v;
                    ls[n] += v; lq[n] += v * v;
                }
            }
        }
    }

    if (statsOut) {
        if (tid < 256) cs[tid] = 0.f;
        __syncthreads();
        #pragma unroll
        for (int n = 0; n < 4; ++n) {
            int lc = wc * 64 + n * 16 + l15;
            atomicAdd(&cs[lc], ls[n]);
            atomicAdd(&cs[128 + lc], lq[n]);
        }
        __syncthreads();
        if (tid < 128) {
            atomicAdd(&statsOut[col0 + tid], cs[tid]);
            atomicAdd(&statsOut[256 + col0 + tid], cs[128 + tid]);
        }
    }
}

// ---------------- C1: A = P (f32, masked), fused row-sum; out hi/lo bf16 ----
__device__ inline void loadP8(const float* __restrict__ rowp, int c0, bool rv,
                              float* a, float& s) {
    if (rv && c0 + 8 <= N_SS) {
        float2 x0 = *reinterpret_cast<const float2*>(rowp + c0);
        float2 x1 = *reinterpret_cast<const float2*>(rowp + c0 + 2);
        float2 x2 = *reinterpret_cast<const float2*>(rowp + c0 + 4);
        float2 x3 = *reinterpret_cast<const float2*>(rowp + c0 + 6);
        a[0] = x0.x; a[1] = x0.y; a[2] = x1.x; a[3] = x1.y;
        a[4] = x2.x; a[5] = x2.y; a[6] = x3.x; a[7] = x3.y;
    } else {
        #pragma unroll
        for (int i = 0; i < 8; ++i) a[i] = (rv && (c0 + i) < N_SS) ? rowp[c0 + i] : 0.f;
    }
    #pragma unroll
    for (int i = 0; i < 8; ++i) s += a[i];
}

__global__ __launch_bounds__(256) void mfma_c1_kernel(
    const float* __restrict__ Pm, const ushort* __restrict__ Bt,
    int M, ushort* __restrict__ outB, ushort* __restrict__ outLo, int ldo)
{
    __shared__ __align__(16) ushort As[128 * LDT];
    __shared__ __align__(16) ushort Bs[128 * LDT];
    __shared__ float sums[128];
    const int tid  = threadIdx.x;
    int bx = blockIdx.x, by = blockIdx.y;
    xcd_swizzle(gridDim.x, gridDim.y, bx, by);
    const int row0 = by * 128;
    const int col0 = bx * 128;
    const int wid  = tid >> 6, lane = tid & 63;
    const int wr = wid >> 1, wc = wid & 1;
    const int l15 = lane & 15, lg = lane >> 4;
    const int kg = lg * 4;
    const int sr = tid >> 2;
    const int sc = (tid & 3) * 8;

    const float* pA0 = Pm + (size_t)(row0 + sr)      * N_SS;
    const float* pA1 = Pm + (size_t)(row0 + sr + 64) * N_SS;
    const bool rv0 = (row0 + sr)      < M;
    const bool rv1 = (row0 + sr + 64) < M;
    const ushort* pB0 = Bt + (size_t)(col0 + sr)      * 416 + sc;
    const ushort* pB1 = Bt + (size_t)(col0 + sr + 64) * 416 + sc;

    float a0[8], a1[8];
    float s0 = 0.f, s1 = 0.f;
    loadP8(pA0, sc, rv0, a0, s0);
    loadP8(pA1, sc, rv1, a1, s1);
    uint4 b0 = *reinterpret_cast<const uint4*>(pB0);
    uint4 b1 = *reinterpret_cast<const uint4*>(pB1);

    f32x4 acc[4][4];
    #pragma unroll
    for (int m = 0; m < 4; ++m)
        #pragma unroll
        for (int n = 0; n < 4; ++n) acc[m][n] = (f32x4)0.f;

    for (int k0 = 0; k0 < 416; k0 += 32) {
        {
            bf16_t h[8];
            #pragma unroll
            for (int i = 0; i < 8; ++i) h[i] = (bf16_t)a0[i];
            *reinterpret_cast<uint4*>(&As[sr * LDT + sc]) = *reinterpret_cast<const uint4*>(h);
            #pragma unroll
            for (int i = 0; i < 8; ++i) h[i] = (bf16_t)a1[i];
            *reinterpret_cast<uint4*>(&As[(sr + 64) * LDT + sc]) = *reinterpret_cast<const uint4*>(h);
        }
        *reinterpret_cast<uint4*>(&Bs[sr * LDT + sc])        = b0;
        *reinterpret_cast<uint4*>(&Bs[(sr + 64) * LDT + sc]) = b1;
        __syncthreads();
        if (k0 + 32 < 416) {
            loadP8(pA0, k0 + 32 + sc, rv0, a0, s0);
            loadP8(pA1, k0 + 32 + sc, rv1, a1, s1);
            b0 = *reinterpret_cast<const uint4*>(pB0 + k0 + 32);
            b1 = *reinterpret_cast<const uint4*>(pB1 + k0 + 32);
        }

        bf16x8v af[4], bfr[4];
        #pragma unroll
        for (int m = 0; m < 4; ++m) {
            int ar = wr * 64 + m * 16 + l15;
            bf16x4v lo = *reinterpret_cast<const bf16x4v*>(&As[ar * LDT + kg]);
            bf16x4v hi = *reinterpret_cast<const bf16x4v*>(&As[ar * LDT + kg + 16]);
            af[m] = __builtin_shufflevector(lo, hi, 0, 1, 2, 3, 4, 5, 6, 7);
        }
        #pragma unroll
        for (int n = 0; n < 4; ++n) {
            int br = wc * 64 + n * 16 + l15;
            bf16x4v lo = *reinterpret_cast<const bf16x4v*>(&Bs[br * LDT + kg]);
            bf16x4v hi = *reinterpret_cast<const bf16x4v*>(&Bs[br * LDT + kg + 16]);
            bfr[n] = __builtin_shufflevector(lo, hi, 0, 1, 2, 3, 4, 5, 6, 7);
        }
        #pragma unroll
        for (int m = 0; m < 4; ++m)
            #pragma unroll
            for (int n = 0; n < 4; ++n)
                acc[m][n] = __builtin_amdgcn_mfma_f32_16x16x32_bf16(af[m], bfr[n], acc[m][n], 0, 0, 0);
        __syncthreads();
    }

    if (tid < 128) sums[tid] = 0.f;
    __syncthreads();
    atomicAdd(&sums[sr], s0);
    atomicAdd(&sums[sr + 64], s1);
    __syncthreads();

    #pragma unroll
    for (int m = 0; m < 4; ++m) {
        int lr_base = wr * 64 + m * 16 + kg;
        #pragma unroll
        for (int j = 0; j < 4; ++j) {
            int lr = lr_base + j;
            int grow = row0 + lr;
            if (grow >= M) continue;
            float t = sums[lr];
            float inv = (t != 0.f) ? 1.0f / t : 0.f;
            #pragma unroll
            for (int n = 0; n < 4; ++n) {
                int gcol = col0 + wc * 64 + n * 16 + l15;
                float v = acc[m][n][j] * inv;
                ushort h = f2bf(v);
                outB[(size_t)grow * ldo + gcol] = h;
                float hv = __uint_as_float(((uint32_t)h) << 16);
                outLo[(size_t)grow * ldo + gcol] = f2bf(v - hv);
            }
        }
    }
}

// ---------------- C3: A = relu(bufM*scale+shift) f32->bf16, K=256, prefetch -
__global__ __launch_bounds__(256) void mfma_c3_kernel(
    const float* __restrict__ Abuf, const ushort* __restrict__ Bt,
    int M, int Nw,
    const float* __restrict__ scale, const float* __restrict__ shift,
    float* __restrict__ outF, int ldo)
{
    __shared__ __align__(16) ushort As[128 * LDT];
    __shared__ __align__(16) ushort Bs[128 * LDT];
    const int tid  = threadIdx.x;
    int bx = blockIdx.x, by = blockIdx.y;
    xcd_swizzle(gridDim.x, gridDim.y, bx, by);
    const int row0 = by * 128;
    const int col0 = bx * 128;
    const int wid  = tid >> 6, lane = tid & 63;
    const int wr = wid >> 1, wc = wid & 1;
    const int l15 = lane & 15, lg = lane >> 4;
    const int kg = lg * 4;
    const int sr = tid >> 2;
    const int sc = (tid & 3) * 8;

    const float*  pA0 = Abuf + (size_t)(row0 + sr)      * 256 + sc;
    const float*  pA1 = Abuf + (size_t)(row0 + sr + 64) * 256 + sc;
    const ushort* pB0 = Bt + (size_t)(col0 + sr)        * 256 + sc;
    const ushort* pB1 = Bt + (size_t)(col0 + sr + 64)   * 256 + sc;

    float4 a00 = *reinterpret_cast<const float4*>(pA0);
    float4 a01 = *reinterpret_cast<const float4*>(pA0 + 4);
    float4 a10 = *reinterpret_cast<const float4*>(pA1);
    float4 a11 = *reinterpret_cast<const float4*>(pA1 + 4);
    uint4  b0  = *reinterpret_cast<const uint4*>(pB0);
    uint4  b1  = *reinterpret_cast<const uint4*>(pB1);

    f32x4 acc[4][4];
    #pragma unroll
    for (int m = 0; m < 4; ++m)
        #pragma unroll
        for (int n = 0; n < 4; ++n) acc[m][n] = (f32x4)0.f;

    for (int k0 = 0; k0 < 256; k0 += 32) {
        float s8[8], t8[8];
        #pragma unroll
        for (int i = 0; i < 8; ++i) { s8[i] = scale[k0 + sc + i]; t8[i] = shift[k0 + sc + i]; }
        {
            bf16_t h[8];
            h[0] = (bf16_t)fmaxf(a00.x * s8[0] + t8[0], 0.f);
            h[1] = (bf16_t)fmaxf(a00.y * s8[1] + t8[1], 0.f);
            h[2] = (bf16_t)fmaxf(a00.z * s8[2] + t8[2], 0.f);
            h[3] = (bf16_t)fmaxf(a00.w * s8[3] + t8[3], 0.f);
            h[4] = (bf16_t)fmaxf(a01.x * s8[4] + t8[4], 0.f);
            h[5] = (bf16_t)fmaxf(a01.y * s8[5] + t8[5], 0.f);
            h[6] = (bf16_t)fmaxf(a01.z * s8[6] + t8[6], 0.f);
            h[7] = (bf16_t)fmaxf(a01.w * s8[7] + t8[7], 0.f);
            *reinterpret_cast<uint4*>(&As[sr * LDT + sc]) = *reinterpret_cast<const uint4*>(h);
            h[0] = (bf16_t)fmaxf(a10.x * s8[0] + t8[0], 0.f);
            h[1] = (bf16_t)fmaxf(a10.y * s8[1] + t8[1], 0.f);
            h[2] = (bf16_t)fmaxf(a10.z * s8[2] + t8[2], 0.f);
            h[3] = (bf16_t)fmaxf(a10.w * s8[3] + t8[3], 0.f);
            h[4] = (bf16_t)fmaxf(a11.x * s8[4] + t8[4], 0.f);
            h[5] = (bf16_t)fmaxf(a11.y * s8[5] + t8[5], 0.f);
            h[6] = (bf16_t)fmaxf(a11.z * s8[6] + t8[6], 0.f);
            h[7] = (bf16_t)fmaxf(a11.w * s8[7] + t8[7], 0.f);
            *reinterpret_cast<uint4*>(&As[(sr + 64) * LDT + sc]) = *reinterpret_cast<const uint4*>(h);
        }
        *reinterpret_cast<uint4*>(&Bs[sr * LDT + sc])        = b0;
        *reinterpret_cast<uint4*>(&Bs[(sr + 64) * LDT + sc]) = b1;
        __syncthreads();
        if (k0 + 32 < 256) {
            a00 = *reinterpret_cast<const float4*>(pA0 + k0 + 32);
            a01 = *reinterpret_cast<const float4*>(pA0 + k0 + 36);
            a10 = *reinterpret_cast<const float4*>(pA1 + k0 + 32);
            a11 = *reinterpret_cast<const float4*>(pA1 + k0 + 36);
            b0  = *reinterpret_cast<const uint4*>(pB0 + k0 + 32);
            b1  = *reinterpret_cast<const uint4*>(pB1 + k0 + 32);
        }

        bf16x8v af[4], bfr[4];
        #pragma unroll
        for (int m = 0; m < 4; ++m) {
            int ar = wr * 64 + m * 16 + l15;
            bf16x4v lo = *reinterpret_cast<const bf16x4v*>(&As[ar * LDT + kg]);
            bf16x4v hi = *reinterpret_cast<const bf16x4v*>(&As[ar * LDT + kg + 16]);
            af[m] = __builtin_shufflevector(lo, hi, 0, 1, 2, 3, 4, 5, 6, 7);
        }
        #pragma unroll
        for (int n = 0; n < 4; ++n) {
            int br = wc * 64 + n * 16 + l15;
            bf16x4v lo = *reinterpret_cast<const bf16x4v*>(&Bs[br * LDT + kg]);
            bf16x4v hi = *reinterpret_cast<const bf16x4v*>(&Bs[br * LDT + kg + 16]);
            bfr[n] = __builtin_shufflevector(lo, hi, 0, 1, 2, 3, 4, 5, 6, 7);
        }
        #pragma unroll
        for (int m = 0; m < 4; ++m)
            #pragma unroll
            for (int n = 0; n < 4; ++n)
                acc[m][n] = __builtin_amdgcn_mfma_f32_16x16x32_bf16(af[m], bfr[n], acc[m][n], 0, 0, 0);
        __syncthreads();
    }

    #pragma unroll
    for (int m = 0; m < 4; ++m) {
        int grow_base = row0 + wr * 64 + m * 16 + kg;
        #pragma unroll
        for (int j = 0; j < 4; ++j) {
            int grow = grow_base + j;
            if (grow >= M) continue;
            #pragma unroll
            for (int n = 0; n < 4; ++n) {
                int gcol = col0 + wc * 64 + n * 16 + l15;
                if (gcol >= Nw) continue;
                outF[(size_t)grow * ldo + gcol] = acc[m][n][j];
            }
        }
    }
}

// ---------------- split-K MFMA: partials (f32), grid.z = K-chunk ------------
__global__ __launch_bounds__(256) void mfma_splitk_kernel(
    const ushort* __restrict__ A, const ushort* __restrict__ Bt,
    int M, int K, int lda, int kChunk, int Ntot,
    float* __restrict__ part)
{
    __shared__ __align__(16) ushort As[128 * LDT];
    __shared__ __align__(16) ushort Bs[128 * LDT];
    const int tid  = threadIdx.x;
    const int row0 = blockIdx.y * 128;
    const int col0 = blockIdx.x * 128;
    const int wid  = tid >> 6, lane = tid & 63;
    const int wr = wid >> 1, wc = wid & 1;
    const int l15 = lane & 15, lg = lane >> 4;
    const int kg = lg * 4;
    const int sr = tid >> 2;
    const int sc = (tid & 3) * 8;

    const int k0s = blockIdx.z * kChunk;
    const int k0e = (k0s + kChunk < K) ? k0s + kChunk : K;

    const ushort* pA0 = A  + (size_t)(row0 + sr)      * lda + sc;
    const ushort* pA1 = A  + (size_t)(row0 + sr + 64) * lda + sc;
    const ushort* pB0 = Bt + (size_t)(col0 + sr)      * lda + sc;
    const ushort* pB1 = Bt + (size_t)(col0 + sr + 64) * lda + sc;

    uint4 ra0 = *reinterpret_cast<const uint4*>(pA0 + k0s);
    uint4 ra1 = *reinterpret_cast<const uint4*>(pA1 + k0s);
    uint4 rb0 = *reinterpret_cast<const uint4*>(pB0 + k0s);
    uint4 rb1 = *reinterpret_cast<const uint4*>(pB1 + k0s);

    f32x4 acc[4][4];
    #pragma unroll
    for (int m = 0; m < 4; ++m)
        #pragma unroll
        for (int n = 0; n < 4; ++n) acc[m][n] = (f32x4)0.f;

    for (int k0 = k0s; k0 < k0e; k0 += 32) {
        *reinterpret_cast<uint4*>(&As[sr * LDT + sc])        = ra0;
        *reinterpret_cast<uint4*>(&As[(sr + 64) * LDT + sc]) = ra1;
        *reinterpret_cast<uint4*>(&Bs[sr * LDT + sc])        = rb0;
        *reinterpret_cast<uint4*>(&Bs[(sr + 64) * LDT + sc]) = rb1;
        __syncthreads();
        if (k0 + 32 < k0e) {
            ra0 = *reinterpret_cast<const uint4*>(pA0 + k0 + 32);
            ra1 = *reinterpret_cast<const uint4*>(pA1 + k0 + 32);
            rb0 = *reinterpret_cast<const uint4*>(pB0 + k0 + 32);
            rb1 = *reinterpret_cast<const uint4*>(pB1 + k0 + 32);
        }

        bf16x8v af[4], bfr[4];
        #pragma unroll
        for (int m = 0; m < 4; ++m) {
            int ar = wr * 64 + m * 16 + l15;
            bf16x4v lo = *reinterpret_cast<const bf16x4v*>(&As[ar * LDT + kg]);
            bf16x4v hi = *reinterpret_cast<const bf16x4v*>(&As[ar * LDT + kg + 16]);
            af[m] = __builtin_shufflevector(lo, hi, 0, 1, 2, 3, 4, 5, 6, 7);
        }
        #pragma unroll
        for (int n = 0; n < 4; ++n) {
            int br = wc * 64 + n * 16 + l15;
            bf16x4v lo = *reinterpret_cast<const bf16x4v*>(&Bs[br * LDT + kg]);
            bf16x4v hi = *reinterpret_cast<const bf16x4v*>(&Bs[br * LDT + kg + 16]);
            bfr[n] = __builtin_shufflevector(lo, hi, 0, 1, 2, 3, 4, 5, 6, 7);
        }
        #pragma unroll
        for (int m = 0; m < 4; ++m)
            #pragma unroll
            for (int n = 0; n < 4; ++n)
                acc[m][n] = __builtin_amdgcn_mfma_f32_16x16x32_bf16(af[m], bfr[n], acc[m][n], 0, 0, 0);
        __syncthreads();
    }

    float* pslab = part + (size_t)blockIdx.z * M * Ntot;
    #pragma unroll
    for (int m = 0; m < 4; ++m) {
        int grow_base = row0 + wr * 64 + m * 16 + kg;
        #pragma unroll
        for (int j = 0; j < 4; ++j) {
            int grow = grow_base + j;
            if (grow >= M) continue;
            #pragma unroll
            for (int n = 0; n < 4; ++n) {
                int gcol = col0 + wc * 64 + n * 16 + l15;
                pslab[(size_t)grow * Ntot + gcol] = acc[m][n][j];
            }
        }
    }
}

// reduce partials; t = tanh(sum*rs). emb? out = (emb + prev + t)/3 : out = t
__global__ void reduce_tanh_kernel(const float* __restrict__ part, int S, int M, int N,
                                   const float* __restrict__ rs,
                                   const float* __restrict__ emb,
                                   const float* __restrict__ prev,
                                   float* __restrict__ out) {
    int i = blockIdx.x * blockDim.x + threadIdx.x;
    if (i >= M * N) return;
    int r = i / N, j = i - r * N;
    float s = 0.f;
    for (int z = 0; z < S; ++z) s += part[(size_t)z * M * N + i];
    if (rs) s *= rs[r];
    float t = tanhf(s);
    if (emb) out[i] = (emb[r * 64 + (j & 63)] + prev[i] + t) * (1.0f / 3.0f);
    else     out[i] = t;
}

// ---------------- conversion / fusion helpers -------------------------------
__global__ void make_cat_weights_kernel(
    const float* __restrict__ w_sh1, const float* __restrict__ w_sh1h,
    const float* __restrict__ b_sh1, const float* __restrict__ b_sh1h,
    const float* __restrict__ w_sh2, const float* __restrict__ w_sh2h,
    const float* __restrict__ b_sh2, const float* __restrict__ b_sh2h,
    const float* __restrict__ w_mlp1, const float* __restrict__ w_mlp1h,
    const float* __restrict__ b_mlp1, const float* __restrict__ b_mlp1h,
    const float* __restrict__ w_mlp,
    float* __restrict__ W1cat, float* __restrict__ b1cat,
    float* __restrict__ W2bd,  float* __restrict__ b2cat,
    float* __restrict__ WMbd,  float* __restrict__ bMcat,
    ushort* __restrict__ wmlp2)
{
    int i = blockIdx.x * blockDim.x + threadIdx.x;
    if (i < 64 * 128) {
        int k = i >> 7, j = i & 127;
        W1cat[i] = (j < 64) ? w_sh1[k * 64 + j] : w_sh1h[k * 64 + (j - 64)];
        return;
    }
    i -= 64 * 128;
    if (i < 128) { b1cat[i] = (i < 64) ? b_sh1[i] : b_sh1h[i - 64]; return; }
    i -= 128;
    if (i < 128 * 128) {
        int k = i >> 7, j = i & 127;
        float v = 0.f;
        if (k < 64 && j < 64) v = w_sh2[k * 64 + j];
        else if (k >= 64 && j >= 64) v = w_sh2h[(k - 64) * 64 + (j - 64)];
        W2bd[i] = v;
        return;
    }
    i -= 128 * 128;
    if (i < 128) { b2cat[i] = (i < 64) ? b_sh2[i] : b_sh2h[i - 64]; return; }
    i -= 128;
    if (i < 128 * 512) {
        int k = i >> 9, j = i & 511;
        float v = 0.f;
        if (j < 256) { if (k < 64) v = w_mlp1[k * 256 + j]; }
        else         { if (k >= 64) v = w_mlp1h[(k - 64) * 256 + (j - 256)]; }
        WMbd[i] = v;
        return;
    }
    i -= 128 * 512;
    if (i < 512) { bMcat[i] = (i < 256) ? b_mlp1[i] : b_mlp1h[i - 256]; return; }
    i -= 512;
    if (i < 256 * 512) {
        int n = i >> 9, k = i & 511;
        wmlp2[i] = f2bf(w_mlp[(size_t)(k & 255) * 256 + n]);
    }
}

__global__ void concat_hh_kernel(const float* __restrict__ emb, const float* __restrict__ kg,
                                 float* __restrict__ out) {
    int i = blockIdx.x * blockDim.x + threadIdx.x;
    const int n = N_HH * 91;
    if (i >= n) return;
    int r = i / 91, c = i % 91;
    out[i] = (c < DIM) ? emb[r * DIM + c] : kg[r * 27 + (c - DIM)];
}

__global__ void make_esbt_kernel(const float* __restrict__ x9cat, const float* __restrict__ ss1,
                                 ushort* __restrict__ out, int Kp) {
    int i = blockIdx.x * blockDim.x + threadIdx.x;
    if (i >= 256 * Kp) return;
    int n = i / Kp, k = i % Kp;
    float v = (k < N_SS) ? (x9cat[(size_t)k * 512 + n] + ss1[(size_t)k * 256 + n]) : 0.f;
    out[i] = f2bf(v);
}

__global__ void make_ehb_kernel(const float* __restrict__ x9cat, const float* __restrict__ hh1,
                                ushort* __restrict__ out, int Rp) {
    int i = blockIdx.x * blockDim.x + threadIdx.x;
    if (i >= Rp * 256) return;
    int r = i >> 8, c = i & 255;
    float v = (r < N_HH) ? (x9cat[(size_t)(N_SS + r) * 512 + 256 + c] + hh1[(size_t)r * 256 + c]) : 0.f;
    out[i] = f2bf(v);
}

// ---------------- BatchNorm -------------------------------------------------
__global__ void bn_apply_cat_kernel(const float* __restrict__ X, const float* __restrict__ stats,
                                    const float* __restrict__ g1, const float* __restrict__ be1,
                                    const float* __restrict__ g2, const float* __restrict__ be2,
                                    int M, float* __restrict__ out) {
    int i = blockIdx.x * blockDim.x + threadIdx.x;
    if (i >= M * 512) return;
    int j = i & 511;
    float invM = 1.0f / (float)M;
    float mean = stats[j] * invM;
    float var  = fmaxf(stats[512 + j] * invM - mean * mean, 0.f);
    float ga = (j < 256) ? g1[j]  : g2[j - 256];
    float bb = (j < 256) ? be1[j] : be2[j - 256];
    float y = (X[i] - mean) * rsqrtf(var + 1e-5f) * ga + bb;
    out[i] = tanhf(y);
}

__global__ void bn_finalize_kernel(const float* __restrict__ stats,
                                   const float* __restrict__ g, const float* __restrict__ be,
                                   int M, float* __restrict__ scale, float* __restrict__ shift) {
    int j = threadIdx.x;  // 256
    float invM = 1.0f / (float)M;
    float mean = stats[j] * invM;
    float var  = fmaxf(stats[256 + j] * invM - mean * mean, 0.f);
    float sc = g[j] * rsqrtf(var + 1e-5f);
    scale[j] = sc;
    shift[j] = be[j] - mean * sc;
}

// ---------------- driver -----------------------------------------------------
extern "C" void kernel_launch(void* const* d_in, const int* in_sizes, int n_in,
                              void* d_out, int out_size, void* d_ws, size_t ws_size,
                              hipStream_t stream) {
    const int*   eiSH = (const int*)d_in[1];
    const int*   eiSS = (const int*)d_in[3];
    const int*   eiHH = (const int*)d_in[5];
    const float* P    = (const float*)d_in[6];
    const float* kg   = (const float*)d_in[7];
    const float* emb  = (const float*)d_in[8];
    const float* w_sh1  = (const float*)d_in[9];   const float* b_sh1  = (const float*)d_in[10];
    const float* w_sh2  = (const float*)d_in[11];  const float* b_sh2  = (const float*)d_in[12];
    const float* w_mlp1 = (const float*)d_in[13];  const float* b_mlp1 = (const float*)d_in[14];
    const float* g_bn1  = (const float*)d_in[15];  const float* be_bn1 = (const float*)d_in[16];
    const float* w_sh1h = (const float*)d_in[17];  const float* b_sh1h = (const float*)d_in[18];
    const float* w_sh2h = (const float*)d_in[19];  const float* b_sh2h = (const float*)d_in[20];
    const float* w_mlp1h= (const float*)d_in[21];  const float* b_mlp1h= (const float*)d_in[22];
    const float* g_bn1h = (const float*)d_in[23];  const float* be_bn1h= (const float*)d_in[24];
    const float* w_ss   = (const float*)d_in[25];  const float* b_ss   = (const float*)d_in[26];
    const float* w_hh   = (const float*)d_in[27];  const float* b_hh   = (const float*)d_in[28];
    const float* w_mlp  = (const float*)d_in[29];  const float* b_mlp  = (const float*)d_in[30];
    const float* g_si   = (const float*)d_in[31];  const float* be_si  = (const float*)d_in[32];
    float* out = (float*)d_out;

    const int E_SH = in_sizes[1] / 2;
    const int E_SS = in_sizes[3] / 2;
    const int E_HH = in_sizes[5] / 2;
    const int B    = in_sizes[6] / N_SS;      // 20000
    const int Mp   = ((B + 127) / 128) * 128; // 20096
    const int KP1  = 416;
    const int NP3  = 896;
    const int KSH  = 1216;
    const int KHH  = 832;
    const int HS_SH = (N_SH + 1) / 2;   // 598
    const int HS_SS = (N_SS + 1) / 2;   // 195
    const int HS_HH = (N_HH + 1) / 2;   // 403

    float* w = (float*)d_ws;
    size_t off = 0;
    auto alloc = [&](size_t n) { float* p = w + off; off += (n + 3) & ~(size_t)3; return p; };

    float* cntInv   = alloc(N_SH);
    // zero-block: statsCat + statsC2 + HT + HSST + HHHT (contiguous)
    float* statsCat = alloc(1024);
    float* statsC2  = alloc(512);
    ushort* HT      = (ushort*)alloc((size_t)128 * KSH / 2);
    ushort* HSST    = (ushort*)alloc((size_t)256 * KP1 / 2);
    ushort* HHHT    = (ushort*)alloc((size_t)256 * KHH / 2);
    float* zeroEnd  = w + off;
    float* bnScale = alloc(256);
    float* bnShift = alloc(256);
    float* W1cat   = alloc(64 * 128);
    float* b1cat   = alloc(128);
    float* W2bd    = alloc(128 * 128);
    float* b2cat   = alloc(128);
    float* WMbd    = alloc(128 * 512);
    float* bMcat   = alloc(512);
    ushort* wmlp2  = (ushort*)alloc((size_t)256 * 512 / 2);
    ushort* adjb   = (ushort*)alloc((size_t)1280 * KSH / 2);
    ushort* adjSSb = (ushort*)alloc((size_t)512 * KP1 / 2);
    ushort* adjHHb = (ushort*)alloc((size_t)896 * KHH / 2);
    float* x2cat   = alloc((size_t)N_SH * 128);
    float* x9a2    = alloc((size_t)N_SH * 128);
    float* tmpBN   = alloc((size_t)N_SH * 512);
    float* x9cat   = alloc((size_t)N_SH * 512);
    float* ss1     = alloc((size_t)N_SS * 256);
    float* hh1     = alloc((size_t)N_HH * 256);
    float* xhh0    = alloc((size_t)N_HH * 91);
    ushort* es_bT  = (ushort*)alloc((size_t)256 * KP1 / 2);
    ushort* eh_b   = (ushort*)alloc((size_t)NP3 * 256 / 2);
    // region A: packed adjacency tables (early) -> bufM f32 [Mp][256]
    float* regionA = alloc((size_t)Mp * 256);
    uint32_t* uSH  = (uint32_t*)regionA;
    uint32_t* uSS  = uSH + (size_t)N_SH * HS_SH;
    uint32_t* uHH  = uSS + (size_t)N_SS * HS_SS;
    size_t packed_words = (size_t)N_SH * HS_SH + (size_t)N_SS * HS_SS + (size_t)N_HH * HS_HH;
    float*  bufM   = regionA;
    // region B: split-K partials (early) -> e_hilo bf16 [Mp][512]
    float* regionB = alloc((size_t)Mp * 256);
    float*  partials = regionB;
    ushort* e_hilo = (ushort*)regionB;
    (void)ws_size; (void)n_in; (void)out_size;

    auto gemmT = [&](const float* Am, const float* Bm, const float* bias,
                     ushort* oT, int ldt, int M, int N, int K) {
        dim3 g((N + BN - 1) / BN, (M + BM - 1) / BM);
        gemm_kernel<<<g, 256, 0, stream>>>(Am, Bm, bias, nullptr, oT, ldt, M, N, K, nullptr, 0);
    };
    auto gemmF = [&](const float* Am, const float* Bm, const float* bias,
                     float* C, int M, int N, int K, float* st, int sstride) {
        dim3 g((N + BN - 1) / BN, (M + BM - 1) / BM);
        gemm_kernel<<<g, 256, 0, stream>>>(Am, Bm, bias, C, nullptr, 0, M, N, K, st, sstride);
    };
    auto splitk = [&](const ushort* Am, const ushort* Bm, int M, int Mtiles, int K, int lda,
                      int Ntot, int S, const float* rs, const float* embA, const float* prev,
                      float* outp) {
        dim3 g(Ntot / 128, Mtiles, S);
        mfma_splitk_kernel<<<g, 256, 0, stream>>>(Am, Bm, M, K, lda, 128, Ntot, partials);
        reduce_tanh_kernel<<<(M * Ntot + 255) / 256, 256, 0, stream>>>(
            partials, S, M, Ntot, rs, embA, prev, outp);
    };

    // ---- memsets: packed tables + {stats, HT block} ----
    hipMemsetAsync(uSH, 0, packed_words * sizeof(uint32_t), stream);
    hipMemsetAsync(statsCat, 0, (size_t)((char*)zeroEnd - (char*)statsCat), stream);

    // ---- adjacency: fused packed build, all three graphs ----
    {
        int Etot = E_SH + E_SS + E_HH;
        build_adj3_kernel<<<(Etot + 255) / 256, 256, 0, stream>>>(
            eiSH, E_SH, HS_SH, uSH, eiSS, E_SS, HS_SS, uSS, eiHH, E_HH, HS_HH, uHH);
    }
    rowsum_inv_packed_kernel<<<(N_SH + 3) / 4, 256, 0, stream>>>(uSH, N_SH, HS_SH, cntInv);
    {
        int n1 = 1280 * KSH, n2 = 512 * KP1, n3 = 896 * KHH;
        cvt_unpack3_kernel<<<(n1 + n2 + n3 + 255) / 256, 256, 0, stream>>>(
            uSH, HS_SH, adjb, n1, KSH, uSS, HS_SS, adjSSb, n2, KP1, uHH, HS_HH, adjHHb, n3, KHH);
    }

    make_cat_weights_kernel<<<(90880 + 131072 + 255) / 256, 256, 0, stream>>>(
        w_sh1, w_sh1h, b_sh1, b_sh1h, w_sh2, w_sh2h, b_sh2, b_sh2h,
        w_mlp1, w_mlp1h, b_mlp1, b_mlp1h, w_mlp,
        W1cat, b1cat, W2bd, b2cat, WMbd, bMcat, wmlp2);

    // ---- SH layers (fused branches; gemm writes transposed bf16 directly) ----
    gemmT(emb, W1cat, b1cat, HT, KSH, N_SH, 128, 64);
    splitk(adjb, HT, N_SH, 10, KSH, KSH, 128, 10, cntInv, nullptr, nullptr, x2cat);
    gemmT(x2cat, W2bd, b2cat, HT, KSH, N_SH, 128, 128);
    splitk(adjb, HT, N_SH, 10, KSH, KSH, 128, 10, cntInv, emb, x2cat, x9a2);  // fused avg3
    gemmF(x9a2, WMbd, bMcat, tmpBN, N_SH, 512, 128, statsCat, 512);           // fused BN stats
    bn_apply_cat_kernel<<<(N_SH * 512 + 255) / 256, 256, 0, stream>>>(
        tmpBN, statsCat, g_bn1, be_bn1, g_bn1h, be_bn1h, N_SH, x9cat);

    // ---- SS graph ----
    gemmT(emb, w_ss, b_ss, HSST, KP1, N_SS, 256, 64);
    splitk(adjSSb, HSST, N_SS, 4, KP1, KP1, 256, 4, nullptr, nullptr, nullptr, ss1);

    // ---- HH graph ----
    concat_hh_kernel<<<(N_HH * 91 + 255) / 256, 256, 0, stream>>>(emb, kg, xhh0);
    gemmT(xhh0, w_hh, b_hh, HHHT, KHH, N_HH, 256, 91);
    splitk(adjHHb, HHHT, N_HH, 7, KHH, KHH, 256, 7, nullptr, nullptr, nullptr, hh1);

    // ---- prepare bf16 operands for prescription path ----
    make_esbt_kernel<<<(256 * KP1 + 255) / 256, 256, 0, stream>>>(x9cat, ss1, es_bT, KP1);
    make_ehb_kernel<<<(NP3 * 256 + 255) / 256, 256, 0, stream>>>(x9cat, hh1, eh_b, NP3);

    // ---- prescription path (bf16 MFMA, prefetched) ----
    {
        dim3 g(2, (B + 127) / 128);
        mfma_c1_kernel<<<g, 256, 0, stream>>>(P, es_bT, B, e_hilo, e_hilo + 256, 512);
    }
    {
        dim3 g(2, (B + 127) / 128);
        mfma_gemm_kernel<<<g, 256, 0, stream>>>(e_hilo, wmlp2, B, 256, 512, 512,
                                                b_mlp, nullptr, bufM, nullptr, nullptr, 256,
                                                statsC2);
    }
    bn_finalize_kernel<<<1, 256, 0, stream>>>(statsC2, g_si, be_si, B, bnScale, bnShift);
    {
        dim3 g(NP3 / 128, (B + 127) / 128);
        mfma_c3_kernel<<<g, 256, 0, stream>>>(bufM, eh_b, B, N_HH, bnScale, bnShift, out, N_HH);
    }
}

// Round 10
// 315.337 us; speedup vs baseline: 1.4221x; 1.0083x over previous
//
#include <hip/hip_runtime.h>
#include <cstddef>
#include <cstdint>

#define N_SH 1195
#define N_SS 390
#define N_HH 805
#define DIM  64

typedef __bf16 bf16_t;
typedef bf16_t bf16x4v __attribute__((ext_vector_type(4)));
typedef bf16_t bf16x8v __attribute__((ext_vector_type(8)));
typedef float f32x4 __attribute__((ext_vector_type(4)));

__device__ inline ushort f2bf(float f) {
    union { float f; uint32_t u; } c; c.f = f;
    uint32_t u = c.u;
    u += 0x7FFFu + ((u >> 16) & 1u);
    return (ushort)(u >> 16);
}

// bijective XCD swizzle (m204)
__device__ inline void xcd_swizzle(int gx, int gy, int& bx, int& by) {
    int nwg = gx * gy;
    int lin = by * gx + bx;
    int q = nwg >> 3, r = nwg & 7;
    int xcd = lin & 7, idx = lin >> 3;
    int nt = (xcd < r ? xcd * (q + 1) : r * (q + 1) + (xcd - r) * q) + idx;
    by = nt / gx; bx = nt % gx;
}

// ---------------- adjacency build: packed 4x8-bit counters, all 3 graphs ----
// counts are small (<=~15) so no carry across the 8-bit lanes.
__global__ void build_adj3_kernel(
    const int* __restrict__ e1, int E1, int hs1, uint32_t* __restrict__ T1,
    const int* __restrict__ e2, int E2, int hs2, uint32_t* __restrict__ T2,
    const int* __restrict__ e3, int E3, int hs3, uint32_t* __restrict__ T3)
{
    int i = blockIdx.x * blockDim.x + threadIdx.x;
    if (i < E1) {
        int src = e1[i], dst = e1[E1 + i];
        atomicAdd(&T1[(size_t)dst * hs1 + (src >> 2)], 1u << ((src & 3) * 8));
    } else if (i < E1 + E2) {
        int j = i - E1;
        int src = e2[j], dst = e2[E2 + j];
        atomicAdd(&T2[(size_t)dst * hs2 + (src >> 2)], 1u << ((src & 3) * 8));
    } else if (i < E1 + E2 + E3) {
        int j = i - E1 - E2;
        int src = e3[j], dst = e3[E3 + j];
        atomicAdd(&T3[(size_t)dst * hs3 + (src >> 2)], 1u << ((src & 3) * 8));
    }
}

__global__ void rowsum_inv_packed_kernel(const uint32_t* __restrict__ T, int R,
                                         int halfStride, float* __restrict__ inv) {
    int row  = blockIdx.x * (blockDim.x / 64) + (threadIdx.x / 64);
    int lane = threadIdx.x & 63;
    if (row >= R) return;
    const uint32_t* p = T + (size_t)row * halfStride;
    uint32_t s = 0;
    for (int c = lane; c < halfStride; c += 64) {
        uint32_t w = p[c];
        s += (w & 0xFFu) + ((w >> 8) & 0xFFu) + ((w >> 16) & 0xFFu) + (w >> 24);
    }
    for (int off = 32; off > 0; off >>= 1) s += __shfl_down(s, off);
    if (lane == 0) inv[row] = 1.0f / fmaxf((float)s, 1.0f);
}

__device__ inline void unpack_one(const uint32_t* __restrict__ T, int R, int C,
                                  int hs, ushort* __restrict__ out, int Cp, int i) {
    int r = i / Cp, c = i % Cp;
    float v = 0.f;
    if (r < R && c < C) {
        uint32_t w = T[(size_t)r * hs + (c >> 2)];
        v = (float)((w >> ((c & 3) * 8)) & 0xFFu);
    }
    out[i] = f2bf(v);
}

__global__ void cvt_unpack3_kernel(
    const uint32_t* __restrict__ T1, int hs1, ushort* __restrict__ o1, int n1, int Cp1,
    const uint32_t* __restrict__ T2, int hs2, ushort* __restrict__ o2, int n2, int Cp2,
    const uint32_t* __restrict__ T3, int hs3, ushort* __restrict__ o3, int n3, int Cp3)
{
    int i = blockIdx.x * blockDim.x + threadIdx.x;
    if (i < n1) { unpack_one(T1, N_SH, N_SH, hs1, o1, Cp1, i); return; }
    i -= n1;
    if (i < n2) { unpack_one(T2, N_SS, N_SS, hs2, o2, Cp2, i); return; }
    i -= n2;
    if (i < n3) { unpack_one(T3, N_HH, N_HH, hs3, o3, Cp3, i); }
}

// -------- fp32 GEMM: optional A2 add-stream, transposed-bf16 out, BN stats --
#define BM 64
#define BN 64
#define BK 16

__global__ __launch_bounds__(256) void gemm_kernel(
    const float* __restrict__ A, const float* __restrict__ A2, int ldaA, int ldaA2,
    const float* __restrict__ B,
    const float* __restrict__ bias,
    float* __restrict__ C, ushort* __restrict__ outT, int ldt,
    int M, int N, int K, float* __restrict__ statsOut, int statsStride)
{
    __shared__ float As[BK][BM + 4];
    __shared__ float Bs[BK][BN];
    __shared__ float cs[128];
    const int tid  = threadIdx.x;
    const int row0 = blockIdx.y * BM;
    const int col0 = blockIdx.x * BN;
    const int tr  = (tid >> 4) << 2;
    const int tc  = (tid & 15) << 2;
    const int lar = tid >> 2;
    const int lac = (tid & 3) << 2;
    const int lbr = tid >> 4;
    const int lbc = (tid & 15) << 2;

    float acc[4][4] = {{0.f}};

    for (int k0 = 0; k0 < K; k0 += BK) {
        const int gr = row0 + lar;
        #pragma unroll
        for (int i = 0; i < 4; ++i) {
            int gk = k0 + lac + i;
            float v = 0.f;
            if (gr < M && gk < K) {
                v = A[(size_t)gr * ldaA + gk];
                if (A2) v += A2[(size_t)gr * ldaA2 + gk];
            }
            As[lac + i][lar] = v;
        }
        const int gk = k0 + lbr;
        const float* Bp = B + (size_t)gk * N + col0 + lbc;
        #pragma unroll
        for (int i = 0; i < 4; ++i) {
            int gc = col0 + lbc + i;
            Bs[lbr][lbc + i] = (gk < K && gc < N) ? Bp[i] : 0.f;
        }
        __syncthreads();
        #pragma unroll
        for (int kk = 0; kk < BK; ++kk) {
            float4 a = *reinterpret_cast<const float4*>(&As[kk][tr]);
            float4 b = *reinterpret_cast<const float4*>(&Bs[kk][tc]);
            acc[0][0] += a.x * b.x; acc[0][1] += a.x * b.y; acc[0][2] += a.x * b.z; acc[0][3] += a.x * b.w;
            acc[1][0] += a.y * b.x; acc[1][1] += a.y * b.y; acc[1][2] += a.y * b.z; acc[1][3] += a.y * b.w;
            acc[2][0] += a.z * b.x; acc[2][1] += a.z * b.y; acc[2][2] += a.z * b.z; acc[2][3] += a.z * b.w;
            acc[3][0] += a.w * b.x; acc[3][1] += a.w * b.y; acc[3][2] += a.w * b.z; acc[3][3] += a.w * b.w;
        }
        __syncthreads();
    }

    float ls[4] = {0.f, 0.f, 0.f, 0.f}, lq[4] = {0.f, 0.f, 0.f, 0.f};
    #pragma unroll
    for (int i = 0; i < 4; ++i) {
        int gr = row0 + tr + i;
        if (gr >= M) continue;
        #pragma unroll
        for (int j = 0; j < 4; ++j) {
            int gc = col0 + tc + j;
            if (gc >= N) continue;
            float v = acc[i][j];
            if (bias) v += bias[gc];
            if (outT) outT[(size_t)gc * ldt + gr] = f2bf(v);
            else      C[(size_t)gr * N + gc] = v;
            ls[j] += v; lq[j] += v * v;
        }
    }

    if (statsOut) {
        if (tid < 128) cs[tid] = 0.f;
        __syncthreads();
        #pragma unroll
        for (int j = 0; j < 4; ++j) {
            atomicAdd(&cs[tc + j], ls[j]);
            atomicAdd(&cs[64 + tc + j], lq[j]);
        }
        __syncthreads();
        if (tid < 64) {
            atomicAdd(&statsOut[col0 + tid], cs[tid]);
            atomicAdd(&statsOut[statsStride + col0 + tid], cs[64 + tid]);
        }
    }
}

// ---------------- C1': bufM = (P @ D^T)·(1/rowsum(P)) + b_mlp, BN stats -----
#define LDT 40

__device__ inline void loadP8(const float* __restrict__ rowp, int c0, bool rv,
                              float* a, float& s) {
    if (rv && c0 + 8 <= N_SS) {
        float2 x0 = *reinterpret_cast<const float2*>(rowp + c0);
        float2 x1 = *reinterpret_cast<const float2*>(rowp + c0 + 2);
        float2 x2 = *reinterpret_cast<const float2*>(rowp + c0 + 4);
        float2 x3 = *reinterpret_cast<const float2*>(rowp + c0 + 6);
        a[0] = x0.x; a[1] = x0.y; a[2] = x1.x; a[3] = x1.y;
        a[4] = x2.x; a[5] = x2.y; a[6] = x3.x; a[7] = x3.y;
    } else {
        #pragma unroll
        for (int i = 0; i < 8; ++i) a[i] = (rv && (c0 + i) < N_SS) ? rowp[c0 + i] : 0.f;
    }
    #pragma unroll
    for (int i = 0; i < 8; ++i) s += a[i];
}

__global__ __launch_bounds__(256) void mfma_c1_kernel(
    const float* __restrict__ Pm, const ushort* __restrict__ Dt,
    int M, const float* __restrict__ bias,
    float* __restrict__ outF, float* __restrict__ statsOut)
{
    __shared__ __align__(16) ushort As[128 * LDT];
    __shared__ __align__(16) ushort Bs[128 * LDT];
    __shared__ float sums[128];
    __shared__ float cs[256];
    const int tid  = threadIdx.x;
    int bx = blockIdx.x, by = blockIdx.y;
    xcd_swizzle(gridDim.x, gridDim.y, bx, by);
    const int row0 = by * 128;
    const int col0 = bx * 128;
    const int wid  = tid >> 6, lane = tid & 63;
    const int wr = wid >> 1, wc = wid & 1;
    const int l15 = lane & 15, lg = lane >> 4;
    const int kg = lg * 4;
    const int sr = tid >> 2;
    const int sc = (tid & 3) * 8;

    const float* pA0 = Pm + (size_t)(row0 + sr)      * N_SS;
    const float* pA1 = Pm + (size_t)(row0 + sr + 64) * N_SS;
    const bool rv0 = (row0 + sr)      < M;
    const bool rv1 = (row0 + sr + 64) < M;
    const ushort* pB0 = Dt + (size_t)(col0 + sr)      * 416 + sc;
    const ushort* pB1 = Dt + (size_t)(col0 + sr + 64) * 416 + sc;

    float a0[8], a1[8];
    float s0 = 0.f, s1 = 0.f;
    loadP8(pA0, sc, rv0, a0, s0);
    loadP8(pA1, sc, rv1, a1, s1);
    uint4 b0 = *reinterpret_cast<const uint4*>(pB0);
    uint4 b1 = *reinterpret_cast<const uint4*>(pB1);

    f32x4 acc[4][4];
    #pragma unroll
    for (int m = 0; m < 4; ++m)
        #pragma unroll
        for (int n = 0; n < 4; ++n) acc[m][n] = (f32x4)0.f;

    for (int k0 = 0; k0 < 416; k0 += 32) {
        {
            bf16_t h[8];
            #pragma unroll
            for (int i = 0; i < 8; ++i) h[i] = (bf16_t)a0[i];
            *reinterpret_cast<uint4*>(&As[sr * LDT + sc]) = *reinterpret_cast<const uint4*>(h);
            #pragma unroll
            for (int i = 0; i < 8; ++i) h[i] = (bf16_t)a1[i];
            *reinterpret_cast<uint4*>(&As[(sr + 64) * LDT + sc]) = *reinterpret_cast<const uint4*>(h);
        }
        *reinterpret_cast<uint4*>(&Bs[sr * LDT + sc])        = b0;
        *reinterpret_cast<uint4*>(&Bs[(sr + 64) * LDT + sc]) = b1;
        __syncthreads();
        if (k0 + 32 < 416) {
            loadP8(pA0, k0 + 32 + sc, rv0, a0, s0);
            loadP8(pA1, k0 + 32 + sc, rv1, a1, s1);
            b0 = *reinterpret_cast<const uint4*>(pB0 + k0 + 32);
            b1 = *reinterpret_cast<const uint4*>(pB1 + k0 + 32);
        }

        bf16x8v af[4], bfr[4];
        #pragma unroll
        for (int m = 0; m < 4; ++m) {
            int ar = wr * 64 + m * 16 + l15;
            bf16x4v lo = *reinterpret_cast<const bf16x4v*>(&As[ar * LDT + kg]);
            bf16x4v hi = *reinterpret_cast<const bf16x4v*>(&As[ar * LDT + kg + 16]);
            af[m] = __builtin_shufflevector(lo, hi, 0, 1, 2, 3, 4, 5, 6, 7);
        }
        #pragma unroll
        for (int n = 0; n < 4; ++n) {
            int br = wc * 64 + n * 16 + l15;
            bf16x4v lo = *reinterpret_cast<const bf16x4v*>(&Bs[br * LDT + kg]);
            bf16x4v hi = *reinterpret_cast<const bf16x4v*>(&Bs[br * LDT + kg + 16]);
            bfr[n] = __builtin_shufflevector(lo, hi, 0, 1, 2, 3, 4, 5, 6, 7);
        }
        #pragma unroll
        for (int m = 0; m < 4; ++m)
            #pragma unroll
            for (int n = 0; n < 4; ++n)
                acc[m][n] = __builtin_amdgcn_mfma_f32_16x16x32_bf16(af[m], bfr[n], acc[m][n], 0, 0, 0);
        __syncthreads();
    }

    if (tid < 128) sums[tid] = 0.f;
    if (tid < 256) cs[tid] = 0.f;
    __syncthreads();
    atomicAdd(&sums[sr], s0);
    atomicAdd(&sums[sr + 64], s1);
    __syncthreads();

    float ls[4] = {0.f, 0.f, 0.f, 0.f}, lq[4] = {0.f, 0.f, 0.f, 0.f};
    #pragma unroll
    for (int m = 0; m < 4; ++m) {
        int lr_base = wr * 64 + m * 16 + kg;
        #pragma unroll
        for (int j = 0; j < 4; ++j) {
            int lr = lr_base + j;
            int grow = row0 + lr;
            if (grow >= M) continue;
            float t = sums[lr];
            float inv = (t != 0.f) ? 1.0f / t : 0.f;
            #pragma unroll
            for (int n = 0; n < 4; ++n) {
                int gcol = col0 + wc * 64 + n * 16 + l15;
                float v = acc[m][n][j] * inv + bias[gcol];
                outF[(size_t)grow * 256 + gcol] = v;
                ls[n] += v; lq[n] += v * v;
            }
        }
    }

    __syncthreads();
    #pragma unroll
    for (int n = 0; n < 4; ++n) {
        int lc = wc * 64 + n * 16 + l15;
        atomicAdd(&cs[lc], ls[n]);
        atomicAdd(&cs[128 + lc], lq[n]);
    }
    __syncthreads();
    if (tid < 128) {
        atomicAdd(&statsOut[col0 + tid], cs[tid]);
        atomicAdd(&statsOut[256 + col0 + tid], cs[128 + tid]);
    }
}

// ------ C3: A = relu(BN(bufM)) (scale/shift computed from stats in LDS) -----
__global__ __launch_bounds__(256) void mfma_c3_kernel(
    const float* __restrict__ Abuf, const ushort* __restrict__ Bt,
    int M, int Nw,
    const float* __restrict__ stats, const float* __restrict__ g,
    const float* __restrict__ be,
    float* __restrict__ outF, int ldo)
{
    __shared__ __align__(16) ushort As[128 * LDT];
    __shared__ __align__(16) ushort Bs[128 * LDT];
    __shared__ float sscale[256], sshift[256];
    const int tid  = threadIdx.x;
    int bx = blockIdx.x, by = blockIdx.y;
    xcd_swizzle(gridDim.x, gridDim.y, bx, by);
    const int row0 = by * 128;
    const int col0 = bx * 128;
    const int wid  = tid >> 6, lane = tid & 63;
    const int wr = wid >> 1, wc = wid & 1;
    const int l15 = lane & 15, lg = lane >> 4;
    const int kg = lg * 4;
    const int sr = tid >> 2;
    const int sc = (tid & 3) * 8;

    if (tid < 256) {
        float invM = 1.0f / (float)M;
        float mean = stats[tid] * invM;
        float var  = fmaxf(stats[256 + tid] * invM - mean * mean, 0.f);
        float scv  = g[tid] * rsqrtf(var + 1e-5f);
        sscale[tid] = scv;
        sshift[tid] = be[tid] - mean * scv;
    }
    __syncthreads();

    const float*  pA0 = Abuf + (size_t)(row0 + sr)      * 256 + sc;
    const float*  pA1 = Abuf + (size_t)(row0 + sr + 64) * 256 + sc;
    const ushort* pB0 = Bt + (size_t)(col0 + sr)        * 256 + sc;
    const ushort* pB1 = Bt + (size_t)(col0 + sr + 64)   * 256 + sc;

    float4 a00 = *reinterpret_cast<const float4*>(pA0);
    float4 a01 = *reinterpret_cast<const float4*>(pA0 + 4);
    float4 a10 = *reinterpret_cast<const float4*>(pA1);
    float4 a11 = *reinterpret_cast<const float4*>(pA1 + 4);
    uint4  b0  = *reinterpret_cast<const uint4*>(pB0);
    uint4  b1  = *reinterpret_cast<const uint4*>(pB1);

    f32x4 acc[4][4];
    #pragma unroll
    for (int m = 0; m < 4; ++m)
        #pragma unroll
        for (int n = 0; n < 4; ++n) acc[m][n] = (f32x4)0.f;

    for (int k0 = 0; k0 < 256; k0 += 32) {
        float s8[8], t8[8];
        #pragma unroll
        for (int i = 0; i < 8; ++i) { s8[i] = sscale[k0 + sc + i]; t8[i] = sshift[k0 + sc + i]; }
        {
            bf16_t h[8];
            h[0] = (bf16_t)fmaxf(a00.x * s8[0] + t8[0], 0.f);
            h[1] = (bf16_t)fmaxf(a00.y * s8[1] + t8[1], 0.f);
            h[2] = (bf16_t)fmaxf(a00.z * s8[2] + t8[2], 0.f);
            h[3] = (bf16_t)fmaxf(a00.w * s8[3] + t8[3], 0.f);
            h[4] = (bf16_t)fmaxf(a01.x * s8[4] + t8[4], 0.f);
            h[5] = (bf16_t)fmaxf(a01.y * s8[5] + t8[5], 0.f);
            h[6] = (bf16_t)fmaxf(a01.z * s8[6] + t8[6], 0.f);
            h[7] = (bf16_t)fmaxf(a01.w * s8[7] + t8[7], 0.f);
            *reinterpret_cast<uint4*>(&As[sr * LDT + sc]) = *reinterpret_cast<const uint4*>(h);
            h[0] = (bf16_t)fmaxf(a10.x * s8[0] + t8[0], 0.f);
            h[1] = (bf16_t)fmaxf(a10.y * s8[1] + t8[1], 0.f);
            h[2] = (bf16_t)fmaxf(a10.z * s8[2] + t8[2], 0.f);
            h[3] = (bf16_t)fmaxf(a10.w * s8[3] + t8[3], 0.f);
            h[4] = (bf16_t)fmaxf(a11.x * s8[4] + t8[4], 0.f);
            h[5] = (bf16_t)fmaxf(a11.y * s8[5] + t8[5], 0.f);
            h[6] = (bf16_t)fmaxf(a11.z * s8[6] + t8[6], 0.f);
            h[7] = (bf16_t)fmaxf(a11.w * s8[7] + t8[7], 0.f);
            *reinterpret_cast<uint4*>(&As[(sr + 64) * LDT + sc]) = *reinterpret_cast<const uint4*>(h);
        }
        *reinterpret_cast<uint4*>(&Bs[sr * LDT + sc])        = b0;
        *reinterpret_cast<uint4*>(&Bs[(sr + 64) * LDT + sc]) = b1;
        __syncthreads();
        if (k0 + 32 < 256) {
            a00 = *reinterpret_cast<const float4*>(pA0 + k0 + 32);
            a01 = *reinterpret_cast<const float4*>(pA0 + k0 + 36);
            a10 = *reinterpret_cast<const float4*>(pA1 + k0 + 32);
            a11 = *reinterpret_cast<const float4*>(pA1 + k0 + 36);
            b0  = *reinterpret_cast<const uint4*>(pB0 + k0 + 32);
            b1  = *reinterpret_cast<const uint4*>(pB1 + k0 + 32);
        }

        bf16x8v af[4], bfr[4];
        #pragma unroll
        for (int m = 0; m < 4; ++m) {
            int ar = wr * 64 + m * 16 + l15;
            bf16x4v lo = *reinterpret_cast<const bf16x4v*>(&As[ar * LDT + kg]);
            bf16x4v hi = *reinterpret_cast<const bf16x4v*>(&As[ar * LDT + kg + 16]);
            af[m] = __builtin_shufflevector(lo, hi, 0, 1, 2, 3, 4, 5, 6, 7);
        }
        #pragma unroll
        for (int n = 0; n < 4; ++n) {
            int br = wc * 64 + n * 16 + l15;
            bf16x4v lo = *reinterpret_cast<const bf16x4v*>(&Bs[br * LDT + kg]);
            bf16x4v hi = *reinterpret_cast<const bf16x4v*>(&Bs[br * LDT + kg + 16]);
            bfr[n] = __builtin_shufflevector(lo, hi, 0, 1, 2, 3, 4, 5, 6, 7);
        }
        #pragma unroll
        for (int m = 0; m < 4; ++m)
            #pragma unroll
            for (int n = 0; n < 4; ++n)
                acc[m][n] = __builtin_amdgcn_mfma_f32_16x16x32_bf16(af[m], bfr[n], acc[m][n], 0, 0, 0);
        __syncthreads();
    }

    #pragma unroll
    for (int m = 0; m < 4; ++m) {
        int grow_base = row0 + wr * 64 + m * 16 + kg;
        #pragma unroll
        for (int j = 0; j < 4; ++j) {
            int grow = grow_base + j;
            if (grow >= M) continue;
            #pragma unroll
            for (int n = 0; n < 4; ++n) {
                int gcol = col0 + wc * 64 + n * 16 + l15;
                if (gcol >= Nw) continue;
                outF[(size_t)grow * ldo + gcol] = acc[m][n][j];
            }
        }
    }
}

// ---------------- split-K MFMA: partials (f32), grid.z = K-chunk ------------
__global__ __launch_bounds__(256) void mfma_splitk_kernel(
    const ushort* __restrict__ A, const ushort* __restrict__ Bt,
    int M, int K, int lda, int kChunk, int Ntot,
    float* __restrict__ part)
{
    __shared__ __align__(16) ushort As[128 * LDT];
    __shared__ __align__(16) ushort Bs[128 * LDT];
    const int tid  = threadIdx.x;
    const int row0 = blockIdx.y * 128;
    const int col0 = blockIdx.x * 128;
    const int wid  = tid >> 6, lane = tid & 63;
    const int wr = wid >> 1, wc = wid & 1;
    const int l15 = lane & 15, lg = lane >> 4;
    const int kg = lg * 4;
    const int sr = tid >> 2;
    const int sc = (tid & 3) * 8;

    const int k0s = blockIdx.z * kChunk;
    const int k0e = (k0s + kChunk < K) ? k0s + kChunk : K;

    const ushort* pA0 = A  + (size_t)(row0 + sr)      * lda + sc;
    const ushort* pA1 = A  + (size_t)(row0 + sr + 64) * lda + sc;
    const ushort* pB0 = Bt + (size_t)(col0 + sr)      * lda + sc;
    const ushort* pB1 = Bt + (size_t)(col0 + sr + 64) * lda + sc;

    uint4 ra0 = *reinterpret_cast<const uint4*>(pA0 + k0s);
    uint4 ra1 = *reinterpret_cast<const uint4*>(pA1 + k0s);
    uint4 rb0 = *reinterpret_cast<const uint4*>(pB0 + k0s);
    uint4 rb1 = *reinterpret_cast<const uint4*>(pB1 + k0s);

    f32x4 acc[4][4];
    #pragma unroll
    for (int m = 0; m < 4; ++m)
        #pragma unroll
        for (int n = 0; n < 4; ++n) acc[m][n] = (f32x4)0.f;

    for (int k0 = k0s; k0 < k0e; k0 += 32) {
        *reinterpret_cast<uint4*>(&As[sr * LDT + sc])        = ra0;
        *reinterpret_cast<uint4*>(&As[(sr + 64) * LDT + sc]) = ra1;
        *reinterpret_cast<uint4*>(&Bs[sr * LDT + sc])        = rb0;
        *reinterpret_cast<uint4*>(&Bs[(sr + 64) * LDT + sc]) = rb1;
        __syncthreads();
        if (k0 + 32 < k0e) {
            ra0 = *reinterpret_cast<const uint4*>(pA0 + k0 + 32);
            ra1 = *reinterpret_cast<const uint4*>(pA1 + k0 + 32);
            rb0 = *reinterpret_cast<const uint4*>(pB0 + k0 + 32);
            rb1 = *reinterpret_cast<const uint4*>(pB1 + k0 + 32);
        }

        bf16x8v af[4], bfr[4];
        #pragma unroll
        for (int m = 0; m < 4; ++m) {
            int ar = wr * 64 + m * 16 + l15;
            bf16x4v lo = *reinterpret_cast<const bf16x4v*>(&As[ar * LDT + kg]);
            bf16x4v hi = *reinterpret_cast<const bf16x4v*>(&As[ar * LDT + kg + 16]);
            af[m] = __builtin_shufflevector(lo, hi, 0, 1, 2, 3, 4, 5, 6, 7);
        }
        #pragma unroll
        for (int n = 0; n < 4; ++n) {
            int br = wc * 64 + n * 16 + l15;
            bf16x4v lo = *reinterpret_cast<const bf16x4v*>(&Bs[br * LDT + kg]);
            bf16x4v hi = *reinterpret_cast<const bf16x4v*>(&Bs[br * LDT + kg + 16]);
            bfr[n] = __builtin_shufflevector(lo, hi, 0, 1, 2, 3, 4, 5, 6, 7);
        }
        #pragma unroll
        for (int m = 0; m < 4; ++m)
            #pragma unroll
            for (int n = 0; n < 4; ++n)
                acc[m][n] = __builtin_amdgcn_mfma_f32_16x16x32_bf16(af[m], bfr[n], acc[m][n], 0, 0, 0);
        __syncthreads();
    }

    float* pslab = part + (size_t)blockIdx.z * M * Ntot;
    #pragma unroll
    for (int m = 0; m < 4; ++m) {
        int grow_base = row0 + wr * 64 + m * 16 + kg;
        #pragma unroll
        for (int j = 0; j < 4; ++j) {
            int grow = grow_base + j;
            if (grow >= M) continue;
            #pragma unroll
            for (int n = 0; n < 4; ++n) {
                int gcol = col0 + wc * 64 + n * 16 + l15;
                pslab[(size_t)grow * Ntot + gcol] = acc[m][n][j];
            }
        }
    }
}

// reduce partials; t = tanh(sum*rs). emb? out = (emb + prev + t)/3 : out = t
__global__ void reduce_tanh_kernel(const float* __restrict__ part, int S, int M, int N,
                                   const float* __restrict__ rs,
                                   const float* __restrict__ emb,
                                   const float* __restrict__ prev,
                                   float* __restrict__ out) {
    int i = blockIdx.x * blockDim.x + threadIdx.x;
    if (i >= M * N) return;
    int r = i / N, j = i - r * N;
    float s = 0.f;
    for (int z = 0; z < S; ++z) s += part[(size_t)z * M * N + i];
    if (rs) s *= rs[r];
    float t = tanhf(s);
    if (emb) out[i] = (emb[r * 64 + (j & 63)] + prev[i] + t) * (1.0f / 3.0f);
    else     out[i] = t;
}

// ---------------- conversion / fusion helpers -------------------------------
__global__ void make_cat_weights_kernel(
    const float* __restrict__ w_sh1, const float* __restrict__ w_sh1h,
    const float* __restrict__ b_sh1, const float* __restrict__ b_sh1h,
    const float* __restrict__ w_sh2, const float* __restrict__ w_sh2h,
    const float* __restrict__ b_sh2, const float* __restrict__ b_sh2h,
    const float* __restrict__ w_mlp1, const float* __restrict__ w_mlp1h,
    const float* __restrict__ b_mlp1, const float* __restrict__ b_mlp1h,
    float* __restrict__ W1cat, float* __restrict__ b1cat,
    float* __restrict__ W2bd,  float* __restrict__ b2cat,
    float* __restrict__ WMbd,  float* __restrict__ bMcat)
{
    int i = blockIdx.x * blockDim.x + threadIdx.x;
    if (i < 64 * 128) {
        int k = i >> 7, j = i & 127;
        W1cat[i] = (j < 64) ? w_sh1[k * 64 + j] : w_sh1h[k * 64 + (j - 64)];
        return;
    }
    i -= 64 * 128;
    if (i < 128) { b1cat[i] = (i < 64) ? b_sh1[i] : b_sh1h[i - 64]; return; }
    i -= 128;
    if (i < 128 * 128) {
        int k = i >> 7, j = i & 127;
        float v = 0.f;
        if (k < 64 && j < 64) v = w_sh2[k * 64 + j];
        else if (k >= 64 && j >= 64) v = w_sh2h[(k - 64) * 64 + (j - 64)];
        W2bd[i] = v;
        return;
    }
    i -= 128 * 128;
    if (i < 128) { b2cat[i] = (i < 64) ? b_sh2[i] : b_sh2h[i - 64]; return; }
    i -= 128;
    if (i < 128 * 512) {
        int k = i >> 9, j = i & 511;
        float v = 0.f;
        if (j < 256) { if (k < 64) v = w_mlp1[k * 256 + j]; }
        else         { if (k >= 64) v = w_mlp1h[(k - 64) * 256 + (j - 256)]; }
        WMbd[i] = v;
        return;
    }
    i -= 128 * 512;
    if (i < 512) { bMcat[i] = (i < 256) ? b_mlp1[i] : b_mlp1h[i - 256]; }
}

__global__ void concat_hh_kernel(const float* __restrict__ emb, const float* __restrict__ kg,
                                 float* __restrict__ out) {
    int i = blockIdx.x * blockDim.x + threadIdx.x;
    const int n = N_HH * 91;
    if (i >= n) return;
    int r = i / 91, c = i % 91;
    out[i] = (c < DIM) ? emb[r * DIM + c] : kg[r * 27 + (c - DIM)];
}

__global__ void make_ehb_kernel(const float* __restrict__ x9cat, const float* __restrict__ hh1,
                                ushort* __restrict__ out, int Rp) {
    int i = blockIdx.x * blockDim.x + threadIdx.x;
    if (i >= Rp * 256) return;
    int r = i >> 8, c = i & 255;
    float v = (r < N_HH) ? (x9cat[(size_t)(N_SS + r) * 512 + 256 + c] + hh1[(size_t)r * 256 + c]) : 0.f;
    out[i] = f2bf(v);
}

// ---------------- BatchNorm (graph path dual-BN apply) ----------------------
__global__ void bn_apply_cat_kernel(const float* __restrict__ X, const float* __restrict__ stats,
                                    const float* __restrict__ g1, const float* __restrict__ be1,
                                    const float* __restrict__ g2, const float* __restrict__ be2,
                                    int M, float* __restrict__ out) {
    int i = blockIdx.x * blockDim.x + threadIdx.x;
    if (i >= M * 512) return;
    int j = i & 511;
    float invM = 1.0f / (float)M;
    float mean = stats[j] * invM;
    float var  = fmaxf(stats[512 + j] * invM - mean * mean, 0.f);
    float ga = (j < 256) ? g1[j]  : g2[j - 256];
    float bb = (j < 256) ? be1[j] : be2[j - 256];
    float y = (X[i] - mean) * rsqrtf(var + 1e-5f) * ga + bb;
    out[i] = tanhf(y);
}

// ---------------- driver -----------------------------------------------------
extern "C" void kernel_launch(void* const* d_in, const int* in_sizes, int n_in,
                              void* d_out, int out_size, void* d_ws, size_t ws_size,
                              hipStream_t stream) {
    const int*   eiSH = (const int*)d_in[1];
    const int*   eiSS = (const int*)d_in[3];
    const int*   eiHH = (const int*)d_in[5];
    const float* P    = (const float*)d_in[6];
    const float* kg   = (const float*)d_in[7];
    const float* emb  = (const float*)d_in[8];
    const float* w_sh1  = (const float*)d_in[9];   const float* b_sh1  = (const float*)d_in[10];
    const float* w_sh2  = (const float*)d_in[11];  const float* b_sh2  = (const float*)d_in[12];
    const float* w_mlp1 = (const float*)d_in[13];  const float* b_mlp1 = (const float*)d_in[14];
    const float* g_bn1  = (const float*)d_in[15];  const float* be_bn1 = (const float*)d_in[16];
    const float* w_sh1h = (const float*)d_in[17];  const float* b_sh1h = (const float*)d_in[18];
    const float* w_sh2h = (const float*)d_in[19];  const float* b_sh2h = (const float*)d_in[20];
    const float* w_mlp1h= (const float*)d_in[21];  const float* b_mlp1h= (const float*)d_in[22];
    const float* g_bn1h = (const float*)d_in[23];  const float* be_bn1h= (const float*)d_in[24];
    const float* w_ss   = (const float*)d_in[25];  const float* b_ss   = (const float*)d_in[26];
    const float* w_hh   = (const float*)d_in[27];  const float* b_hh   = (const float*)d_in[28];
    const float* w_mlp  = (const float*)d_in[29];  const float* b_mlp  = (const float*)d_in[30];
    const float* g_si   = (const float*)d_in[31];  const float* be_si  = (const float*)d_in[32];
    float* out = (float*)d_out;

    const int E_SH = in_sizes[1] / 2;
    const int E_SS = in_sizes[3] / 2;
    const int E_HH = in_sizes[5] / 2;
    const int B    = in_sizes[6] / N_SS;      // 20000
    const int Mp   = ((B + 127) / 128) * 128; // 20096
    const int KP1  = 416;
    const int NP3  = 896;
    const int KSH  = 1216;
    const int KHH  = 832;
    const int HS_SH = (N_SH + 3) / 4;   // 299
    const int HS_SS = (N_SS + 3) / 4;   // 98
    const int HS_HH = (N_HH + 3) / 4;   // 202

    float* w = (float*)d_ws;
    size_t off = 0;
    auto alloc = [&](size_t n) { float* p = w + off; off += (n + 3) & ~(size_t)3; return p; };

    float* cntInv   = alloc(N_SH);
    // zero-block: statsCat + statsC2 + HT + HSST + HHHT + eswT (contiguous)
    float* statsCat = alloc(1024);
    float* statsC2  = alloc(512);
    ushort* HT      = (ushort*)alloc((size_t)128 * KSH / 2);
    ushort* HSST    = (ushort*)alloc((size_t)256 * KP1 / 2);
    ushort* HHHT    = (ushort*)alloc((size_t)256 * KHH / 2);
    ushort* eswT    = (ushort*)alloc((size_t)256 * KP1 / 2);
    float* zeroEnd  = w + off;
    float* W1cat   = alloc(64 * 128);
    float* b1cat   = alloc(128);
    float* W2bd    = alloc(128 * 128);
    float* b2cat   = alloc(128);
    float* WMbd    = alloc(128 * 512);
    float* bMcat   = alloc(512);
    ushort* adjb   = (ushort*)alloc((size_t)1280 * KSH / 2);
    ushort* adjSSb = (ushort*)alloc((size_t)512 * KP1 / 2);
    ushort* adjHHb = (ushort*)alloc((size_t)896 * KHH / 2);
    float* x2cat   = alloc((size_t)N_SH * 128);
    float* x9a2    = alloc((size_t)N_SH * 128);
    float* tmpBN   = alloc((size_t)N_SH * 512);
    float* x9cat   = alloc((size_t)N_SH * 512);
    float* ss1     = alloc((size_t)N_SS * 256);
    float* hh1     = alloc((size_t)N_HH * 256);
    float* xhh0    = alloc((size_t)N_HH * 91);
    ushort* eh_b   = (ushort*)alloc((size_t)NP3 * 256 / 2);
    // region A: packed adjacency tables (early) -> bufM f32 [Mp][256]
    float* regionA = alloc((size_t)Mp * 256);
    uint32_t* uSH  = (uint32_t*)regionA;
    uint32_t* uSS  = uSH + (size_t)N_SH * HS_SH;
    uint32_t* uHH  = uSS + (size_t)N_SS * HS_SS;
    size_t packed_words = (size_t)N_SH * HS_SH + (size_t)N_SS * HS_SS + (size_t)N_HH * HS_HH;
    float*  bufM   = regionA;
    // region B: split-K partials
    float* regionB = alloc((size_t)Mp * 256);
    float*  partials = regionB;
    (void)ws_size; (void)n_in; (void)out_size;

    auto gemmT = [&](const float* Am, const float* A2m, int lda1, int lda2,
                     const float* Bm, const float* bias,
                     ushort* oT, int ldt, int M, int N, int K) {
        dim3 g((N + BN - 1) / BN, (M + BM - 1) / BM);
        gemm_kernel<<<g, 256, 0, stream>>>(Am, A2m, lda1, lda2, Bm, bias,
                                           nullptr, oT, ldt, M, N, K, nullptr, 0);
    };
    auto gemmF = [&](const float* Am, const float* Bm, const float* bias,
                     float* C, int M, int N, int K, float* st, int sstride) {
        dim3 g((N + BN - 1) / BN, (M + BM - 1) / BM);
        gemm_kernel<<<g, 256, 0, stream>>>(Am, nullptr, K, 0, Bm, bias,
                                           C, nullptr, 0, M, N, K, st, sstride);
    };
    auto splitk = [&](const ushort* Am, const ushort* Bm, int M, int Mtiles, int K, int lda,
                      int Ntot, int S, const float* rs, const float* embA, const float* prev,
                      float* outp) {
        dim3 g(Ntot / 128, Mtiles, S);
        mfma_splitk_kernel<<<g, 256, 0, stream>>>(Am, Bm, M, K, lda, 128, Ntot, partials);
        reduce_tanh_kernel<<<(M * Ntot + 255) / 256, 256, 0, stream>>>(
            partials, S, M, Ntot, rs, embA, prev, outp);
    };

    // ---- memsets ----
    hipMemsetAsync(uSH, 0, packed_words * sizeof(uint32_t), stream);
    hipMemsetAsync(statsCat, 0, (size_t)((char*)zeroEnd - (char*)statsCat), stream);

    // ---- adjacency: fused packed build (4x8-bit counters) ----
    {
        int Etot = E_SH + E_SS + E_HH;
        build_adj3_kernel<<<(Etot + 255) / 256, 256, 0, stream>>>(
            eiSH, E_SH, HS_SH, uSH, eiSS, E_SS, HS_SS, uSS, eiHH, E_HH, HS_HH, uHH);
    }
    rowsum_inv_packed_kernel<<<(N_SH + 3) / 4, 256, 0, stream>>>(uSH, N_SH, HS_SH, cntInv);
    {
        int n1 = 1280 * KSH, n2 = 512 * KP1, n3 = 896 * KHH;
        cvt_unpack3_kernel<<<(n1 + n2 + n3 + 255) / 256, 256, 0, stream>>>(
            uSH, HS_SH, adjb, n1, KSH, uSS, HS_SS, adjSSb, n2, KP1, uHH, HS_HH, adjHHb, n3, KHH);
    }

    make_cat_weights_kernel<<<(90880 + 255) / 256, 256, 0, stream>>>(
        w_sh1, w_sh1h, b_sh1, b_sh1h, w_sh2, w_sh2h, b_sh2, b_sh2h,
        w_mlp1, w_mlp1h, b_mlp1, b_mlp1h,
        W1cat, b1cat, W2bd, b2cat, WMbd, bMcat);

    // ---- SH layers (fused branches) ----
    gemmT(emb, nullptr, 64, 0, W1cat, b1cat, HT, KSH, N_SH, 128, 64);
    splitk(adjb, HT, N_SH, 10, KSH, KSH, 128, 10, cntInv, nullptr, nullptr, x2cat);
    gemmT(x2cat, nullptr, 128, 0, W2bd, b2cat, HT, KSH, N_SH, 128, 128);
    splitk(adjb, HT, N_SH, 10, KSH, KSH, 128, 10, cntInv, emb, x2cat, x9a2);  // fused avg3
    gemmF(x9a2, WMbd, bMcat, tmpBN, N_SH, 512, 128, statsCat, 512);           // fused BN stats
    bn_apply_cat_kernel<<<(N_SH * 512 + 255) / 256, 256, 0, stream>>>(
        tmpBN, statsCat, g_bn1, be_bn1, g_bn1h, be_bn1h, N_SH, x9cat);

    // ---- SS graph ----
    gemmT(emb, nullptr, 64, 0, w_ss, b_ss, HSST, KP1, N_SS, 256, 64);
    splitk(adjSSb, HSST, N_SS, 4, KP1, KP1, 256, 4, nullptr, nullptr, nullptr, ss1);

    // ---- HH graph ----
    concat_hh_kernel<<<(N_HH * 91 + 255) / 256, 256, 0, stream>>>(emb, kg, xhh0);
    gemmT(xhh0, nullptr, 91, 0, w_hh, b_hh, HHHT, KHH, N_HH, 256, 91);
    splitk(adjHHb, HHHT, N_HH, 7, KHH, KHH, 256, 7, nullptr, nullptr, nullptr, hh1);

    // ---- eh operand ----
    make_ehb_kernel<<<(NP3 * 256 + 255) / 256, 256, 0, stream>>>(x9cat, hh1, eh_b, NP3);

    // ---- prescription path ----
    // esw: D^T = (es @ w_mlp)^T, es = x9cat[:,0:256][:390] + ss1 (fused A2)
    gemmT(x9cat, ss1, 512, 256, w_mlp, nullptr, eswT, KP1, N_SS, 256, 256);
    // C1': bufM = (P @ D)·(1/rowsum P) + b_mlp, with fused BN stats
    {
        dim3 g(2, (B + 127) / 128);
        mfma_c1_kernel<<<g, 256, 0, stream>>>(P, eswT, B, b_mlp, bufM, statsC2);
    }
    // C3: out = relu(BN(bufM)) @ eh^T (scale/shift from stats in-kernel)
    {
        dim3 g(NP3 / 128, (B + 127) / 128);
        mfma_c3_kernel<<<g, 256, 0, stream>>>(bufM, eh_b, B, N_HH, statsC2, g_si, be_si, out, N_HH);
    }
}